// Round 1
// baseline (7610.995 us; speedup 1.0000x reference)
//
#include <hip/hip_runtime.h>
#include <math.h>

#define KNN 20
constexpr int B_ = 8, N_ = 1024, BN_ = B_ * N_;

// ---------------- helpers ----------------
__device__ __forceinline__ float wave_sum(float v) {
#pragma unroll
  for (int off = 32; off >= 1; off >>= 1) v += __shfl_xor(v, off, 64);
  return v;
}

// top-K insertion with jax.lax.top_k stable tie semantics (equal values keep
// earlier index first). All indices static -> stays in VGPRs.
__device__ __forceinline__ void topk_insert(float (&val)[KNN], int (&ind)[KNN],
                                            float v, int m) {
  if (v > val[KNN - 1]) {
    int pos = 0;
#pragma unroll
    for (int j = 0; j < KNN; ++j) pos += (val[j] >= v) ? 1 : 0;
#pragma unroll
    for (int p = KNN - 1; p >= 1; --p)
      if (p - 1 >= pos) { val[p] = val[p - 1]; ind[p] = ind[p - 1]; }
#pragma unroll
    for (int p = 0; p < KNN; ++p)
      if (p == pos) { val[p] = v; ind[p] = m; }
  }
}

// ---------------- prep: transpose + expmap0 ----------------
__global__ void k_prep(const float* __restrict__ x, float* __restrict__ xt,
                       float* __restrict__ xp) {
  int i = blockIdx.x * 256 + threadIdx.x;  // 0..8191
  int b = i >> 10, n = i & 1023;
  float v0 = x[(b * 3 + 0) * N_ + n];
  float v1 = x[(b * 3 + 1) * N_ + n];
  float v2 = x[(b * 3 + 2) * N_ + n];
  xt[i * 3 + 0] = v0; xt[i * 3 + 1] = v1; xt[i * 3 + 2] = v2;
  float nsq = v0 * v0 + v1 * v1 + v2 * v2;
  float nn = sqrtf(fmaxf(nsq, 1e-15f));
  float s = tanhf(0.1f * nn) / (0.1f * nn);
  xp[i * 3 + 0] = s * v0; xp[i * 3 + 1] = s * v1; xp[i * 3 + 2] = s * v2;
}

// ---------------- knn in 3-d (euclidean coords) ----------------
__global__ void k_knn3(const float* __restrict__ xt, int* __restrict__ idx) {
  __shared__ float pts[3 * N_];
  __shared__ float sq[N_];
  int b = blockIdx.x >> 2;
  int chunk = blockIdx.x & 3;
  int t = threadIdx.x;
  const float* xb = xt + b * 3 * N_;
  for (int e = t; e < 3 * N_; e += 256) pts[e] = xb[e];
  __syncthreads();
  for (int i = t; i < N_; i += 256)
    sq[i] = pts[3 * i] * pts[3 * i] + pts[3 * i + 1] * pts[3 * i + 1] +
            pts[3 * i + 2] * pts[3 * i + 2];
  __syncthreads();
  int row = chunk * 256 + t;
  float p0 = pts[3 * row], p1 = pts[3 * row + 1], p2 = pts[3 * row + 2];
  float sr = sq[row];
  float val[KNN]; int ind[KNN];
#pragma unroll
  for (int j = 0; j < KNN; ++j) { val[j] = -INFINITY; ind[j] = 0; }
  for (int m = 0; m < N_; ++m) {
    float dot = p0 * pts[3 * m] + p1 * pts[3 * m + 1] + p2 * pts[3 * m + 2];
    float v = 2.f * dot - sr - sq[m];
    topk_insert(val, ind, v, m);
  }
  int base = (b * N_ + row) * KNN;
#pragma unroll
  for (int j = 0; j < KNN; ++j) idx[base + j] = ind[j];
}

// ---------------- hyperbolic feature u (per b,n,k, channel=lane) ----------
__device__ __forceinline__ float hyper_u(const float* __restrict__ xp,
                                         const float w1r[6], int b, int nbr,
                                         float c0, float c1, float c2) {
  const float* pn = xp + (size_t)(b * N_ + nbr) * 3;
  float a0 = pn[0], a1 = pn[1], a2 = pn[2];
  float x2 = a0 * a0 + a1 * a1 + a2 * a2;
  float y2 = c0 * c0 + c1 * c1 + c2 * c2;
  float xy = -(a0 * c0 + a1 * c1 + a2 * c2);
  float f1 = 1.f + 0.02f * xy + 0.01f * y2;
  float f2 = 1.f - 0.01f * x2;
  float den = 1.f + 0.02f * xy + 0.0001f * x2 * y2;
  float rden = 1.f / fmaxf(den, 1e-15f);
  float m0 = (f1 * a0 - f2 * c0) * rden;
  float m1 = (f1 * a1 - f2 * c1) * rden;
  float m2 = (f1 * a2 - f2 * c2) * rden;
  float nsq = m0 * m0 + m1 * m1 + m2 * m2 + y2;  // |[m,ctr]|^2
  float nn = sqrtf(fmaxf(nsq, 1e-15f));
  float sn = 0.1f * nn;
  float tt = fminf(sn, 1.f - 1e-7f);
  float s = atanhf(tt) / sn;  // scalar factors through the matvec
  float u = w1r[0] * m0 + w1r[1] * m1 + w1r[2] * m2 + w1r[3] * c0 +
            w1r[4] * c1 + w1r[5] * c2;
  return s * u;
}

__global__ void k_hyper_stats(const float* __restrict__ xp,
                              const int* __restrict__ idx,
                              const float* __restrict__ w1, float* gsum,
                              float* gsq) {
  int t = threadIdx.x, lane = t & 63, w = t >> 6;
  int gw = blockIdx.x * 4 + w;
  int b = gw >> 10;
  float w1r[6];
#pragma unroll
  for (int j = 0; j < 6; ++j) w1r[j] = w1[lane * 6 + j];
  const float* pc = xp + (size_t)gw * 3;
  float c0 = pc[0], c1 = pc[1], c2 = pc[2];
  float s = 0.f, s2 = 0.f;
  const int* ip = idx + (size_t)gw * KNN;
  for (int k = 0; k < KNN; ++k) {
    float u = hyper_u(xp, w1r, b, ip[k], c0, c1, c2);
    s += u; s2 += u * u;
  }
  __shared__ float ls[256], ls2[256];
  ls[t] = s; ls2[t] = s2;
  __syncthreads();
  if (t < 64) {
    float S = ls[t] + ls[64 + t] + ls[128 + t] + ls[192 + t];
    float S2 = ls2[t] + ls2[64 + t] + ls2[128 + t] + ls2[192 + t];
    int bkt = blockIdx.x & 31;
    atomicAdd(&gsum[bkt * 1024 + t], S);
    atomicAdd(&gsq[bkt * 1024 + t], S2);
  }
}

__global__ void k_hyper_fin(const float* gsum, const float* gsq, float* mu64,
                            float* invv) {
  int c = threadIdx.x;  // 64 threads
  float S = 0, S2 = 0;
  for (int k = 0; k < 32; ++k) { S += gsum[k * 1024 + c]; S2 += gsq[k * 1024 + c]; }
  const float Mi = 1.f / 163840.f;
  float mu = S * Mi;
  float ex2 = S2 * Mi - mu * mu;
  float var = wave_sum(ex2);
  mu64[c] = mu;
  if (c == 0) invv[0] = 1.f / sqrtf(var + 1e-5f);
}

__global__ void k_hyper_x1(const float* __restrict__ xp,
                           const int* __restrict__ idx,
                           const float* __restrict__ w1,
                           const float* __restrict__ mu64,
                           const float* __restrict__ invv,
                           float* __restrict__ x1) {
  int t = threadIdx.x, lane = t & 63, w = t >> 6;
  int gw = blockIdx.x * 4 + w;
  int b = gw >> 10;
  float w1r[6];
#pragma unroll
  for (int j = 0; j < 6; ++j) w1r[j] = w1[lane * 6 + j];
  const float* pc = xp + (size_t)gw * 3;
  float c0 = pc[0], c1 = pc[1], c2 = pc[2];
  float mu = mu64[lane];
  float inv = invv[0];
  const int* ip = idx + (size_t)gw * KNN;
  float mx = -INFINITY;
  for (int k = 0; k < KNN; ++k) {
    float u = hyper_u(xp, w1r, b, ip[k], c0, c1, c2);
    float vv = (u - mu) * inv;
    float l = vv > 0.f ? vv : 0.2f * vv;
    float nsq = wave_sum(l * l);
    float nn = sqrtf(fmaxf(nsq, 1e-15f));
    float sc = tanhf(0.1f * nn) / (0.1f * nn);
    mx = fmaxf(mx, sc * l);
  }
  float msq = wave_sum(mx * mx);
  float mn = sqrtf(fmaxf(msq, 1e-15f));
  float sn = 0.1f * mn;
  float tt = fminf(sn, 1.f - 1e-7f);
  x1[(size_t)gw * 64 + lane] = atanhf(tt) / sn * mx;
}

// ---------------- row squared norms ----------------
template <int CIN>
__global__ void k_rownorm(const float* __restrict__ xin, float* __restrict__ xx) {
  int r = blockIdx.x * 256 + threadIdx.x;
  const float* p = xin + (size_t)r * CIN;
  float s = 0.f;
  for (int c = 0; c < CIN; c += 4) {
    float4 v = *(const float4*)(p + c);
    s += v.x * v.x + v.y * v.y + v.z * v.z + v.w * v.w;
  }
  xx[r] = s;
}

// ---------------- pairwise pd = 2 x.y - |x|^2 - |y|^2 ----------------
template <int CIN>
__global__ __launch_bounds__(256) void k_pd(const float* __restrict__ xin,
                                            const float* __restrict__ xx,
                                            float* __restrict__ pd) {
  __shared__ float As[64][17], Bs[64][17];
  int b = blockIdx.z;
  int n0 = blockIdx.x * 64, m0 = blockIdx.y * 64;
  int t = threadIdx.x;
  int tr = t >> 4, tc = t & 15;
  float acc[4][4] = {};
  const float* xb = xin + (size_t)b * N_ * CIN;
  for (int c0 = 0; c0 < CIN; c0 += 16) {
    int e = t * 4;
    int i = e >> 4, cc = e & 15;
    float4 va = *(const float4*)(xb + (size_t)(n0 + i) * CIN + c0 + cc);
    As[i][cc] = va.x; As[i][cc + 1] = va.y; As[i][cc + 2] = va.z; As[i][cc + 3] = va.w;
    float4 vb = *(const float4*)(xb + (size_t)(m0 + i) * CIN + c0 + cc);
    Bs[i][cc] = vb.x; Bs[i][cc + 1] = vb.y; Bs[i][cc + 2] = vb.z; Bs[i][cc + 3] = vb.w;
    __syncthreads();
#pragma unroll
    for (int k = 0; k < 16; ++k) {
      float a[4], bb[4];
#pragma unroll
      for (int ii = 0; ii < 4; ++ii) a[ii] = As[tr * 4 + ii][k];
#pragma unroll
      for (int jj = 0; jj < 4; ++jj) bb[jj] = Bs[tc * 4 + jj][k];
#pragma unroll
      for (int ii = 0; ii < 4; ++ii)
#pragma unroll
        for (int jj = 0; jj < 4; ++jj) acc[ii][jj] += a[ii] * bb[jj];
    }
    __syncthreads();
  }
  const float* xxn = xx + b * N_;
#pragma unroll
  for (int ii = 0; ii < 4; ++ii) {
    int r = n0 + tr * 4 + ii;
#pragma unroll
    for (int jj = 0; jj < 4; ++jj) {
      int c = m0 + tc * 4 + jj;
      pd[((size_t)b * N_ + r) * N_ + c] = 2.f * acc[ii][jj] - xxn[r] - xxn[c];
    }
  }
}

// ---------------- top-20 of a pd row ----------------
__global__ void k_topk(const float* __restrict__ pd, int* __restrict__ idx) {
  int r = blockIdx.x * 64 + threadIdx.x;  // 8192 rows
  const float* row = pd + (size_t)r * N_;
  float val[KNN]; int ind[KNN];
#pragma unroll
  for (int j = 0; j < KNN; ++j) { val[j] = -INFINITY; ind[j] = 0; }
  for (int m = 0; m < N_; ++m) topk_insert(val, ind, row[m], m);
  int base = r * KNN;
#pragma unroll
  for (int j = 0; j < KNN; ++j) idx[base + j] = ind[j];
}

// ---------------- edge conv (two passes: PASS0 stats, PASS1 apply) --------
// y[o,k<K] = sum_c wA[o,c]*(nb_k - ctr)_c ;  y[o,K] = sum_c wB[o,c]*ctr_c
// full y = y[o,k] + y[o,K]
template <int CIN, int COUT, int PASS>
__global__ __launch_bounds__(256) void k_edge(
    const float* __restrict__ xin, const int* __restrict__ idx,
    const float* __restrict__ w, float* gsum, float* gsq,
    const float* __restrict__ aArr, const float* __restrict__ cArr,
    float* __restrict__ xout) {
  constexpr int ITEMS = COUT * (KNN + 1);
  constexpr int IPT = (ITEMS + 255) / 256;
  __shared__ float fsh[(KNN + 1) * (CIN + 1)];
  __shared__ float wch[2 * 8 * COUT];
  __shared__ float ysh[(KNN + 1) * (COUT + 1)];
  __shared__ int nidx[KNN];
  int t = threadIdx.x;
  int bn = blockIdx.x;
  int b = bn >> 10;
  if (t < KNN) nidx[t] = idx[(size_t)bn * KNN + t];
  for (int c = t; c < CIN; c += 256) fsh[KNN * (CIN + 1) + c] = xin[(size_t)bn * CIN + c];
  __syncthreads();
  for (int e = t; e < KNN * CIN; e += 256) {
    int k = e / CIN, c = e - k * CIN;
    fsh[k * (CIN + 1) + c] =
        xin[((size_t)(b << 10) + nidx[k]) * CIN + c] - fsh[KNN * (CIN + 1) + c];
  }
  float acc[IPT];
#pragma unroll
  for (int j = 0; j < IPT; ++j) acc[j] = 0.f;
  for (int c0 = 0; c0 < CIN; c0 += 8) {
    __syncthreads();
    for (int e = t; e < 8 * COUT; e += 256) {
      int o = e >> 3, cc = e & 7;
      wch[cc * COUT + o] = w[(size_t)o * (2 * CIN) + c0 + cc];
      wch[8 * COUT + cc * COUT + o] = w[(size_t)o * (2 * CIN) + CIN + c0 + cc];
    }
    __syncthreads();
#pragma unroll
    for (int j = 0; j < IPT; ++j) {
      int q = t + 256 * j;
      if (q < ITEMS) {
        int o = q / (KNN + 1), k = q - o * (KNN + 1);
        const float* wp = &wch[(k == KNN ? 8 * COUT : 0) + o];
        const float* fp = &fsh[k * (CIN + 1) + c0];
        float a = acc[j];
#pragma unroll
        for (int cc = 0; cc < 8; ++cc) a = fmaf(wp[cc * COUT], fp[cc], a);
        acc[j] = a;
      }
    }
  }
  __syncthreads();
#pragma unroll
  for (int j = 0; j < IPT; ++j) {
    int q = t + 256 * j;
    if (q < ITEMS) {
      int o = q / (KNN + 1), k = q - o * (KNN + 1);
      ysh[k * (COUT + 1) + o] = acc[j];
    }
  }
  __syncthreads();
  if (PASS == 0) {
    int bkt = bn & 31;
    for (int o = t; o < COUT; o += 256) {
      float yk = ysh[KNN * (COUT + 1) + o];
      float s = 0.f, s2 = 0.f;
#pragma unroll
      for (int k = 0; k < KNN; ++k) {
        float v = ysh[k * (COUT + 1) + o] + yk;
        s += v; s2 += v * v;
      }
      atomicAdd(&gsum[bkt * 1024 + o], s);
      atomicAdd(&gsq[bkt * 1024 + o], s2);
    }
  } else {
    for (int o = t; o < COUT; o += 256) {
      float av = aArr[o], cv = cArr[o];
      float yk = ysh[KNN * (COUT + 1) + o];
      float mx = -INFINITY;
#pragma unroll
      for (int k = 0; k < KNN; ++k) {
        float v = av * (ysh[k * (COUT + 1) + o] + yk) + cv;
        v = v > 0.f ? v : 0.2f * v;
        mx = fmaxf(mx, v);
      }
      xout[(size_t)bn * COUT + o] = mx;
    }
  }
}

// ---------------- bn finalize: scale/shift from bucketed sums -------------
__global__ void k_bnfin(const float* gsum, const float* gsq,
                        const float* __restrict__ g, const float* __restrict__ bb,
                        float* aArr, float* cArr, int COUT, float Minv) {
  int ch = blockIdx.x * 256 + threadIdx.x;
  if (ch >= COUT) return;
  float S = 0, S2 = 0;
  for (int k = 0; k < 32; ++k) { S += gsum[k * 1024 + ch]; S2 += gsq[k * 1024 + ch]; }
  float mu = S * Minv;
  float var = S2 * Minv - mu * mu;
  float a = g[ch] / sqrtf(var + 1e-5f);
  aArr[ch] = a;
  cArr[ch] = bb[ch] - mu * a;
}

// ---------------- final GEMM (feat 512 -> 1024) + stats ----------------
__global__ __launch_bounds__(256) void k_fgemm(
    const float* __restrict__ x1, const float* __restrict__ x2,
    const float* __restrict__ x3, const float* __restrict__ x4,
    const float* __restrict__ w5, float* __restrict__ y5, float* gsum,
    float* gsq) {
  __shared__ float fsh[8][513];
  __shared__ float wch[8 * 1024];
  int t = threadIdx.x;
  int bn0 = blockIdx.x * 8;
  for (int e = t; e < 8 * 512; e += 256) {
    int g = e >> 9, c = e & 511;
    int bn = bn0 + g;
    float v;
    if (c < 64) v = x1[(size_t)bn * 64 + c];
    else if (c < 128) v = x2[(size_t)bn * 64 + (c - 64)];
    else if (c < 256) v = x3[(size_t)bn * 128 + (c - 128)];
    else v = x4[(size_t)bn * 256 + (c - 256)];
    fsh[g][c] = v;
  }
  float acc[8][4] = {};
  for (int c0 = 0; c0 < 512; c0 += 8) {
    __syncthreads();
    for (int e = t; e < 8192; e += 256) {
      int o = e >> 3, cc = e & 7;
      wch[cc * 1024 + o] = w5[(size_t)o * 512 + c0 + cc];
    }
    __syncthreads();
#pragma unroll
    for (int cc = 0; cc < 8; ++cc) {
      float fv[8];
#pragma unroll
      for (int g = 0; g < 8; ++g) fv[g] = fsh[g][c0 + cc];
#pragma unroll
      for (int os = 0; os < 4; ++os) {
        float wv = wch[cc * 1024 + t + 256 * os];
#pragma unroll
        for (int g = 0; g < 8; ++g) acc[g][os] = fmaf(wv, fv[g], acc[g][os]);
      }
    }
  }
  int bkt = blockIdx.x & 31;
#pragma unroll
  for (int os = 0; os < 4; ++os) {
    int o = t + 256 * os;
    float s = 0.f, s2 = 0.f;
#pragma unroll
    for (int g = 0; g < 8; ++g) {
      float v = acc[g][os];
      y5[(size_t)(bn0 + g) * 1024 + o] = v;
      s += v; s2 += v * v;
    }
    atomicAdd(&gsum[bkt * 1024 + o], s);
    atomicAdd(&gsq[bkt * 1024 + o], s2);
  }
}

// ---------------- final bn + leaky + max over n ----------------
__global__ void k_fmax(const float* __restrict__ y5, const float* __restrict__ aArr,
                       const float* __restrict__ cArr, float* __restrict__ out) {
  int i = blockIdx.x * 256 + threadIdx.x;  // B*1024
  int b = i >> 10, o = i & 1023;
  float av = aArr[o], cv = cArr[o];
  float mx = -INFINITY;
  const float* p = y5 + (size_t)b * N_ * 1024 + o;
  for (int n = 0; n < N_; ++n) {
    float v = av * p[(size_t)n * 1024] + cv;
    v = v > 0.f ? v : 0.2f * v;
    mx = fmaxf(mx, v);
  }
  out[i] = mx;
}

// ---------------- launch ----------------
extern "C" void kernel_launch(void* const* d_in, const int* in_sizes, int n_in,
                              void* d_out, int out_size, void* d_ws,
                              size_t ws_size, hipStream_t stream) {
  const float* x  = (const float*)d_in[0];
  const float* w1 = (const float*)d_in[1];
  const float* w2 = (const float*)d_in[2];
  const float* g2 = (const float*)d_in[3];
  const float* b2 = (const float*)d_in[4];
  const float* w3 = (const float*)d_in[5];
  const float* g3 = (const float*)d_in[6];
  const float* b3 = (const float*)d_in[7];
  const float* w4 = (const float*)d_in[8];
  const float* g4 = (const float*)d_in[9];
  const float* b4 = (const float*)d_in[10];
  const float* w5 = (const float*)d_in[11];
  const float* g5 = (const float*)d_in[12];
  const float* b5 = (const float*)d_in[13];

  float* W = (float*)d_ws;
  float* xt = W;                       // 24576
  float* xp = W + 24576;               // 24576
  float* xx = W + 49152;               // 8192
  float* stats = W + 57344;            // gsum 32768 | gsq 32768 | a 1024 | c 1024 | mu 64 | inv
  float* gsum = stats;
  float* gsq  = stats + 32768;
  float* aArr = stats + 65536;
  float* cArr = stats + 66560;
  float* mu64 = stats + 67584;
  float* invv = stats + 67648;
  float* x1 = W + 126976;              // 524288
  float* x2 = W + 651264;              // 524288
  float* x3 = W + 1175552;             // 1048576
  float* x4 = W + 2224128;             // 2097152
  float* pd = W + 4321280;             // 8388608 (reused as y5)
  int* idx = (int*)(W + 12709888);     // 163840 ints
  float* out = (float*)d_out;

  // prep + hyper block
  k_prep<<<32, 256, 0, stream>>>(x, xt, xp);
  k_knn3<<<32, 256, 0, stream>>>(xt, idx);
  hipMemsetAsync(gsum, 0, 65536 * sizeof(float), stream);
  k_hyper_stats<<<2048, 256, 0, stream>>>(xp, idx, w1, gsum, gsq);
  k_hyper_fin<<<1, 64, 0, stream>>>(gsum, gsq, mu64, invv);
  k_hyper_x1<<<2048, 256, 0, stream>>>(xp, idx, w1, mu64, invv, x1);

  const float MinvE = 1.f / (float)(BN_ * KNN);

  // edge block 2: x1(64) -> x2(64)
  k_rownorm<64><<<32, 256, 0, stream>>>(x1, xx);
  k_pd<64><<<dim3(16, 16, 8), 256, 0, stream>>>(x1, xx, pd);
  k_topk<<<128, 64, 0, stream>>>(pd, idx);
  hipMemsetAsync(gsum, 0, 65536 * sizeof(float), stream);
  k_edge<64, 64, 0><<<8192, 256, 0, stream>>>(x1, idx, w2, gsum, gsq, aArr, cArr, x2);
  k_bnfin<<<1, 256, 0, stream>>>(gsum, gsq, g2, b2, aArr, cArr, 64, MinvE);
  k_edge<64, 64, 1><<<8192, 256, 0, stream>>>(x1, idx, w2, gsum, gsq, aArr, cArr, x2);

  // edge block 3: x2(64) -> x3(128)
  k_rownorm<64><<<32, 256, 0, stream>>>(x2, xx);
  k_pd<64><<<dim3(16, 16, 8), 256, 0, stream>>>(x2, xx, pd);
  k_topk<<<128, 64, 0, stream>>>(pd, idx);
  hipMemsetAsync(gsum, 0, 65536 * sizeof(float), stream);
  k_edge<64, 128, 0><<<8192, 256, 0, stream>>>(x2, idx, w3, gsum, gsq, aArr, cArr, x3);
  k_bnfin<<<1, 256, 0, stream>>>(gsum, gsq, g3, b3, aArr, cArr, 128, MinvE);
  k_edge<64, 128, 1><<<8192, 256, 0, stream>>>(x2, idx, w3, gsum, gsq, aArr, cArr, x3);

  // edge block 4: x3(128) -> x4(256)
  k_rownorm<128><<<32, 256, 0, stream>>>(x3, xx);
  k_pd<128><<<dim3(16, 16, 8), 256, 0, stream>>>(x3, xx, pd);
  k_topk<<<128, 64, 0, stream>>>(pd, idx);
  hipMemsetAsync(gsum, 0, 65536 * sizeof(float), stream);
  k_edge<128, 256, 0><<<8192, 256, 0, stream>>>(x3, idx, w4, gsum, gsq, aArr, cArr, x4);
  k_bnfin<<<1, 256, 0, stream>>>(gsum, gsq, g4, b4, aArr, cArr, 256, MinvE);
  k_edge<128, 256, 1><<<8192, 256, 0, stream>>>(x3, idx, w4, gsum, gsq, aArr, cArr, x4);

  // final: feat(512) @ w5^T -> y5(1024), bn over (B,N), leaky, max over n
  hipMemsetAsync(gsum, 0, 65536 * sizeof(float), stream);
  k_fgemm<<<1024, 256, 0, stream>>>(x1, x2, x3, x4, w5, pd, gsum, gsq);
  k_bnfin<<<4, 256, 0, stream>>>(gsum, gsq, g5, b5, aArr, cArr, 1024, 1.f / (float)BN_);
  k_fmax<<<32, 256, 0, stream>>>(pd, aArr, cArr, out);
}

// Round 2
// 2998.529 us; speedup vs baseline: 2.5382x; 2.5382x over previous
//
#include <hip/hip_runtime.h>
#include <math.h>

#define KNN 20
constexpr int B_ = 8, N_ = 1024, BN_ = B_ * N_;

// ---------------- helpers ----------------
__device__ __forceinline__ float wave_sum(float v) {
#pragma unroll
  for (int off = 32; off >= 1; off >>= 1) v += __shfl_xor(v, off, 64);
  return v;
}

// top-K insertion with jax.lax.top_k stable tie semantics (equal values keep
// earlier index first). All indices static -> stays in VGPRs.
__device__ __forceinline__ void topk_insert(float (&val)[KNN], int (&ind)[KNN],
                                            float v, int m) {
  if (v > val[KNN - 1]) {
    int pos = 0;
#pragma unroll
    for (int j = 0; j < KNN; ++j) pos += (val[j] >= v) ? 1 : 0;
#pragma unroll
    for (int p = KNN - 1; p >= 1; --p)
      if (p - 1 >= pos) { val[p] = val[p - 1]; ind[p] = ind[p - 1]; }
#pragma unroll
    for (int p = 0; p < KNN; ++p)
      if (p == pos) { val[p] = v; ind[p] = m; }
  }
}

// ---------------- prep: transpose + expmap0 ----------------
__global__ void k_prep(const float* __restrict__ x, float* __restrict__ xt,
                       float* __restrict__ xp) {
  int i = blockIdx.x * 256 + threadIdx.x;  // 0..8191
  int b = i >> 10, n = i & 1023;
  float v0 = x[(b * 3 + 0) * N_ + n];
  float v1 = x[(b * 3 + 1) * N_ + n];
  float v2 = x[(b * 3 + 2) * N_ + n];
  xt[i * 3 + 0] = v0; xt[i * 3 + 1] = v1; xt[i * 3 + 2] = v2;
  float nsq = v0 * v0 + v1 * v1 + v2 * v2;
  float nn = sqrtf(fmaxf(nsq, 1e-15f));
  float s = tanhf(0.1f * nn) / (0.1f * nn);
  xp[i * 3 + 0] = s * v0; xp[i * 3 + 1] = s * v1; xp[i * 3 + 2] = s * v2;
}

// ---------------- knn in 3-d (euclidean coords) ----------------
__global__ void k_knn3(const float* __restrict__ xt, int* __restrict__ idx) {
  __shared__ float pts[3 * N_];
  __shared__ float sq[N_];
  int b = blockIdx.x >> 2;
  int chunk = blockIdx.x & 3;
  int t = threadIdx.x;
  const float* xb = xt + b * 3 * N_;
  for (int e = t; e < 3 * N_; e += 256) pts[e] = xb[e];
  __syncthreads();
  for (int i = t; i < N_; i += 256)
    sq[i] = pts[3 * i] * pts[3 * i] + pts[3 * i + 1] * pts[3 * i + 1] +
            pts[3 * i + 2] * pts[3 * i + 2];
  __syncthreads();
  int row = chunk * 256 + t;
  float p0 = pts[3 * row], p1 = pts[3 * row + 1], p2 = pts[3 * row + 2];
  float sr = sq[row];
  float val[KNN]; int ind[KNN];
#pragma unroll
  for (int j = 0; j < KNN; ++j) { val[j] = -INFINITY; ind[j] = 0; }
  for (int m = 0; m < N_; ++m) {
    float dot = p0 * pts[3 * m] + p1 * pts[3 * m + 1] + p2 * pts[3 * m + 2];
    float v = 2.f * dot - sr - sq[m];
    topk_insert(val, ind, v, m);
  }
  int base = (b * N_ + row) * KNN;
#pragma unroll
  for (int j = 0; j < KNN; ++j) idx[base + j] = ind[j];
}

// ---------------- hyperbolic feature u (per b,n,k, channel=lane) ----------
__device__ __forceinline__ float hyper_u(const float* __restrict__ xp,
                                         const float w1r[6], int b, int nbr,
                                         float c0, float c1, float c2) {
  const float* pn = xp + (size_t)(b * N_ + nbr) * 3;
  float a0 = pn[0], a1 = pn[1], a2 = pn[2];
  float x2 = a0 * a0 + a1 * a1 + a2 * a2;
  float y2 = c0 * c0 + c1 * c1 + c2 * c2;
  float xy = -(a0 * c0 + a1 * c1 + a2 * c2);
  float f1 = 1.f + 0.02f * xy + 0.01f * y2;
  float f2 = 1.f - 0.01f * x2;
  float den = 1.f + 0.02f * xy + 0.0001f * x2 * y2;
  float rden = 1.f / fmaxf(den, 1e-15f);
  float m0 = (f1 * a0 - f2 * c0) * rden;
  float m1 = (f1 * a1 - f2 * c1) * rden;
  float m2 = (f1 * a2 - f2 * c2) * rden;
  float nsq = m0 * m0 + m1 * m1 + m2 * m2 + y2;  // |[m,ctr]|^2
  float nn = sqrtf(fmaxf(nsq, 1e-15f));
  float sn = 0.1f * nn;
  float tt = fminf(sn, 1.f - 1e-7f);
  float s = atanhf(tt) / sn;  // scalar factors through the matvec
  float u = w1r[0] * m0 + w1r[1] * m1 + w1r[2] * m2 + w1r[3] * c0 +
            w1r[4] * c1 + w1r[5] * c2;
  return s * u;
}

__global__ void k_hyper_stats(const float* __restrict__ xp,
                              const int* __restrict__ idx,
                              const float* __restrict__ w1, float* gsum,
                              float* gsq) {
  int t = threadIdx.x, lane = t & 63, w = t >> 6;
  int gw = blockIdx.x * 4 + w;
  int b = gw >> 10;
  float w1r[6];
#pragma unroll
  for (int j = 0; j < 6; ++j) w1r[j] = w1[lane * 6 + j];
  const float* pc = xp + (size_t)gw * 3;
  float c0 = pc[0], c1 = pc[1], c2 = pc[2];
  float s = 0.f, s2 = 0.f;
  const int* ip = idx + (size_t)gw * KNN;
  for (int k = 0; k < KNN; ++k) {
    float u = hyper_u(xp, w1r, b, ip[k], c0, c1, c2);
    s += u; s2 += u * u;
  }
  __shared__ float ls[256], ls2[256];
  ls[t] = s; ls2[t] = s2;
  __syncthreads();
  if (t < 64) {
    float S = ls[t] + ls[64 + t] + ls[128 + t] + ls[192 + t];
    float S2 = ls2[t] + ls2[64 + t] + ls2[128 + t] + ls2[192 + t];
    int bkt = blockIdx.x & 31;
    atomicAdd(&gsum[bkt * 1024 + t], S);
    atomicAdd(&gsq[bkt * 1024 + t], S2);
  }
}

__global__ void k_hyper_fin(const float* gsum, const float* gsq, float* mu64,
                            float* invv) {
  int c = threadIdx.x;  // 64 threads
  float S = 0, S2 = 0;
  for (int k = 0; k < 32; ++k) { S += gsum[k * 1024 + c]; S2 += gsq[k * 1024 + c]; }
  const float Mi = 1.f / 163840.f;
  float mu = S * Mi;
  float ex2 = S2 * Mi - mu * mu;
  float var = wave_sum(ex2);
  mu64[c] = mu;
  if (c == 0) invv[0] = 1.f / sqrtf(var + 1e-5f);
}

__global__ void k_hyper_x1(const float* __restrict__ xp,
                           const int* __restrict__ idx,
                           const float* __restrict__ w1,
                           const float* __restrict__ mu64,
                           const float* __restrict__ invv,
                           float* __restrict__ x1) {
  int t = threadIdx.x, lane = t & 63, w = t >> 6;
  int gw = blockIdx.x * 4 + w;
  int b = gw >> 10;
  float w1r[6];
#pragma unroll
  for (int j = 0; j < 6; ++j) w1r[j] = w1[lane * 6 + j];
  const float* pc = xp + (size_t)gw * 3;
  float c0 = pc[0], c1 = pc[1], c2 = pc[2];
  float mu = mu64[lane];
  float inv = invv[0];
  const int* ip = idx + (size_t)gw * KNN;
  float mx = -INFINITY;
  for (int k = 0; k < KNN; ++k) {
    float u = hyper_u(xp, w1r, b, ip[k], c0, c1, c2);
    float vv = (u - mu) * inv;
    float l = vv > 0.f ? vv : 0.2f * vv;
    float nsq = wave_sum(l * l);
    float nn = sqrtf(fmaxf(nsq, 1e-15f));
    float sc = tanhf(0.1f * nn) / (0.1f * nn);
    mx = fmaxf(mx, sc * l);
  }
  float msq = wave_sum(mx * mx);
  float mn = sqrtf(fmaxf(msq, 1e-15f));
  float sn = 0.1f * mn;
  float tt = fminf(sn, 1.f - 1e-7f);
  x1[(size_t)gw * 64 + lane] = atanhf(tt) / sn * mx;
}

// ---------------- row squared norms ----------------
template <int CIN>
__global__ void k_rownorm(const float* __restrict__ xin, float* __restrict__ xx) {
  int r = blockIdx.x * 256 + threadIdx.x;
  const float* p = xin + (size_t)r * CIN;
  float s = 0.f;
  for (int c = 0; c < CIN; c += 4) {
    float4 v = *(const float4*)(p + c);
    s += v.x * v.x + v.y * v.y + v.z * v.z + v.w * v.w;
  }
  xx[r] = s;
}

// ---------------- pairwise pd = 2 x.y - |x|^2 - |y|^2 ----------------
template <int CIN>
__global__ __launch_bounds__(256) void k_pd(const float* __restrict__ xin,
                                            const float* __restrict__ xx,
                                            float* __restrict__ pd) {
  __shared__ float As[64][17], Bs[64][17];
  int b = blockIdx.z;
  int n0 = blockIdx.x * 64, m0 = blockIdx.y * 64;
  int t = threadIdx.x;
  int tr = t >> 4, tc = t & 15;
  float acc[4][4] = {};
  const float* xb = xin + (size_t)b * N_ * CIN;
  int i = t >> 2, cc = (t & 3) * 4;
  for (int c0 = 0; c0 < CIN; c0 += 16) {
    float4 va = *(const float4*)(xb + (size_t)(n0 + i) * CIN + c0 + cc);
    float4 vb = *(const float4*)(xb + (size_t)(m0 + i) * CIN + c0 + cc);
    As[i][cc] = va.x; As[i][cc + 1] = va.y; As[i][cc + 2] = va.z; As[i][cc + 3] = va.w;
    Bs[i][cc] = vb.x; Bs[i][cc + 1] = vb.y; Bs[i][cc + 2] = vb.z; Bs[i][cc + 3] = vb.w;
    __syncthreads();
#pragma unroll
    for (int k = 0; k < 16; ++k) {
      float a[4], bb[4];
#pragma unroll
      for (int ii = 0; ii < 4; ++ii) a[ii] = As[tr * 4 + ii][k];
#pragma unroll
      for (int jj = 0; jj < 4; ++jj) bb[jj] = Bs[tc * 4 + jj][k];
#pragma unroll
      for (int ii = 0; ii < 4; ++ii)
#pragma unroll
        for (int jj = 0; jj < 4; ++jj) acc[ii][jj] += a[ii] * bb[jj];
    }
    __syncthreads();
  }
  const float* xxn = xx + b * N_;
#pragma unroll
  for (int ii = 0; ii < 4; ++ii) {
    int r = n0 + tr * 4 + ii;
#pragma unroll
    for (int jj = 0; jj < 4; ++jj) {
      int c = m0 + tc * 4 + jj;
      pd[((size_t)b * N_ + r) * N_ + c] = 2.f * acc[ii][jj] - xxn[r] - xxn[c];
    }
  }
}

// ---------------- top-20 of a pd row: 4 threads/row + stable 4-way merge ---
__global__ __launch_bounds__(256) void k_topk4(const float* __restrict__ pd,
                                               int* __restrict__ idx) {
  __shared__ float Lval[64][4][21];
  __shared__ int Lidx[64][4][21];
  int t = threadIdx.x;
  int rl = t >> 2;       // local row 0..63
  int q = t & 3;         // chunk of 256 columns
  int row = blockIdx.x * 64 + rl;
  const float4* rp = (const float4*)(pd + (size_t)row * N_ + q * 256);
  float val[KNN]; int ind[KNN];
#pragma unroll
  for (int j = 0; j < KNN; ++j) { val[j] = -INFINITY; ind[j] = 0; }
  int mbase = q * 256;
  for (int m4 = 0; m4 < 64; ++m4) {
    float4 v4 = rp[m4];
    int m = mbase + m4 * 4;
    topk_insert(val, ind, v4.x, m);
    topk_insert(val, ind, v4.y, m + 1);
    topk_insert(val, ind, v4.z, m + 2);
    topk_insert(val, ind, v4.w, m + 3);
  }
#pragma unroll
  for (int j = 0; j < KNN; ++j) { Lval[rl][q][j] = val[j]; Lidx[rl][q][j] = ind[j]; }
  __syncthreads();
  if (t < 64) {
    int p0 = 0, p1 = 0, p2 = 0, p3 = 0;
    int base = (blockIdx.x * 64 + t) * KNN;
#pragma unroll
    for (int sel = 0; sel < KNN; ++sel) {
      float v0 = p0 < KNN ? Lval[t][0][p0] : -INFINITY;
      float v1 = p1 < KNN ? Lval[t][1][p1] : -INFINITY;
      float v2 = p2 < KNN ? Lval[t][2][p2] : -INFINITY;
      float v3 = p3 < KNN ? Lval[t][3][p3] : -INFINITY;
      float best = v0; int bq = 0;
      if (v1 > best) { best = v1; bq = 1; }
      if (v2 > best) { best = v2; bq = 2; }
      if (v3 > best) { best = v3; bq = 3; }
      int pb = bq == 0 ? p0 : bq == 1 ? p1 : bq == 2 ? p2 : p3;
      idx[base + sel] = Lidx[t][bq][pb];
      p0 += (bq == 0); p1 += (bq == 1); p2 += (bq == 2); p3 += (bq == 3);
    }
  }
}

// ---------------- per-point linear maps: Y = X wA^T, Z = X wB^T ----------
template <int CIN, int COUT>
__global__ __launch_bounds__(256) void k_xw(const float* __restrict__ xin,
                                            const float* __restrict__ w,
                                            float* __restrict__ Y,
                                            float* __restrict__ Z) {
  __shared__ float As[64][17], Ws[64][17];
  int n0 = blockIdx.x * 64;
  int j0 = blockIdx.y * 64;
  float* outp; int obase, coff;
  if (j0 < COUT) { outp = Y; obase = j0; coff = 0; }
  else { outp = Z; obase = j0 - COUT; coff = CIN; }
  int t = threadIdx.x;
  int tr = t >> 4, tc = t & 15;
  int i = t >> 2, cc = (t & 3) * 4;
  float acc[4][4] = {};
  for (int c0 = 0; c0 < CIN; c0 += 16) {
    float4 va = *(const float4*)(xin + (size_t)(n0 + i) * CIN + c0 + cc);
    float4 vb = *(const float4*)(w + (size_t)(obase + i) * (2 * CIN) + coff + c0 + cc);
    As[i][cc] = va.x; As[i][cc + 1] = va.y; As[i][cc + 2] = va.z; As[i][cc + 3] = va.w;
    Ws[i][cc] = vb.x; Ws[i][cc + 1] = vb.y; Ws[i][cc + 2] = vb.z; Ws[i][cc + 3] = vb.w;
    __syncthreads();
#pragma unroll
    for (int k = 0; k < 16; ++k) {
      float a[4], bb[4];
#pragma unroll
      for (int ii = 0; ii < 4; ++ii) a[ii] = As[tr * 4 + ii][k];
#pragma unroll
      for (int jj = 0; jj < 4; ++jj) bb[jj] = Ws[tc * 4 + jj][k];
#pragma unroll
      for (int ii = 0; ii < 4; ++ii)
#pragma unroll
        for (int jj = 0; jj < 4; ++jj) acc[ii][jj] += a[ii] * bb[jj];
    }
    __syncthreads();
  }
#pragma unroll
  for (int ii = 0; ii < 4; ++ii)
#pragma unroll
    for (int jj = 0; jj < 4; ++jj)
      outp[(size_t)(n0 + tr * 4 + ii) * COUT + obase + tc * 4 + jj] = acc[ii][jj];
}

// ---------------- gather + BN-stats (PASS0) / BN+leaky+max (PASS1) --------
// edge value v[bn,k,o] = Y[nbr,o] - Y[bn,o] + Z[bn,o]
template <int COUT, int PASS>
__global__ __launch_bounds__(256) void k_gather(
    const float* __restrict__ Y, const float* __restrict__ Z,
    const int* __restrict__ idx, float* gsum, float* gsq,
    const float* __restrict__ aArr, const float* __restrict__ cArr,
    float* __restrict__ xout) {
  constexpr int J = COUT / 64;
  int t = threadIdx.x, lane = t & 63, w = t >> 6;
  int bn = blockIdx.x * 4 + w;
  int b = bn >> 10;
  int myidx = 0;
  if (lane < KNN) myidx = idx[(size_t)bn * KNN + lane];
  float base[J], acc[J], acc2[J], av[J], cv[J], mx[J];
#pragma unroll
  for (int j = 0; j < J; ++j) {
    int o = lane + 64 * j;
    base[j] = Z[(size_t)bn * COUT + o] - Y[(size_t)bn * COUT + o];
    acc[j] = 0.f; acc2[j] = 0.f; mx[j] = -INFINITY;
    if (PASS == 1) { av[j] = aArr[o]; cv[j] = cArr[o]; }
  }
  for (int k = 0; k < KNN; ++k) {
    int nbr = __shfl(myidx, k);
    const float* yr = Y + ((size_t)(b << 10) + nbr) * COUT;
#pragma unroll
    for (int j = 0; j < J; ++j) {
      float v = yr[lane + 64 * j] + base[j];
      if (PASS == 0) { acc[j] += v; acc2[j] += v * v; }
      else {
        float u = av[j] * v + cv[j];
        u = u > 0.f ? u : 0.2f * u;
        mx[j] = fmaxf(mx[j], u);
      }
    }
  }
  if (PASS == 0) {
    int bkt = bn & 31;
#pragma unroll
    for (int j = 0; j < J; ++j) {
      atomicAdd(&gsum[bkt * 1024 + lane + 64 * j], acc[j]);
      atomicAdd(&gsq[bkt * 1024 + lane + 64 * j], acc2[j]);
    }
  } else {
#pragma unroll
    for (int j = 0; j < J; ++j)
      xout[(size_t)bn * COUT + lane + 64 * j] = mx[j];
  }
}

// ---------------- bn finalize: scale/shift from bucketed sums -------------
__global__ void k_bnfin(const float* gsum, const float* gsq,
                        const float* __restrict__ g, const float* __restrict__ bb,
                        float* aArr, float* cArr, int COUT, float Minv) {
  int ch = blockIdx.x * 256 + threadIdx.x;
  if (ch >= COUT) return;
  float S = 0, S2 = 0;
  for (int k = 0; k < 32; ++k) { S += gsum[k * 1024 + ch]; S2 += gsq[k * 1024 + ch]; }
  float mu = S * Minv;
  float var = S2 * Minv - mu * mu;
  float a = g[ch] / sqrtf(var + 1e-5f);
  aArr[ch] = a;
  cArr[ch] = bb[ch] - mu * a;
}

// ---------------- final GEMM: feat(8192x512) @ w5^T(512x1024) + stats -----
__global__ __launch_bounds__(256) void k_fgemm2(
    const float* __restrict__ x1, const float* __restrict__ x2,
    const float* __restrict__ x3, const float* __restrict__ x4,
    const float* __restrict__ w5, float* __restrict__ y5, float* gsum,
    float* gsq) {
  __shared__ float As[64][17], Ws[64][17];
  __shared__ float st[16][65], st2[16][65];
  int n0 = blockIdx.x * 64, j0 = blockIdx.y * 64;
  int t = threadIdx.x;
  int tr = t >> 4, tc = t & 15;
  int i = t >> 2, cc = (t & 3) * 4;
  float acc[4][4] = {};
  for (int c0 = 0; c0 < 512; c0 += 16) {
    const float* src; int off, ld;
    if (c0 < 64) { src = x1; off = 0; ld = 64; }
    else if (c0 < 128) { src = x2; off = 64; ld = 64; }
    else if (c0 < 256) { src = x3; off = 128; ld = 128; }
    else { src = x4; off = 256; ld = 256; }
    float4 va = *(const float4*)(src + (size_t)(n0 + i) * ld + (c0 - off) + cc);
    float4 vb = *(const float4*)(w5 + (size_t)(j0 + i) * 512 + c0 + cc);
    As[i][cc] = va.x; As[i][cc + 1] = va.y; As[i][cc + 2] = va.z; As[i][cc + 3] = va.w;
    Ws[i][cc] = vb.x; Ws[i][cc + 1] = vb.y; Ws[i][cc + 2] = vb.z; Ws[i][cc + 3] = vb.w;
    __syncthreads();
#pragma unroll
    for (int k = 0; k < 16; ++k) {
      float a[4], bb[4];
#pragma unroll
      for (int ii = 0; ii < 4; ++ii) a[ii] = As[tr * 4 + ii][k];
#pragma unroll
      for (int jj = 0; jj < 4; ++jj) bb[jj] = Ws[tc * 4 + jj][k];
#pragma unroll
      for (int ii = 0; ii < 4; ++ii)
#pragma unroll
        for (int jj = 0; jj < 4; ++jj) acc[ii][jj] += a[ii] * bb[jj];
    }
    __syncthreads();
  }
  float s[4] = {}, s2[4] = {};
#pragma unroll
  for (int ii = 0; ii < 4; ++ii) {
    int r = n0 + tr * 4 + ii;
#pragma unroll
    for (int jj = 0; jj < 4; ++jj) {
      float v = acc[ii][jj];
      y5[(size_t)r * 1024 + j0 + tc * 4 + jj] = v;
      s[jj] += v; s2[jj] += v * v;
    }
  }
#pragma unroll
  for (int jj = 0; jj < 4; ++jj) { st[tr][tc * 4 + jj] = s[jj]; st2[tr][tc * 4 + jj] = s2[jj]; }
  __syncthreads();
  if (t < 64) {
    float S = 0.f, S2 = 0.f;
#pragma unroll
    for (int rr = 0; rr < 16; ++rr) { S += st[rr][t]; S2 += st2[rr][t]; }
    int bkt = blockIdx.x & 31;
    atomicAdd(&gsum[bkt * 1024 + j0 + t], S);
    atomicAdd(&gsq[bkt * 1024 + j0 + t], S2);
  }
}

// ---------------- final bn + leaky + max over n ----------------
__global__ void k_fmax(const float* __restrict__ y5, const float* __restrict__ aArr,
                       const float* __restrict__ cArr, float* __restrict__ out) {
  int i = blockIdx.x * 256 + threadIdx.x;  // B*1024
  int b = i >> 10, o = i & 1023;
  float av = aArr[o], cv = cArr[o];
  float mx = -INFINITY;
  const float* p = y5 + (size_t)b * N_ * 1024 + o;
  for (int n = 0; n < N_; ++n) {
    float v = av * p[(size_t)n * 1024] + cv;
    v = v > 0.f ? v : 0.2f * v;
    mx = fmaxf(mx, v);
  }
  out[i] = mx;
}

// ---------------- launch ----------------
extern "C" void kernel_launch(void* const* d_in, const int* in_sizes, int n_in,
                              void* d_out, int out_size, void* d_ws,
                              size_t ws_size, hipStream_t stream) {
  const float* x  = (const float*)d_in[0];
  const float* w1 = (const float*)d_in[1];
  const float* w2 = (const float*)d_in[2];
  const float* g2 = (const float*)d_in[3];
  const float* b2 = (const float*)d_in[4];
  const float* w3 = (const float*)d_in[5];
  const float* g3 = (const float*)d_in[6];
  const float* b3 = (const float*)d_in[7];
  const float* w4 = (const float*)d_in[8];
  const float* g4 = (const float*)d_in[9];
  const float* b4 = (const float*)d_in[10];
  const float* w5 = (const float*)d_in[11];
  const float* g5 = (const float*)d_in[12];
  const float* b5 = (const float*)d_in[13];

  float* W = (float*)d_ws;
  float* xt = W;                       // 24576
  float* xp = W + 24576;               // 24576
  float* xx = W + 49152;               // 8192
  float* stats = W + 57344;            // gsum 32768 | gsq 32768 | a 1024 | c 1024 | mu 64 | inv
  float* gsum = stats;
  float* gsq  = stats + 32768;
  float* aArr = stats + 65536;
  float* cArr = stats + 66560;
  float* mu64 = stats + 67584;
  float* invv = stats + 67648;
  float* x1 = W + 126976;              // 524288
  float* x2 = W + 651264;              // 524288
  float* x3 = W + 1175552;             // 1048576
  float* x4 = W + 2224128;             // 2097152
  float* pd = W + 4321280;             // 8388608 floats (aliased: Y|Z during edge, y5 at end)
  float* Y  = pd;                      // up to 8192*256
  float* Z  = pd + 2097152;            // up to 8192*256
  int* idx = (int*)(W + 12709888);     // 163840 ints
  float* out = (float*)d_out;

  // prep + hyper block
  k_prep<<<32, 256, 0, stream>>>(x, xt, xp);
  k_knn3<<<32, 256, 0, stream>>>(xt, idx);
  hipMemsetAsync(gsum, 0, 65536 * sizeof(float), stream);
  k_hyper_stats<<<2048, 256, 0, stream>>>(xp, idx, w1, gsum, gsq);
  k_hyper_fin<<<1, 64, 0, stream>>>(gsum, gsq, mu64, invv);
  k_hyper_x1<<<2048, 256, 0, stream>>>(xp, idx, w1, mu64, invv, x1);

  const float MinvE = 1.f / (float)(BN_ * KNN);

  // edge block 2: x1(64) -> x2(64)
  k_rownorm<64><<<32, 256, 0, stream>>>(x1, xx);
  k_pd<64><<<dim3(16, 16, 8), 256, 0, stream>>>(x1, xx, pd);
  k_topk4<<<128, 256, 0, stream>>>(pd, idx);
  k_xw<64, 64><<<dim3(128, 2), 256, 0, stream>>>(x1, w2, Y, Z);
  hipMemsetAsync(gsum, 0, 65536 * sizeof(float), stream);
  k_gather<64, 0><<<2048, 256, 0, stream>>>(Y, Z, idx, gsum, gsq, aArr, cArr, x2);
  k_bnfin<<<1, 256, 0, stream>>>(gsum, gsq, g2, b2, aArr, cArr, 64, MinvE);
  k_gather<64, 1><<<2048, 256, 0, stream>>>(Y, Z, idx, gsum, gsq, aArr, cArr, x2);

  // edge block 3: x2(64) -> x3(128)
  k_rownorm<64><<<32, 256, 0, stream>>>(x2, xx);
  k_pd<64><<<dim3(16, 16, 8), 256, 0, stream>>>(x2, xx, pd);
  k_topk4<<<128, 256, 0, stream>>>(pd, idx);
  k_xw<64, 128><<<dim3(128, 4), 256, 0, stream>>>(x2, w3, Y, Z);
  hipMemsetAsync(gsum, 0, 65536 * sizeof(float), stream);
  k_gather<128, 0><<<2048, 256, 0, stream>>>(Y, Z, idx, gsum, gsq, aArr, cArr, x3);
  k_bnfin<<<1, 256, 0, stream>>>(gsum, gsq, g3, b3, aArr, cArr, 128, MinvE);
  k_gather<128, 1><<<2048, 256, 0, stream>>>(Y, Z, idx, gsum, gsq, aArr, cArr, x3);

  // edge block 4: x3(128) -> x4(256)
  k_rownorm<128><<<32, 256, 0, stream>>>(x3, xx);
  k_pd<128><<<dim3(16, 16, 8), 256, 0, stream>>>(x3, xx, pd);
  k_topk4<<<128, 256, 0, stream>>>(pd, idx);
  k_xw<128, 256><<<dim3(128, 8), 256, 0, stream>>>(x3, w4, Y, Z);
  hipMemsetAsync(gsum, 0, 65536 * sizeof(float), stream);
  k_gather<256, 0><<<2048, 256, 0, stream>>>(Y, Z, idx, gsum, gsq, aArr, cArr, x4);
  k_bnfin<<<1, 256, 0, stream>>>(gsum, gsq, g4, b4, aArr, cArr, 256, MinvE);
  k_gather<256, 1><<<2048, 256, 0, stream>>>(Y, Z, idx, gsum, gsq, aArr, cArr, x4);

  // final: feat(512) @ w5^T -> y5(1024), bn over (B,N), leaky, max over n
  hipMemsetAsync(gsum, 0, 65536 * sizeof(float), stream);
  k_fgemm2<<<dim3(128, 16), 256, 0, stream>>>(x1, x2, x3, x4, w5, pd, gsum, gsq);
  k_bnfin<<<4, 256, 0, stream>>>(gsum, gsq, g5, b5, aArr, cArr, 1024, 1.f / (float)BN_);
  k_fmax<<<32, 256, 0, stream>>>(pd, aArr, cArr, out);
}

// Round 3
// 842.321 us; speedup vs baseline: 9.0357x; 3.5598x over previous
//
#include <hip/hip_runtime.h>
#include <math.h>

#define KNN 20
constexpr int B_ = 8, N_ = 1024, BN_ = B_ * N_;

// ---------------- helpers ----------------
__device__ __forceinline__ float wave_sum(float v) {
#pragma unroll
  for (int off = 32; off >= 1; off >>= 1) v += __shfl_xor(v, off, 64);
  return v;
}

// Sortable key: monotone float->u32 map (larger float => larger uint).
__device__ __forceinline__ unsigned sortable(float f) {
  unsigned u = __float_as_uint(f);
  return u ^ ((u & 0x80000000u) ? 0xFFFFFFFFu : 0x80000000u);
}

// Wave-per-row top-K extraction. Lane holds 16 candidates, element index
// m = lane + 64*s (so within-lane s ascending == m ascending). 20 rounds of
// lane-local max + butterfly reduce with jax.lax.top_k tie rule
// (value desc, index asc). Winner masked to key=0 (< any finite key).
__device__ __forceinline__ void topk_extract(unsigned (&key)[16], int lane,
                                             int* __restrict__ out) {
  for (int sel = 0; sel < KNN; ++sel) {
    unsigned bk = key[0]; int bs = 0;
#pragma unroll
    for (int s = 1; s < 16; ++s)
      if (key[s] > bk) { bk = key[s]; bs = s; }
    int bm = lane + (bs << 6);
#pragma unroll
    for (int off = 32; off >= 1; off >>= 1) {
      unsigned ok = __shfl_xor(bk, off, 64);
      int om = __shfl_xor(bm, off, 64);
      if (ok > bk || (ok == bk && om < bm)) { bk = ok; bm = om; }
    }
    if (lane == 0) out[sel] = bm;
    if ((bm & 63) == lane) {
      int ws_ = bm >> 6;
#pragma unroll
      for (int s = 0; s < 16; ++s)
        if (s == ws_) key[s] = 0u;
    }
  }
}

// ---------------- prep: transpose + expmap0 ----------------
__global__ void k_prep(const float* __restrict__ x, float* __restrict__ xt,
                       float* __restrict__ xp) {
  int i = blockIdx.x * 256 + threadIdx.x;  // 0..8191
  int b = i >> 10, n = i & 1023;
  float v0 = x[(b * 3 + 0) * N_ + n];
  float v1 = x[(b * 3 + 1) * N_ + n];
  float v2 = x[(b * 3 + 2) * N_ + n];
  xt[i * 3 + 0] = v0; xt[i * 3 + 1] = v1; xt[i * 3 + 2] = v2;
  float nsq = v0 * v0 + v1 * v1 + v2 * v2;
  float nn = sqrtf(fmaxf(nsq, 1e-15f));
  float s = tanhf(0.1f * nn) / (0.1f * nn);
  xp[i * 3 + 0] = s * v0; xp[i * 3 + 1] = s * v1; xp[i * 3 + 2] = s * v2;
}

// ---------------- knn in 3-d: wave per row, extraction top-k ----------------
__global__ __launch_bounds__(256) void k_knn3w(const float* __restrict__ xt,
                                               int* __restrict__ idx) {
  __shared__ float4 pts4[N_];
  int t = threadIdx.x;
  int row0 = blockIdx.x * 4;        // 4 rows per block, same batch (4 | 1024)
  int b = row0 >> 10;
  const float* xb = xt + (size_t)b * 3 * N_;
  for (int i = t; i < N_; i += 256) {
    float px = xb[3 * i], py = xb[3 * i + 1], pz = xb[3 * i + 2];
    pts4[i] = make_float4(px, py, pz, px * px + py * py + pz * pz);
  }
  __syncthreads();
  int lane = t & 63, w = t >> 6;
  int row = row0 + w, rl = row & 1023;
  float4 c = pts4[rl];
  unsigned key[16];
#pragma unroll
  for (int s = 0; s < 16; ++s) {
    int m = lane + 64 * s;
    float4 q = pts4[m];
    float dot = c.x * q.x + c.y * q.y + c.z * q.z;
    float v = 2.f * dot - c.w - q.w;
    key[s] = sortable(v);
  }
  topk_extract(key, lane, idx + (size_t)row * KNN);
}

// ---------------- top-20 of a pd row: wave per row ----------------
__global__ __launch_bounds__(256) void k_topkw(const float* __restrict__ pd,
                                               int* __restrict__ idx) {
  int t = threadIdx.x, lane = t & 63, w = t >> 6;
  int row = blockIdx.x * 4 + w;
  const float* rp = pd + (size_t)row * N_;
  unsigned key[16];
#pragma unroll
  for (int s = 0; s < 16; ++s) key[s] = sortable(rp[lane + 64 * s]);
  topk_extract(key, lane, idx + (size_t)row * KNN);
}

// ---------------- hyperbolic feature u (per b,n,k, channel=lane) ----------
__device__ __forceinline__ float hyper_u(const float* __restrict__ xp,
                                         const float w1r[6], int b, int nbr,
                                         float c0, float c1, float c2) {
  const float* pn = xp + (size_t)(b * N_ + nbr) * 3;
  float a0 = pn[0], a1 = pn[1], a2 = pn[2];
  float x2 = a0 * a0 + a1 * a1 + a2 * a2;
  float y2 = c0 * c0 + c1 * c1 + c2 * c2;
  float xy = -(a0 * c0 + a1 * c1 + a2 * c2);
  float f1 = 1.f + 0.02f * xy + 0.01f * y2;
  float f2 = 1.f - 0.01f * x2;
  float den = 1.f + 0.02f * xy + 0.0001f * x2 * y2;
  float rden = 1.f / fmaxf(den, 1e-15f);
  float m0 = (f1 * a0 - f2 * c0) * rden;
  float m1 = (f1 * a1 - f2 * c1) * rden;
  float m2 = (f1 * a2 - f2 * c2) * rden;
  float nsq = m0 * m0 + m1 * m1 + m2 * m2 + y2;  // |[m,ctr]|^2
  float nn = sqrtf(fmaxf(nsq, 1e-15f));
  float sn = 0.1f * nn;
  float tt = fminf(sn, 1.f - 1e-7f);
  float s = atanhf(tt) / sn;  // scalar factors through the matvec
  float u = w1r[0] * m0 + w1r[1] * m1 + w1r[2] * m2 + w1r[3] * c0 +
            w1r[4] * c1 + w1r[5] * c2;
  return s * u;
}

__global__ void k_hyper_stats(const float* __restrict__ xp,
                              const int* __restrict__ idx,
                              const float* __restrict__ w1, float* gsum,
                              float* gsq) {
  int t = threadIdx.x, lane = t & 63, w = t >> 6;
  int gw = blockIdx.x * 4 + w;
  int b = gw >> 10;
  float w1r[6];
#pragma unroll
  for (int j = 0; j < 6; ++j) w1r[j] = w1[lane * 6 + j];
  const float* pc = xp + (size_t)gw * 3;
  float c0 = pc[0], c1 = pc[1], c2 = pc[2];
  float s = 0.f, s2 = 0.f;
  const int* ip = idx + (size_t)gw * KNN;
  for (int k = 0; k < KNN; ++k) {
    float u = hyper_u(xp, w1r, b, ip[k], c0, c1, c2);
    s += u; s2 += u * u;
  }
  __shared__ float ls[256], ls2[256];
  ls[t] = s; ls2[t] = s2;
  __syncthreads();
  if (t < 64) {
    float S = ls[t] + ls[64 + t] + ls[128 + t] + ls[192 + t];
    float S2 = ls2[t] + ls2[64 + t] + ls2[128 + t] + ls2[192 + t];
    int bkt = blockIdx.x & 31;
    atomicAdd(&gsum[bkt * 1024 + t], S);
    atomicAdd(&gsq[bkt * 1024 + t], S2);
  }
}

__global__ void k_hyper_fin(const float* gsum, const float* gsq, float* mu64,
                            float* invv) {
  int c = threadIdx.x;  // 64 threads
  float S = 0, S2 = 0;
  for (int k = 0; k < 32; ++k) { S += gsum[k * 1024 + c]; S2 += gsq[k * 1024 + c]; }
  const float Mi = 1.f / 163840.f;
  float mu = S * Mi;
  float ex2 = S2 * Mi - mu * mu;
  float var = wave_sum(ex2);
  mu64[c] = mu;
  if (c == 0) invv[0] = 1.f / sqrtf(var + 1e-5f);
}

__global__ void k_hyper_x1(const float* __restrict__ xp,
                           const int* __restrict__ idx,
                           const float* __restrict__ w1,
                           const float* __restrict__ mu64,
                           const float* __restrict__ invv,
                           float* __restrict__ x1) {
  int t = threadIdx.x, lane = t & 63, w = t >> 6;
  int gw = blockIdx.x * 4 + w;
  int b = gw >> 10;
  float w1r[6];
#pragma unroll
  for (int j = 0; j < 6; ++j) w1r[j] = w1[lane * 6 + j];
  const float* pc = xp + (size_t)gw * 3;
  float c0 = pc[0], c1 = pc[1], c2 = pc[2];
  float mu = mu64[lane];
  float inv = invv[0];
  const int* ip = idx + (size_t)gw * KNN;
  float mx = -INFINITY;
  for (int k = 0; k < KNN; ++k) {
    float u = hyper_u(xp, w1r, b, ip[k], c0, c1, c2);
    float vv = (u - mu) * inv;
    float l = vv > 0.f ? vv : 0.2f * vv;
    float nsq = wave_sum(l * l);
    float nn = sqrtf(fmaxf(nsq, 1e-15f));
    float sc = tanhf(0.1f * nn) / (0.1f * nn);
    mx = fmaxf(mx, sc * l);
  }
  float msq = wave_sum(mx * mx);
  float mn = sqrtf(fmaxf(msq, 1e-15f));
  float sn = 0.1f * mn;
  float tt = fminf(sn, 1.f - 1e-7f);
  x1[(size_t)gw * 64 + lane] = atanhf(tt) / sn * mx;
}

// ---------------- row squared norms ----------------
template <int CIN>
__global__ void k_rownorm(const float* __restrict__ xin, float* __restrict__ xx) {
  int r = blockIdx.x * 256 + threadIdx.x;
  const float* p = xin + (size_t)r * CIN;
  float s = 0.f;
  for (int c = 0; c < CIN; c += 4) {
    float4 v = *(const float4*)(p + c);
    s += v.x * v.x + v.y * v.y + v.z * v.z + v.w * v.w;
  }
  xx[r] = s;
}

// ---------------- pairwise pd = 2 x.y - |x|^2 - |y|^2 ----------------
// NOTE: FMA/accumulation order deliberately unchanged (pd bits feed top-k ties).
template <int CIN>
__global__ __launch_bounds__(256) void k_pd(const float* __restrict__ xin,
                                            const float* __restrict__ xx,
                                            float* __restrict__ pd) {
  __shared__ float As[64][17], Bs[64][17];
  int b = blockIdx.z;
  int n0 = blockIdx.x * 64, m0 = blockIdx.y * 64;
  int t = threadIdx.x;
  int tr = t >> 4, tc = t & 15;
  float acc[4][4] = {};
  const float* xb = xin + (size_t)b * N_ * CIN;
  int i = t >> 2, cc = (t & 3) * 4;
  for (int c0 = 0; c0 < CIN; c0 += 16) {
    float4 va = *(const float4*)(xb + (size_t)(n0 + i) * CIN + c0 + cc);
    float4 vb = *(const float4*)(xb + (size_t)(m0 + i) * CIN + c0 + cc);
    As[i][cc] = va.x; As[i][cc + 1] = va.y; As[i][cc + 2] = va.z; As[i][cc + 3] = va.w;
    Bs[i][cc] = vb.x; Bs[i][cc + 1] = vb.y; Bs[i][cc + 2] = vb.z; Bs[i][cc + 3] = vb.w;
    __syncthreads();
#pragma unroll
    for (int k = 0; k < 16; ++k) {
      float a[4], bb[4];
#pragma unroll
      for (int ii = 0; ii < 4; ++ii) a[ii] = As[tr * 4 + ii][k];
#pragma unroll
      for (int jj = 0; jj < 4; ++jj) bb[jj] = Bs[tc * 4 + jj][k];
#pragma unroll
      for (int ii = 0; ii < 4; ++ii)
#pragma unroll
        for (int jj = 0; jj < 4; ++jj) acc[ii][jj] += a[ii] * bb[jj];
    }
    __syncthreads();
  }
  const float* xxn = xx + b * N_;
#pragma unroll
  for (int ii = 0; ii < 4; ++ii) {
    int r = n0 + tr * 4 + ii;
#pragma unroll
    for (int jj = 0; jj < 4; ++jj) {
      int c = m0 + tc * 4 + jj;
      pd[((size_t)b * N_ + r) * N_ + c] = 2.f * acc[ii][jj] - xxn[r] - xxn[c];
    }
  }
}

// ---------------- per-point linear maps: Y = X wA^T, Z = X wB^T ----------
template <int CIN, int COUT>
__global__ __launch_bounds__(256) void k_xw(const float* __restrict__ xin,
                                            const float* __restrict__ w,
                                            float* __restrict__ Y,
                                            float* __restrict__ Z) {
  __shared__ float As[64][17], Ws[64][17];
  int n0 = blockIdx.x * 64;
  int j0 = blockIdx.y * 64;
  float* outp; int obase, coff;
  if (j0 < COUT) { outp = Y; obase = j0; coff = 0; }
  else { outp = Z; obase = j0 - COUT; coff = CIN; }
  int t = threadIdx.x;
  int tr = t >> 4, tc = t & 15;
  int i = t >> 2, cc = (t & 3) * 4;
  float acc[4][4] = {};
  for (int c0 = 0; c0 < CIN; c0 += 16) {
    float4 va = *(const float4*)(xin + (size_t)(n0 + i) * CIN + c0 + cc);
    float4 vb = *(const float4*)(w + (size_t)(obase + i) * (2 * CIN) + coff + c0 + cc);
    As[i][cc] = va.x; As[i][cc + 1] = va.y; As[i][cc + 2] = va.z; As[i][cc + 3] = va.w;
    Ws[i][cc] = vb.x; Ws[i][cc + 1] = vb.y; Ws[i][cc + 2] = vb.z; Ws[i][cc + 3] = vb.w;
    __syncthreads();
#pragma unroll
    for (int k = 0; k < 16; ++k) {
      float a[4], bb[4];
#pragma unroll
      for (int ii = 0; ii < 4; ++ii) a[ii] = As[tr * 4 + ii][k];
#pragma unroll
      for (int jj = 0; jj < 4; ++jj) bb[jj] = Ws[tc * 4 + jj][k];
#pragma unroll
      for (int ii = 0; ii < 4; ++ii)
#pragma unroll
        for (int jj = 0; jj < 4; ++jj) acc[ii][jj] += a[ii] * bb[jj];
    }
    __syncthreads();
  }
#pragma unroll
  for (int ii = 0; ii < 4; ++ii)
#pragma unroll
    for (int jj = 0; jj < 4; ++jj)
      outp[(size_t)(n0 + tr * 4 + ii) * COUT + obase + tc * 4 + jj] = acc[ii][jj];
}

// ---------------- gather + BN-stats (PASS0) / BN+leaky+max (PASS1) --------
// edge value v[bn,k,o] = Y[nbr,o] - Y[bn,o] + Z[bn,o]
template <int COUT, int PASS>
__global__ __launch_bounds__(256) void k_gather(
    const float* __restrict__ Y, const float* __restrict__ Z,
    const int* __restrict__ idx, float* gsum, float* gsq,
    const float* __restrict__ aArr, const float* __restrict__ cArr,
    float* __restrict__ xout) {
  constexpr int J = COUT / 64;
  int t = threadIdx.x, lane = t & 63, w = t >> 6;
  int bn = blockIdx.x * 4 + w;
  int b = bn >> 10;
  int myidx = 0;
  if (lane < KNN) myidx = idx[(size_t)bn * KNN + lane];
  float base[J], acc[J], acc2[J], av[J], cv[J], mx[J];
#pragma unroll
  for (int j = 0; j < J; ++j) {
    int o = lane + 64 * j;
    base[j] = Z[(size_t)bn * COUT + o] - Y[(size_t)bn * COUT + o];
    acc[j] = 0.f; acc2[j] = 0.f; mx[j] = -INFINITY;
    if (PASS == 1) { av[j] = aArr[o]; cv[j] = cArr[o]; }
  }
  for (int k = 0; k < KNN; ++k) {
    int nbr = __shfl(myidx, k);
    const float* yr = Y + ((size_t)(b << 10) + nbr) * COUT;
#pragma unroll
    for (int j = 0; j < J; ++j) {
      float v = yr[lane + 64 * j] + base[j];
      if (PASS == 0) { acc[j] += v; acc2[j] += v * v; }
      else {
        float u = av[j] * v + cv[j];
        u = u > 0.f ? u : 0.2f * u;
        mx[j] = fmaxf(mx[j], u);
      }
    }
  }
  if (PASS == 0) {
    int bkt = bn & 31;
#pragma unroll
    for (int j = 0; j < J; ++j) {
      atomicAdd(&gsum[bkt * 1024 + lane + 64 * j], acc[j]);
      atomicAdd(&gsq[bkt * 1024 + lane + 64 * j], acc2[j]);
    }
  } else {
#pragma unroll
    for (int j = 0; j < J; ++j)
      xout[(size_t)bn * COUT + lane + 64 * j] = mx[j];
  }
}

// ---------------- bn finalize: scale/shift from bucketed sums -------------
__global__ void k_bnfin(const float* gsum, const float* gsq,
                        const float* __restrict__ g, const float* __restrict__ bb,
                        float* aArr, float* cArr, int COUT, float Minv) {
  int ch = blockIdx.x * 256 + threadIdx.x;
  if (ch >= COUT) return;
  float S = 0, S2 = 0;
  for (int k = 0; k < 32; ++k) { S += gsum[k * 1024 + ch]; S2 += gsq[k * 1024 + ch]; }
  float mu = S * Minv;
  float var = S2 * Minv - mu * mu;
  float a = g[ch] / sqrtf(var + 1e-5f);
  aArr[ch] = a;
  cArr[ch] = bb[ch] - mu * a;
}

// ---------------- final GEMM: feat(8192x512) @ w5^T(512x1024) + stats -----
__global__ __launch_bounds__(256) void k_fgemm2(
    const float* __restrict__ x1, const float* __restrict__ x2,
    const float* __restrict__ x3, const float* __restrict__ x4,
    const float* __restrict__ w5, float* __restrict__ y5, float* gsum,
    float* gsq) {
  __shared__ float As[64][17], Ws[64][17];
  __shared__ float st[16][65], st2[16][65];
  int n0 = blockIdx.x * 64, j0 = blockIdx.y * 64;
  int t = threadIdx.x;
  int tr = t >> 4, tc = t & 15;
  int i = t >> 2, cc = (t & 3) * 4;
  float acc[4][4] = {};
  for (int c0 = 0; c0 < 512; c0 += 16) {
    const float* src; int off, ld;
    if (c0 < 64) { src = x1; off = 0; ld = 64; }
    else if (c0 < 128) { src = x2; off = 64; ld = 64; }
    else if (c0 < 256) { src = x3; off = 128; ld = 128; }
    else { src = x4; off = 256; ld = 256; }
    float4 va = *(const float4*)(src + (size_t)(n0 + i) * ld + (c0 - off) + cc);
    float4 vb = *(const float4*)(w5 + (size_t)(j0 + i) * 512 + c0 + cc);
    As[i][cc] = va.x; As[i][cc + 1] = va.y; As[i][cc + 2] = va.z; As[i][cc + 3] = va.w;
    Ws[i][cc] = vb.x; Ws[i][cc + 1] = vb.y; Ws[i][cc + 2] = vb.z; Ws[i][cc + 3] = vb.w;
    __syncthreads();
#pragma unroll
    for (int k = 0; k < 16; ++k) {
      float a[4], bb[4];
#pragma unroll
      for (int ii = 0; ii < 4; ++ii) a[ii] = As[tr * 4 + ii][k];
#pragma unroll
      for (int jj = 0; jj < 4; ++jj) bb[jj] = Ws[tc * 4 + jj][k];
#pragma unroll
      for (int ii = 0; ii < 4; ++ii)
#pragma unroll
        for (int jj = 0; jj < 4; ++jj) acc[ii][jj] += a[ii] * bb[jj];
    }
    __syncthreads();
  }
  float s[4] = {}, s2[4] = {};
#pragma unroll
  for (int ii = 0; ii < 4; ++ii) {
    int r = n0 + tr * 4 + ii;
#pragma unroll
    for (int jj = 0; jj < 4; ++jj) {
      float v = acc[ii][jj];
      y5[(size_t)r * 1024 + j0 + tc * 4 + jj] = v;
      s[jj] += v; s2[jj] += v * v;
    }
  }
#pragma unroll
  for (int jj = 0; jj < 4; ++jj) { st[tr][tc * 4 + jj] = s[jj]; st2[tr][tc * 4 + jj] = s2[jj]; }
  __syncthreads();
  if (t < 64) {
    float S = 0.f, S2 = 0.f;
#pragma unroll
    for (int rr = 0; rr < 16; ++rr) { S += st[rr][t]; S2 += st2[rr][t]; }
    int bkt = blockIdx.x & 31;
    atomicAdd(&gsum[bkt * 1024 + j0 + t], S);
    atomicAdd(&gsq[bkt * 1024 + j0 + t], S2);
  }
}

// ---------------- final max over n: 8-way split + finalize ----------------
__global__ void k_fmax1(const float* __restrict__ y5, float* __restrict__ pmax) {
  int chunk = blockIdx.x >> 5;                       // 0..7
  int j = (blockIdx.x & 31) * 256 + threadIdx.x;     // 0..8191 = b*1024+o
  int b = j >> 10, o = j & 1023;
  int bn0 = b * 1024 + chunk * 128;
  const float* p = y5 + (size_t)bn0 * 1024 + o;
  float mx = -INFINITY;
  for (int n = 0; n < 128; ++n) mx = fmaxf(mx, p[(size_t)n * 1024]);
  pmax[chunk * 8192 + j] = mx;
}

// bn scale a = g/sqrt(var+eps) > 0 here (g == ones), so affine+leaky is
// monotone increasing and commutes with max.
__global__ void k_fmax2(const float* __restrict__ pmax,
                        const float* __restrict__ aArr,
                        const float* __restrict__ cArr, float* __restrict__ out) {
  int j = blockIdx.x * 256 + threadIdx.x;  // 0..8191
  int o = j & 1023;
  float mx = -INFINITY;
#pragma unroll
  for (int c = 0; c < 8; ++c) mx = fmaxf(mx, pmax[c * 8192 + j]);
  float v = aArr[o] * mx + cArr[o];
  v = v > 0.f ? v : 0.2f * v;
  out[j] = v;
}

// ---------------- launch ----------------
extern "C" void kernel_launch(void* const* d_in, const int* in_sizes, int n_in,
                              void* d_out, int out_size, void* d_ws,
                              size_t ws_size, hipStream_t stream) {
  const float* x  = (const float*)d_in[0];
  const float* w1 = (const float*)d_in[1];
  const float* w2 = (const float*)d_in[2];
  const float* g2 = (const float*)d_in[3];
  const float* b2 = (const float*)d_in[4];
  const float* w3 = (const float*)d_in[5];
  const float* g3 = (const float*)d_in[6];
  const float* b3 = (const float*)d_in[7];
  const float* w4 = (const float*)d_in[8];
  const float* g4 = (const float*)d_in[9];
  const float* b4 = (const float*)d_in[10];
  const float* w5 = (const float*)d_in[11];
  const float* g5 = (const float*)d_in[12];
  const float* b5 = (const float*)d_in[13];

  float* W = (float*)d_ws;
  float* xt = W;                       // 24576
  float* xp = W + 24576;               // 24576
  float* xx = W + 49152;               // 8192
  float* stats = W + 57344;            // gsum 32768 | gsq 32768 | a 1024 | c 1024 | mu 64 | inv
  float* gsum = stats;
  float* gsq  = stats + 32768;
  float* aArr = stats + 65536;
  float* cArr = stats + 66560;
  float* mu64 = stats + 67584;
  float* invv = stats + 67648;
  float* x1 = W + 126976;              // 524288
  float* x2 = W + 651264;              // 524288
  float* x3 = W + 1175552;             // 1048576 (reused as pmax at the end)
  float* x4 = W + 2224128;             // 2097152
  float* pd = W + 4321280;             // 8388608 floats (aliased: Y|Z during edge, y5 at end)
  float* Y  = pd;                      // up to 8192*256
  float* Z  = pd + 2097152;            // up to 8192*256
  int* idx = (int*)(W + 12709888);     // 163840 ints
  float* pmax = x3;                    // 65536 floats, x3 dead by then
  float* out = (float*)d_out;

  // prep + hyper block
  k_prep<<<32, 256, 0, stream>>>(x, xt, xp);
  k_knn3w<<<2048, 256, 0, stream>>>(xt, idx);
  hipMemsetAsync(gsum, 0, 65536 * sizeof(float), stream);
  k_hyper_stats<<<2048, 256, 0, stream>>>(xp, idx, w1, gsum, gsq);
  k_hyper_fin<<<1, 64, 0, stream>>>(gsum, gsq, mu64, invv);
  k_hyper_x1<<<2048, 256, 0, stream>>>(xp, idx, w1, mu64, invv, x1);

  const float MinvE = 1.f / (float)(BN_ * KNN);

  // edge block 2: x1(64) -> x2(64)
  k_rownorm<64><<<32, 256, 0, stream>>>(x1, xx);
  k_pd<64><<<dim3(16, 16, 8), 256, 0, stream>>>(x1, xx, pd);
  k_topkw<<<2048, 256, 0, stream>>>(pd, idx);
  k_xw<64, 64><<<dim3(128, 2), 256, 0, stream>>>(x1, w2, Y, Z);
  hipMemsetAsync(gsum, 0, 65536 * sizeof(float), stream);
  k_gather<64, 0><<<2048, 256, 0, stream>>>(Y, Z, idx, gsum, gsq, aArr, cArr, x2);
  k_bnfin<<<1, 256, 0, stream>>>(gsum, gsq, g2, b2, aArr, cArr, 64, MinvE);
  k_gather<64, 1><<<2048, 256, 0, stream>>>(Y, Z, idx, gsum, gsq, aArr, cArr, x2);

  // edge block 3: x2(64) -> x3(128)
  k_rownorm<64><<<32, 256, 0, stream>>>(x2, xx);
  k_pd<64><<<dim3(16, 16, 8), 256, 0, stream>>>(x2, xx, pd);
  k_topkw<<<2048, 256, 0, stream>>>(pd, idx);
  k_xw<64, 128><<<dim3(128, 4), 256, 0, stream>>>(x2, w3, Y, Z);
  hipMemsetAsync(gsum, 0, 65536 * sizeof(float), stream);
  k_gather<128, 0><<<2048, 256, 0, stream>>>(Y, Z, idx, gsum, gsq, aArr, cArr, x3);
  k_bnfin<<<1, 256, 0, stream>>>(gsum, gsq, g3, b3, aArr, cArr, 128, MinvE);
  k_gather<128, 1><<<2048, 256, 0, stream>>>(Y, Z, idx, gsum, gsq, aArr, cArr, x3);

  // edge block 4: x3(128) -> x4(256)
  k_rownorm<128><<<32, 256, 0, stream>>>(x3, xx);
  k_pd<128><<<dim3(16, 16, 8), 256, 0, stream>>>(x3, xx, pd);
  k_topkw<<<2048, 256, 0, stream>>>(pd, idx);
  k_xw<128, 256><<<dim3(128, 8), 256, 0, stream>>>(x3, w4, Y, Z);
  hipMemsetAsync(gsum, 0, 65536 * sizeof(float), stream);
  k_gather<256, 0><<<2048, 256, 0, stream>>>(Y, Z, idx, gsum, gsq, aArr, cArr, x4);
  k_bnfin<<<1, 256, 0, stream>>>(gsum, gsq, g4, b4, aArr, cArr, 256, MinvE);
  k_gather<256, 1><<<2048, 256, 0, stream>>>(Y, Z, idx, gsum, gsq, aArr, cArr, x4);

  // final: feat(512) @ w5^T -> y5(1024), bn over (B,N), leaky, max over n
  hipMemsetAsync(gsum, 0, 65536 * sizeof(float), stream);
  k_fgemm2<<<dim3(128, 16), 256, 0, stream>>>(x1, x2, x3, x4, w5, pd, gsum, gsq);
  k_bnfin<<<4, 256, 0, stream>>>(gsum, gsq, g5, b5, aArr, cArr, 1024, 1.f / (float)BN_);
  k_fmax1<<<256, 256, 0, stream>>>(pd, pmax);
  k_fmax2<<<32, 256, 0, stream>>>(pmax, aArr, cArr, out);
}

// Round 5
// 640.501 us; speedup vs baseline: 11.8829x; 1.3151x over previous
//
#include <hip/hip_runtime.h>
#include <math.h>

#define KNN 20
constexpr int B_ = 8, N_ = 1024, BN_ = B_ * N_;

using f32x4 = __attribute__((ext_vector_type(4))) float;
using s8v = __attribute__((ext_vector_type(8))) short;

// ---------------- helpers ----------------
__device__ __forceinline__ float wave_sum(float v) {
#pragma unroll
  for (int off = 32; off >= 1; off >>= 1) v += __shfl_xor(v, off, 64);
  return v;
}

__device__ __forceinline__ unsigned sortable(float f) {
  unsigned u = __float_as_uint(f);
  return u ^ ((u & 0x80000000u) ? 0xFFFFFFFFu : 0x80000000u);
}

__device__ __forceinline__ unsigned short rne_bf16(float f) {
  unsigned u = __float_as_uint(f);
  unsigned r = (u + 0x7FFFu + ((u >> 16) & 1u)) >> 16;
  return (unsigned short)r;
}

// Wave-per-row top-K extraction (jax.lax.top_k tie rule: value desc, index asc).
__device__ __forceinline__ void topk_extract(unsigned (&key)[16], int lane,
                                             int* __restrict__ out) {
  for (int sel = 0; sel < KNN; ++sel) {
    unsigned bk = key[0]; int bs = 0;
#pragma unroll
    for (int s = 1; s < 16; ++s)
      if (key[s] > bk) { bk = key[s]; bs = s; }
    int bm = lane + (bs << 6);
#pragma unroll
    for (int off = 32; off >= 1; off >>= 1) {
      unsigned ok = __shfl_xor(bk, off, 64);
      int om = __shfl_xor(bm, off, 64);
      if (ok > bk || (ok == bk && om < bm)) { bk = ok; bm = om; }
    }
    if (lane == 0) out[sel] = bm;
    if ((bm & 63) == lane) {
      int ws_ = bm >> 6;
#pragma unroll
      for (int s = 0; s < 16; ++s)
        if (s == ws_) key[s] = 0u;
    }
  }
}

// ---------------- prep: transpose + expmap0 ----------------
__global__ void k_prep(const float* __restrict__ x, float* __restrict__ xt,
                       float* __restrict__ xp) {
  int i = blockIdx.x * 256 + threadIdx.x;  // 0..8191
  int b = i >> 10, n = i & 1023;
  float v0 = x[(b * 3 + 0) * N_ + n];
  float v1 = x[(b * 3 + 1) * N_ + n];
  float v2 = x[(b * 3 + 2) * N_ + n];
  xt[i * 3 + 0] = v0; xt[i * 3 + 1] = v1; xt[i * 3 + 2] = v2;
  float nsq = v0 * v0 + v1 * v1 + v2 * v2;
  float nn = sqrtf(fmaxf(nsq, 1e-15f));
  float s = tanhf(0.1f * nn) / (0.1f * nn);
  xp[i * 3 + 0] = s * v0; xp[i * 3 + 1] = s * v1; xp[i * 3 + 2] = s * v2;
}

// ---------------- knn in 3-d: wave per row, extraction top-k ----------------
__global__ __launch_bounds__(256) void k_knn3w(const float* __restrict__ xt,
                                               int* __restrict__ idx) {
  __shared__ float4 pts4[N_];
  int t = threadIdx.x;
  int row0 = blockIdx.x * 4;
  int b = row0 >> 10;
  const float* xb = xt + (size_t)b * 3 * N_;
  for (int i = t; i < N_; i += 256) {
    float px = xb[3 * i], py = xb[3 * i + 1], pz = xb[3 * i + 2];
    pts4[i] = make_float4(px, py, pz, px * px + py * py + pz * pz);
  }
  __syncthreads();
  int lane = t & 63, w = t >> 6;
  int row = row0 + w, rl = row & 1023;
  float4 c = pts4[rl];
  unsigned key[16];
#pragma unroll
  for (int s = 0; s < 16; ++s) {
    int m = lane + 64 * s;
    float4 q = pts4[m];
    float dot = c.x * q.x + c.y * q.y + c.z * q.z;
    float v = 2.f * dot - c.w - q.w;
    key[s] = sortable(v);
  }
  topk_extract(key, lane, idx + (size_t)row * KNN);
}

// ---------------- top-20 of a pd row: wave per row ----------------
__global__ __launch_bounds__(256) void k_topkw(const float* __restrict__ pd,
                                               int* __restrict__ idx) {
  int t = threadIdx.x, lane = t & 63, w = t >> 6;
  int row = blockIdx.x * 4 + w;
  const float* rp = pd + (size_t)row * N_;
  unsigned key[16];
#pragma unroll
  for (int s = 0; s < 16; ++s) key[s] = sortable(rp[lane + 64 * s]);
  topk_extract(key, lane, idx + (size_t)row * KNN);
}

// ---------------- hyperbolic feature u (per b,n,k, channel=lane) ----------
__device__ __forceinline__ float hyper_u(const float* __restrict__ xp,
                                         const float w1r[6], int b, int nbr,
                                         float c0, float c1, float c2) {
  const float* pn = xp + (size_t)(b * N_ + nbr) * 3;
  float a0 = pn[0], a1 = pn[1], a2 = pn[2];
  float x2 = a0 * a0 + a1 * a1 + a2 * a2;
  float y2 = c0 * c0 + c1 * c1 + c2 * c2;
  float xy = -(a0 * c0 + a1 * c1 + a2 * c2);
  float f1 = 1.f + 0.02f * xy + 0.01f * y2;
  float f2 = 1.f - 0.01f * x2;
  float den = 1.f + 0.02f * xy + 0.0001f * x2 * y2;
  float rden = 1.f / fmaxf(den, 1e-15f);
  float m0 = (f1 * a0 - f2 * c0) * rden;
  float m1 = (f1 * a1 - f2 * c1) * rden;
  float m2 = (f1 * a2 - f2 * c2) * rden;
  float nsq = m0 * m0 + m1 * m1 + m2 * m2 + y2;
  float nn = sqrtf(fmaxf(nsq, 1e-15f));
  float sn = 0.1f * nn;
  float tt = fminf(sn, 1.f - 1e-7f);
  float s = atanhf(tt) / sn;
  float u = w1r[0] * m0 + w1r[1] * m1 + w1r[2] * m2 + w1r[3] * c0 +
            w1r[4] * c1 + w1r[5] * c2;
  return s * u;
}

__global__ void k_hyper_stats(const float* __restrict__ xp,
                              const int* __restrict__ idx,
                              const float* __restrict__ w1, float* gsum,
                              float* gsq) {
  int t = threadIdx.x, lane = t & 63, w = t >> 6;
  int gw = blockIdx.x * 4 + w;
  int b = gw >> 10;
  float w1r[6];
#pragma unroll
  for (int j = 0; j < 6; ++j) w1r[j] = w1[lane * 6 + j];
  const float* pc = xp + (size_t)gw * 3;
  float c0 = pc[0], c1 = pc[1], c2 = pc[2];
  float s = 0.f, s2 = 0.f;
  const int* ip = idx + (size_t)gw * KNN;
  for (int k = 0; k < KNN; ++k) {
    float u = hyper_u(xp, w1r, b, ip[k], c0, c1, c2);
    s += u; s2 += u * u;
  }
  __shared__ float ls[256], ls2[256];
  ls[t] = s; ls2[t] = s2;
  __syncthreads();
  if (t < 64) {
    float S = ls[t] + ls[64 + t] + ls[128 + t] + ls[192 + t];
    float S2 = ls2[t] + ls2[64 + t] + ls2[128 + t] + ls2[192 + t];
    int bkt = blockIdx.x & 31;
    atomicAdd(&gsum[bkt * 1024 + t], S);
    atomicAdd(&gsq[bkt * 1024 + t], S2);
  }
}

__global__ void k_hyper_fin(const float* gsum, const float* gsq, float* mu64,
                            float* invv) {
  int c = threadIdx.x;  // 64 threads
  float S = 0, S2 = 0;
  for (int k = 0; k < 32; ++k) { S += gsum[k * 1024 + c]; S2 += gsq[k * 1024 + c]; }
  const float Mi = 1.f / 163840.f;
  float mu = S * Mi;
  float ex2 = S2 * Mi - mu * mu;
  float var = wave_sum(ex2);
  mu64[c] = mu;
  if (c == 0) invv[0] = 1.f / sqrtf(var + 1e-5f);
}

__global__ void k_hyper_x1(const float* __restrict__ xp,
                           const int* __restrict__ idx,
                           const float* __restrict__ w1,
                           const float* __restrict__ mu64,
                           const float* __restrict__ invv,
                           float* __restrict__ x1) {
  int t = threadIdx.x, lane = t & 63, w = t >> 6;
  int gw = blockIdx.x * 4 + w;
  int b = gw >> 10;
  float w1r[6];
#pragma unroll
  for (int j = 0; j < 6; ++j) w1r[j] = w1[lane * 6 + j];
  const float* pc = xp + (size_t)gw * 3;
  float c0 = pc[0], c1 = pc[1], c2 = pc[2];
  float mu = mu64[lane];
  float inv = invv[0];
  const int* ip = idx + (size_t)gw * KNN;
  float mx = -INFINITY;
  for (int k = 0; k < KNN; ++k) {
    float u = hyper_u(xp, w1r, b, ip[k], c0, c1, c2);
    float vv = (u - mu) * inv;
    float l = vv > 0.f ? vv : 0.2f * vv;
    float nsq = wave_sum(l * l);
    float nn = sqrtf(fmaxf(nsq, 1e-15f));
    float sc = tanhf(0.1f * nn) / (0.1f * nn);
    mx = fmaxf(mx, sc * l);
  }
  float msq = wave_sum(mx * mx);
  float mn = sqrtf(fmaxf(msq, 1e-15f));
  float sn = 0.1f * mn;
  float tt = fminf(sn, 1.f - 1e-7f);
  x1[(size_t)gw * 64 + lane] = atanhf(tt) / sn * mx;
}

// ---------------- row squared norms ----------------
template <int CIN>
__global__ void k_rownorm(const float* __restrict__ xin, float* __restrict__ xx) {
  int r = blockIdx.x * 256 + threadIdx.x;
  const float* p = xin + (size_t)r * CIN;
  float s = 0.f;
  for (int c = 0; c < CIN; c += 4) {
    float4 v = *(const float4*)(p + c);
    s += v.x * v.x + v.y * v.y + v.z * v.z + v.w * v.w;
  }
  xx[r] = s;
}

// ---- fp32 GEMM tile core: LDS transposed [k][row] stride 68, b128 reads ----
// loads 64 rows x 64 k-cols from src (row stride LDR) into Lt[k][row]
__device__ __forceinline__ void load_t68(float (&Lt)[64][68],
                                         const float* __restrict__ src,
                                         int ldr, int t) {
  int row = t >> 2, kq = (t & 3) * 16;
  const float* p = src + (size_t)row * ldr + kq;
  float4 v0 = *(const float4*)(p);
  float4 v1 = *(const float4*)(p + 4);
  float4 v2 = *(const float4*)(p + 8);
  float4 v3 = *(const float4*)(p + 12);
  Lt[kq + 0][row] = v0.x;  Lt[kq + 1][row] = v0.y;
  Lt[kq + 2][row] = v0.z;  Lt[kq + 3][row] = v0.w;
  Lt[kq + 4][row] = v1.x;  Lt[kq + 5][row] = v1.y;
  Lt[kq + 6][row] = v1.z;  Lt[kq + 7][row] = v1.w;
  Lt[kq + 8][row] = v2.x;  Lt[kq + 9][row] = v2.y;
  Lt[kq + 10][row] = v2.z; Lt[kq + 11][row] = v2.w;
  Lt[kq + 12][row] = v3.x; Lt[kq + 13][row] = v3.y;
  Lt[kq + 14][row] = v3.z; Lt[kq + 15][row] = v3.w;
}

// ---------------- pairwise pd = 2 x.y - |x|^2 - |y|^2 (fp32!) -------------
template <int CIN>
__global__ __launch_bounds__(256) void k_pd2(const float* __restrict__ xin,
                                             const float* __restrict__ xx,
                                             float* __restrict__ pd) {
  __shared__ float At[64][68], Bt[64][68];
  int b = blockIdx.z;
  int n0 = blockIdx.x * 64, m0 = blockIdx.y * 64;
  int t = threadIdx.x;
  int tr4 = (t >> 4) * 4, tc4 = (t & 15) * 4;
  float acc[4][4] = {};
  const float* xb = xin + (size_t)b * N_ * CIN;
  for (int c0 = 0; c0 < CIN; c0 += 64) {
    if (c0) __syncthreads();
    load_t68(At, xb + (size_t)n0 * CIN + c0, CIN, t);
    load_t68(Bt, xb + (size_t)m0 * CIN + c0, CIN, t);
    __syncthreads();
#pragma unroll 4
    for (int k = 0; k < 64; ++k) {
      float4 a = *(const float4*)&At[k][tr4];
      float4 bb = *(const float4*)&Bt[k][tc4];
      float av[4] = {a.x, a.y, a.z, a.w};
      float bv[4] = {bb.x, bb.y, bb.z, bb.w};
#pragma unroll
      for (int ii = 0; ii < 4; ++ii)
#pragma unroll
        for (int jj = 0; jj < 4; ++jj) acc[ii][jj] = fmaf(av[ii], bv[jj], acc[ii][jj]);
    }
  }
  const float* xxn = xx + b * N_;
#pragma unroll
  for (int ii = 0; ii < 4; ++ii) {
    int r = n0 + tr4 + ii;
#pragma unroll
    for (int jj = 0; jj < 4; ++jj) {
      int c = m0 + tc4 + jj;
      pd[((size_t)b * N_ + r) * N_ + c] = 2.f * acc[ii][jj] - xxn[r] - xxn[c];
    }
  }
}

// ---------------- per-point linear maps: Y = X wA^T, Z = X wB^T ----------
template <int CIN, int COUT>
__global__ __launch_bounds__(256) void k_xw2(const float* __restrict__ xin,
                                             const float* __restrict__ w,
                                             float* __restrict__ Y,
                                             float* __restrict__ Z) {
  __shared__ float At[64][68], Bt[64][68];
  int n0 = blockIdx.x * 64;
  int j0 = blockIdx.y * 64;
  float* outp; int obase, coff;
  if (j0 < COUT) { outp = Y; obase = j0; coff = 0; }
  else { outp = Z; obase = j0 - COUT; coff = CIN; }
  int t = threadIdx.x;
  int tr4 = (t >> 4) * 4, tc4 = (t & 15) * 4;
  float acc[4][4] = {};
  for (int c0 = 0; c0 < CIN; c0 += 64) {
    if (c0) __syncthreads();
    load_t68(At, xin + (size_t)n0 * CIN + c0, CIN, t);
    load_t68(Bt, w + (size_t)obase * (2 * CIN) + coff + c0, 2 * CIN, t);
    __syncthreads();
#pragma unroll 4
    for (int k = 0; k < 64; ++k) {
      float4 a = *(const float4*)&At[k][tr4];
      float4 bb = *(const float4*)&Bt[k][tc4];
      float av[4] = {a.x, a.y, a.z, a.w};
      float bv[4] = {bb.x, bb.y, bb.z, bb.w};
#pragma unroll
      for (int ii = 0; ii < 4; ++ii)
#pragma unroll
        for (int jj = 0; jj < 4; ++jj) acc[ii][jj] = fmaf(av[ii], bv[jj], acc[ii][jj]);
    }
  }
#pragma unroll
  for (int ii = 0; ii < 4; ++ii)
#pragma unroll
    for (int jj = 0; jj < 4; ++jj)
      outp[(size_t)(n0 + tr4 + ii) * COUT + obase + tc4 + jj] = acc[ii][jj];
}

// ---------------- gather + BN-stats (PASS0) / BN+leaky+max (PASS1) --------
template <int COUT, int PASS>
__global__ __launch_bounds__(256) void k_gather(
    const float* __restrict__ Y, const float* __restrict__ Z,
    const int* __restrict__ idx, float* gsum, float* gsq,
    const float* __restrict__ aArr, const float* __restrict__ cArr,
    float* __restrict__ xout) {
  constexpr int J = COUT / 64;
  int t = threadIdx.x, lane = t & 63, w = t >> 6;
  int bn = blockIdx.x * 4 + w;
  int b = bn >> 10;
  int myidx = 0;
  if (lane < KNN) myidx = idx[(size_t)bn * KNN + lane];
  float base[J], acc[J], acc2[J], av[J], cv[J], mx[J];
#pragma unroll
  for (int j = 0; j < J; ++j) {
    int o = lane + 64 * j;
    base[j] = Z[(size_t)bn * COUT + o] - Y[(size_t)bn * COUT + o];
    acc[j] = 0.f; acc2[j] = 0.f; mx[j] = -INFINITY;
    if (PASS == 1) { av[j] = aArr[o]; cv[j] = cArr[o]; }
  }
  for (int k = 0; k < KNN; ++k) {
    int nbr = __shfl(myidx, k);
    const float* yr = Y + ((size_t)(b << 10) + nbr) * COUT;
#pragma unroll
    for (int j = 0; j < J; ++j) {
      float v = yr[lane + 64 * j] + base[j];
      if (PASS == 0) { acc[j] += v; acc2[j] += v * v; }
      else {
        float u = av[j] * v + cv[j];
        u = u > 0.f ? u : 0.2f * u;
        mx[j] = fmaxf(mx[j], u);
      }
    }
  }
  if (PASS == 0) {
    int bkt = bn & 31;
#pragma unroll
    for (int j = 0; j < J; ++j) {
      atomicAdd(&gsum[bkt * 1024 + lane + 64 * j], acc[j]);
      atomicAdd(&gsq[bkt * 1024 + lane + 64 * j], acc2[j]);
    }
  } else {
#pragma unroll
    for (int j = 0; j < J; ++j)
      xout[(size_t)bn * COUT + lane + 64 * j] = mx[j];
  }
}

// ---------------- bn finalize: scale/shift from bucketed sums -------------
__global__ void k_bnfin(const float* gsum, const float* gsq,
                        const float* __restrict__ g, const float* __restrict__ bb,
                        float* aArr, float* cArr, int COUT, float Minv) {
  int ch = blockIdx.x * 256 + threadIdx.x;
  if (ch >= COUT) return;
  float S = 0, S2 = 0;
  for (int k = 0; k < 32; ++k) { S += gsum[k * 1024 + ch]; S2 += gsq[k * 1024 + ch]; }
  float mu = S * Minv;
  float var = S2 * Minv - mu * mu;
  float a = g[ch] / sqrtf(var + 1e-5f);
  aArr[ch] = a;
  cArr[ch] = bb[ch] - mu * a;
}

// ---------------- pack feat (x1|x2|x3|x4) -> bf16 [8192][512] -------------
__global__ void k_packbf(const float* __restrict__ x1, const float* __restrict__ x2,
                         const float* __restrict__ x3, const float* __restrict__ x4,
                         unsigned short* __restrict__ fb) {
  int e = (blockIdx.x * 256 + threadIdx.x) * 4;
  int row = e >> 9, c = e & 511;
  const float* src; int off, ld;
  if (c < 64) { src = x1; off = 0; ld = 64; }
  else if (c < 128) { src = x2; off = 64; ld = 64; }
  else if (c < 256) { src = x3; off = 128; ld = 128; }
  else { src = x4; off = 256; ld = 256; }
  float4 v = *(const float4*)(src + (size_t)row * ld + (c - off));
  ushort4 o;
  o.x = rne_bf16(v.x); o.y = rne_bf16(v.y); o.z = rne_bf16(v.z); o.w = rne_bf16(v.w);
  *(ushort4*)(fb + (size_t)row * 512 + c) = o;
}

// ---------------- fp32 -> bf16 straight convert ----------------
__global__ void k_cvt(const float* __restrict__ src, unsigned short* __restrict__ dst) {
  int e = (blockIdx.x * 256 + threadIdx.x) * 4;
  float4 v = *(const float4*)(src + e);
  ushort4 o;
  o.x = rne_bf16(v.x); o.y = rne_bf16(v.y); o.z = rne_bf16(v.z); o.w = rne_bf16(v.w);
  *(ushort4*)(dst + e) = o;
}

// ---------------- final GEMM via MFMA bf16, fused stats + per-block max ---
// C[8192][1024] = featb @ w5b^T; emits bucketed sum/sumsq + partial max; no C store.
__global__ __launch_bounds__(256) void k_fgemm3(
    const unsigned short* __restrict__ fb, const unsigned short* __restrict__ wb,
    float* gsum, float* gsq, float* __restrict__ pmax) {
  int t = threadIdx.x, lane = t & 63, w = t >> 6;
  int m0 = blockIdx.x * 128;       // row block (128 rows, one batch)
  int j0 = blockIdx.y * 64;        // col block
  int r16 = lane & 15, kg = lane >> 4;
  f32x4 acc[2][4];
#pragma unroll
  for (int mi = 0; mi < 2; ++mi)
#pragma unroll
    for (int nj = 0; nj < 4; ++nj) acc[mi][nj] = {0.f, 0.f, 0.f, 0.f};
  const unsigned short* pa0 = fb + (size_t)(m0 + w * 32 + r16) * 512 + kg * 8;
  const unsigned short* pa1 = pa0 + 16 * 512;
  const unsigned short* pb0 = wb + (size_t)(j0 + r16) * 512 + kg * 8;
#pragma unroll 2
  for (int k0 = 0; k0 < 512; k0 += 32) {
    s8v a0 = *(const s8v*)(pa0 + k0);
    s8v a1 = *(const s8v*)(pa1 + k0);
    s8v b0 = *(const s8v*)(pb0 + k0);
    s8v b1 = *(const s8v*)(pb0 + 16 * 512 + k0);
    s8v b2 = *(const s8v*)(pb0 + 32 * 512 + k0);
    s8v b3 = *(const s8v*)(pb0 + 48 * 512 + k0);
    acc[0][0] = __builtin_amdgcn_mfma_f32_16x16x32_bf16(a0, b0, acc[0][0], 0, 0, 0);
    acc[0][1] = __builtin_amdgcn_mfma_f32_16x16x32_bf16(a0, b1, acc[0][1], 0, 0, 0);
    acc[0][2] = __builtin_amdgcn_mfma_f32_16x16x32_bf16(a0, b2, acc[0][2], 0, 0, 0);
    acc[0][3] = __builtin_amdgcn_mfma_f32_16x16x32_bf16(a0, b3, acc[0][3], 0, 0, 0);
    acc[1][0] = __builtin_amdgcn_mfma_f32_16x16x32_bf16(a1, b0, acc[1][0], 0, 0, 0);
    acc[1][1] = __builtin_amdgcn_mfma_f32_16x16x32_bf16(a1, b1, acc[1][1], 0, 0, 0);
    acc[1][2] = __builtin_amdgcn_mfma_f32_16x16x32_bf16(a1, b2, acc[1][2], 0, 0, 0);
    acc[1][3] = __builtin_amdgcn_mfma_f32_16x16x32_bf16(a1, b3, acc[1][3], 0, 0, 0);
  }
  // per-lane partials per col-frag nj (col = j0 + nj*16 + r16)
  float s[4], s2[4], mx[4];
#pragma unroll
  for (int nj = 0; nj < 4; ++nj) {
    s[nj] = 0.f; s2[nj] = 0.f; mx[nj] = -INFINITY;
#pragma unroll
    for (int mi = 0; mi < 2; ++mi)
#pragma unroll
      for (int r = 0; r < 4; ++r) {
        float v = acc[mi][nj][r];
        s[nj] += v; s2[nj] += v * v; mx[nj] = fmaxf(mx[nj], v);
      }
    // combine the 4 row-groups (lanes differing in bits 4-5)
    s[nj] += __shfl_xor(s[nj], 16, 64);  s[nj] += __shfl_xor(s[nj], 32, 64);
    s2[nj] += __shfl_xor(s2[nj], 16, 64); s2[nj] += __shfl_xor(s2[nj], 32, 64);
    mx[nj] = fmaxf(mx[nj], __shfl_xor(mx[nj], 16, 64));
    mx[nj] = fmaxf(mx[nj], __shfl_xor(mx[nj], 32, 64));
  }
  __shared__ float wsum[4][64], wsq[4][64], wmax[4][64];
  if (lane < 16) {
#pragma unroll
    for (int nj = 0; nj < 4; ++nj) {
      wsum[w][nj * 16 + lane] = s[nj];
      wsq[w][nj * 16 + lane] = s2[nj];
      wmax[w][nj * 16 + lane] = mx[nj];
    }
  }
  __syncthreads();
  if (t < 64) {
    float S = 0.f, S2 = 0.f, MX = -INFINITY;
#pragma unroll
    for (int ww = 0; ww < 4; ++ww) {
      S += wsum[ww][t]; S2 += wsq[ww][t]; MX = fmaxf(MX, wmax[ww][t]);
    }
    int o = j0 + t;
    int bkt = blockIdx.x & 31;
    atomicAdd(&gsum[bkt * 1024 + o], S);
    atomicAdd(&gsq[bkt * 1024 + o], S2);
    pmax[(size_t)(blockIdx.x & 7) * 8192 + (blockIdx.x >> 3) * 1024 + o] = MX;
  }
}

// final: bn + leaky over per-chunk maxes (a>0 so affine+leaky commutes w/ max)
__global__ void k_fmax2(const float* __restrict__ pmax,
                        const float* __restrict__ aArr,
                        const float* __restrict__ cArr, float* __restrict__ out) {
  int j = blockIdx.x * 256 + threadIdx.x;  // 0..8191
  int o = j & 1023;
  float mx = -INFINITY;
#pragma unroll
  for (int c = 0; c < 8; ++c) mx = fmaxf(mx, pmax[c * 8192 + j]);
  float v = aArr[o] * mx + cArr[o];
  v = v > 0.f ? v : 0.2f * v;
  out[j] = v;
}

// ---------------- launch ----------------
extern "C" void kernel_launch(void* const* d_in, const int* in_sizes, int n_in,
                              void* d_out, int out_size, void* d_ws,
                              size_t ws_size, hipStream_t stream) {
  const float* x  = (const float*)d_in[0];
  const float* w1 = (const float*)d_in[1];
  const float* w2 = (const float*)d_in[2];
  const float* g2 = (const float*)d_in[3];
  const float* b2 = (const float*)d_in[4];
  const float* w3 = (const float*)d_in[5];
  const float* g3 = (const float*)d_in[6];
  const float* b3 = (const float*)d_in[7];
  const float* w4 = (const float*)d_in[8];
  const float* g4 = (const float*)d_in[9];
  const float* b4 = (const float*)d_in[10];
  const float* w5 = (const float*)d_in[11];
  const float* g5 = (const float*)d_in[12];
  const float* b5 = (const float*)d_in[13];

  float* W = (float*)d_ws;
  float* xt = W;                       // 24576
  float* xp = W + 24576;               // 24576
  float* xx = W + 49152;               // 8192
  float* stats = W + 57344;
  float* gsum = stats;
  float* gsq  = stats + 32768;
  float* aArr = stats + 65536;
  float* cArr = stats + 66560;
  float* mu64 = stats + 67584;
  float* invv = stats + 67648;
  float* x1 = W + 126976;              // 8192*64
  float* x2 = W + 651264;              // 8192*64
  float* x3 = W + 1175552;             // 8192*128 (reused as pmax at the end)
  float* x4 = W + 2224128;             // 8192*256
  float* pd = W + 4321280;             // 8388608 floats (Y|Z alias; featb/w5b at end)
  float* Y  = pd;
  float* Z  = pd + 2097152;
  int* idx = (int*)(W + 12709888);     // 163840 ints
  unsigned short* featb = (unsigned short*)pd;              // 8192*512 bf16
  unsigned short* w5b   = (unsigned short*)(pd + 2097152);  // 1024*512 bf16
  float* pmax = x3;                    // 8*8192 floats, x3 dead by then
  float* out = (float*)d_out;

  // prep + hyper block
  k_prep<<<32, 256, 0, stream>>>(x, xt, xp);
  k_knn3w<<<2048, 256, 0, stream>>>(xt, idx);
  hipMemsetAsync(gsum, 0, 65536 * sizeof(float), stream);
  k_hyper_stats<<<2048, 256, 0, stream>>>(xp, idx, w1, gsum, gsq);
  k_hyper_fin<<<1, 64, 0, stream>>>(gsum, gsq, mu64, invv);
  k_hyper_x1<<<2048, 256, 0, stream>>>(xp, idx, w1, mu64, invv, x1);

  const float MinvE = 1.f / (float)(BN_ * KNN);

  // edge block 2: x1(64) -> x2(64)
  k_rownorm<64><<<32, 256, 0, stream>>>(x1, xx);
  k_pd2<64><<<dim3(16, 16, 8), 256, 0, stream>>>(x1, xx, pd);
  k_topkw<<<2048, 256, 0, stream>>>(pd, idx);
  k_xw2<64, 64><<<dim3(128, 2), 256, 0, stream>>>(x1, w2, Y, Z);
  hipMemsetAsync(gsum, 0, 65536 * sizeof(float), stream);
  k_gather<64, 0><<<2048, 256, 0, stream>>>(Y, Z, idx, gsum, gsq, aArr, cArr, x2);
  k_bnfin<<<1, 256, 0, stream>>>(gsum, gsq, g2, b2, aArr, cArr, 64, MinvE);
  k_gather<64, 1><<<2048, 256, 0, stream>>>(Y, Z, idx, gsum, gsq, aArr, cArr, x2);

  // edge block 3: x2(64) -> x3(128)
  k_rownorm<64><<<32, 256, 0, stream>>>(x2, xx);
  k_pd2<64><<<dim3(16, 16, 8), 256, 0, stream>>>(x2, xx, pd);
  k_topkw<<<2048, 256, 0, stream>>>(pd, idx);
  k_xw2<64, 128><<<dim3(128, 4), 256, 0, stream>>>(x2, w3, Y, Z);
  hipMemsetAsync(gsum, 0, 65536 * sizeof(float), stream);
  k_gather<128, 0><<<2048, 256, 0, stream>>>(Y, Z, idx, gsum, gsq, aArr, cArr, x3);
  k_bnfin<<<1, 256, 0, stream>>>(gsum, gsq, g3, b3, aArr, cArr, 128, MinvE);
  k_gather<128, 1><<<2048, 256, 0, stream>>>(Y, Z, idx, gsum, gsq, aArr, cArr, x3);

  // edge block 4: x3(128) -> x4(256)
  k_rownorm<128><<<32, 256, 0, stream>>>(x3, xx);
  k_pd2<128><<<dim3(16, 16, 8), 256, 0, stream>>>(x3, xx, pd);
  k_topkw<<<2048, 256, 0, stream>>>(pd, idx);
  k_xw2<128, 256><<<dim3(128, 8), 256, 0, stream>>>(x3, w4, Y, Z);
  hipMemsetAsync(gsum, 0, 65536 * sizeof(float), stream);
  k_gather<256, 0><<<2048, 256, 0, stream>>>(Y, Z, idx, gsum, gsq, aArr, cArr, x4);
  k_bnfin<<<1, 256, 0, stream>>>(gsum, gsq, g4, b4, aArr, cArr, 256, MinvE);
  k_gather<256, 1><<<2048, 256, 0, stream>>>(Y, Z, idx, gsum, gsq, aArr, cArr, x4);

  // pack bf16 operands (pd/Y/Z region is dead now)
  k_packbf<<<4096, 256, 0, stream>>>(x1, x2, x3, x4, featb);
  k_cvt<<<512, 256, 0, stream>>>(w5, w5b);

  // final: MFMA GEMM w/ fused stats+max, then bn+leaky+reduce
  hipMemsetAsync(gsum, 0, 65536 * sizeof(float), stream);
  k_fgemm3<<<dim3(64, 16), 256, 0, stream>>>(featb, w5b, gsum, gsq, pmax);
  k_bnfin<<<4, 256, 0, stream>>>(gsum, gsq, g5, b5, aArr, cArr, 1024, 1.f / (float)BN_);
  k_fmax2<<<32, 256, 0, stream>>>(pmax, aArr, cArr, out);
}

// Round 6
// 544.703 us; speedup vs baseline: 13.9727x; 1.1759x over previous
//
#include <hip/hip_runtime.h>
#include <math.h>

#define KNN 20
constexpr int B_ = 8, N_ = 1024, BN_ = B_ * N_;
constexpr int NEDGE = BN_ * KNN;  // 163840

using f32x4 = __attribute__((ext_vector_type(4))) float;
using s8v = __attribute__((ext_vector_type(8))) short;

// ---------------- helpers ----------------
__device__ __forceinline__ float wave_sum(float v) {
#pragma unroll
  for (int off = 32; off >= 1; off >>= 1) v += __shfl_xor(v, off, 64);
  return v;
}

__device__ __forceinline__ unsigned sortable(float f) {
  unsigned u = __float_as_uint(f);
  return u ^ ((u & 0x80000000u) ? 0xFFFFFFFFu : 0x80000000u);
}

__device__ __forceinline__ unsigned short rne_bf16(float f) {
  unsigned u = __float_as_uint(f);
  unsigned r = (u + 0x7FFFu + ((u >> 16) & 1u)) >> 16;
  return (unsigned short)r;
}

// Wave-per-row top-K extraction (jax.lax.top_k tie rule: value desc, index asc).
__device__ __forceinline__ void topk_extract(unsigned (&key)[16], int lane,
                                             int* __restrict__ out) {
  for (int sel = 0; sel < KNN; ++sel) {
    unsigned bk = key[0]; int bs = 0;
#pragma unroll
    for (int s = 1; s < 16; ++s)
      if (key[s] > bk) { bk = key[s]; bs = s; }
    int bm = lane + (bs << 6);
#pragma unroll
    for (int off = 32; off >= 1; off >>= 1) {
      unsigned ok = __shfl_xor(bk, off, 64);
      int om = __shfl_xor(bm, off, 64);
      if (ok > bk || (ok == bk && om < bm)) { bk = ok; bm = om; }
    }
    if (lane == 0) out[sel] = bm;
    if ((bm & 63) == lane) {
      int ws_ = bm >> 6;
#pragma unroll
      for (int s = 0; s < 16; ++s)
        if (s == ws_) key[s] = 0u;
    }
  }
}

// ---------------- prep: transpose + expmap0 ----------------
__global__ void k_prep(const float* __restrict__ x, float* __restrict__ xt,
                       float* __restrict__ xp) {
  int i = blockIdx.x * 256 + threadIdx.x;  // 0..8191
  int b = i >> 10, n = i & 1023;
  float v0 = x[(b * 3 + 0) * N_ + n];
  float v1 = x[(b * 3 + 1) * N_ + n];
  float v2 = x[(b * 3 + 2) * N_ + n];
  xt[i * 3 + 0] = v0; xt[i * 3 + 1] = v1; xt[i * 3 + 2] = v2;
  float nsq = v0 * v0 + v1 * v1 + v2 * v2;
  float nn = sqrtf(fmaxf(nsq, 1e-15f));
  float s = tanhf(0.1f * nn) / (0.1f * nn);
  xp[i * 3 + 0] = s * v0; xp[i * 3 + 1] = s * v1; xp[i * 3 + 2] = s * v2;
}

// ---------------- knn in 3-d: wave per row, extraction top-k ---------------
__global__ __launch_bounds__(256) void k_knn3w(const float* __restrict__ xt,
                                               int* __restrict__ idx) {
  __shared__ float4 pts4[N_];
  int t = threadIdx.x;
  int row0 = blockIdx.x * 4;
  int b = row0 >> 10;
  const float* xb = xt + (size_t)b * 3 * N_;
  for (int i = t; i < N_; i += 256) {
    float px = xb[3 * i], py = xb[3 * i + 1], pz = xb[3 * i + 2];
    pts4[i] = make_float4(px, py, pz, px * px + py * py + pz * pz);
  }
  __syncthreads();
  int lane = t & 63, w = t >> 6;
  int row = row0 + w, rl = row & 1023;
  float4 c = pts4[rl];
  unsigned key[16];
#pragma unroll
  for (int s = 0; s < 16; ++s) {
    int m = lane + 64 * s;
    float4 q = pts4[m];
    float dot = c.x * q.x + c.y * q.y + c.z * q.z;
    float v = 2.f * dot - c.w - q.w;
    key[s] = sortable(v);
  }
  topk_extract(key, lane, idx + (size_t)row * KNN);
}

// ---------------- top-20 of a pd row: wave per row ----------------
__global__ __launch_bounds__(256) void k_topkw(const float* __restrict__ pd,
                                               int* __restrict__ idx) {
  int t = threadIdx.x, lane = t & 63, w = t >> 6;
  int row = blockIdx.x * 4 + w;
  const float* rp = pd + (size_t)row * N_;
  unsigned key[16];
#pragma unroll
  for (int s = 0; s < 16; ++s) key[s] = sortable(rp[lane + 64 * s]);
  topk_extract(key, lane, idx + (size_t)row * KNN);
}

// ---------------- hyper geometry per edge + moment accumulation -----------
// f[e][0..5] = s * [m0,m1,m2,c0,c1,c2]; u[e,ch] = w1[ch] . f[e]
// mom: 27 x 16 buckets: 6 first moments, 21 upper-tri second moments.
__global__ __launch_bounds__(256) void k_hgeom(const float* __restrict__ xp,
                                               const int* __restrict__ idx,
                                               float* __restrict__ fgeo,
                                               float* __restrict__ mom) {
  int e = blockIdx.x * 256 + threadIdx.x;  // 0..163839
  int gw = e / KNN;
  int b = gw >> 10;
  int nbr = idx[e];
  const float* pc = xp + (size_t)gw * 3;
  float c0 = pc[0], c1 = pc[1], c2 = pc[2];
  const float* pn = xp + ((size_t)(b << 10) + nbr) * 3;
  float a0 = pn[0], a1 = pn[1], a2 = pn[2];
  float x2 = a0 * a0 + a1 * a1 + a2 * a2;
  float y2 = c0 * c0 + c1 * c1 + c2 * c2;
  float xy = -(a0 * c0 + a1 * c1 + a2 * c2);
  float f1 = 1.f + 0.02f * xy + 0.01f * y2;
  float f2 = 1.f - 0.01f * x2;
  float den = 1.f + 0.02f * xy + 0.0001f * x2 * y2;
  float rden = 1.f / fmaxf(den, 1e-15f);
  float m0 = (f1 * a0 - f2 * c0) * rden;
  float m1 = (f1 * a1 - f2 * c1) * rden;
  float m2 = (f1 * a2 - f2 * c2) * rden;
  float nsq = m0 * m0 + m1 * m1 + m2 * m2 + y2;
  float nn = sqrtf(fmaxf(nsq, 1e-15f));
  float sn = 0.1f * nn;
  float tt = fminf(sn, 1.f - 1e-7f);
  float s = atanhf(tt) / sn;
  float f[6] = {s * m0, s * m1, s * m2, s * c0, s * c1, s * c2};
#pragma unroll
  for (int j = 0; j < 6; ++j) fgeo[j * NEDGE + e] = f[j];
  // moments
  float mm[27];
  {
    int q = 0;
#pragma unroll
    for (int i = 0; i < 6; ++i) mm[q++] = f[i];
#pragma unroll
    for (int i = 0; i < 6; ++i)
#pragma unroll
      for (int j = i; j < 6; ++j) mm[q++] = f[i] * f[j];
  }
#pragma unroll
  for (int m = 0; m < 27; ++m) mm[m] = wave_sum(mm[m]);
  __shared__ float part[4][27];
  int lane = threadIdx.x & 63, w = threadIdx.x >> 6;
  if (lane == 0) {
#pragma unroll
    for (int m = 0; m < 27; ++m) part[w][m] = mm[m];
  }
  __syncthreads();
  int t = threadIdx.x;
  if (t < 27) {
    float v = part[0][t] + part[1][t] + part[2][t] + part[3][t];
    atomicAdd(&mom[t * 16 + (blockIdx.x & 15)], v);
  }
}

// mu[ch] = w1[ch].fbar ; var = sum_ch (w1[ch]^T M w1[ch] - mu^2)
__global__ void k_hfin2(const float* __restrict__ mom,
                        const float* __restrict__ w1, float* mu64,
                        float* invv) {
  __shared__ float M[27];
  int t = threadIdx.x;  // 64
  if (t < 27) {
    float s = 0.f;
    for (int k = 0; k < 16; ++k) s += mom[t * 16 + k];
    M[t] = s * (1.f / (float)NEDGE);
  }
  __syncthreads();
  float w1r[6];
#pragma unroll
  for (int j = 0; j < 6; ++j) w1r[j] = w1[t * 6 + j];
  float mu = 0.f;
#pragma unroll
  for (int j = 0; j < 6; ++j) mu = fmaf(w1r[j], M[j], mu);
  float q = 0.f;
  {
    int off = 6;
#pragma unroll
    for (int i = 0; i < 6; ++i) {
      q = fmaf(w1r[i] * w1r[i], M[off], q); ++off;
#pragma unroll
      for (int j = i + 1; j < 6; ++j) {
        q = fmaf(2.f * w1r[i] * w1r[j], M[off], q); ++off;
      }
    }
  }
  float varc = q - mu * mu;
  float var = wave_sum(varc);
  mu64[t] = mu;
  if (t == 0) invv[0] = 1.f / sqrtf(var + 1e-5f);
}

// ---------------- hyper x1: matvec + BN + leaky + expmap/max/logmap -------
// also emits xx[gw] = |x1 row|^2 (rownorm fused)
__global__ __launch_bounds__(256) void k_hyper_x1(
    const float* __restrict__ fgeo, const float* __restrict__ w1,
    const float* __restrict__ mu64, const float* __restrict__ invv,
    float* __restrict__ x1, float* __restrict__ xx) {
  int t = threadIdx.x, lane = t & 63, w = t >> 6;
  int gw = blockIdx.x * 4 + w;
  float w1r[6];
#pragma unroll
  for (int j = 0; j < 6; ++j) w1r[j] = w1[lane * 6 + j];
  float f[6] = {0.f, 0.f, 0.f, 0.f, 0.f, 0.f};
  if (lane < KNN) {
    int e = gw * KNN + lane;
#pragma unroll
    for (int j = 0; j < 6; ++j) f[j] = fgeo[j * NEDGE + e];
  }
  float mu = mu64[lane];
  float inv = invv[0];
  float mx = -INFINITY;
  for (int k = 0; k < KNN; ++k) {
    float u = 0.f;
#pragma unroll
    for (int j = 0; j < 6; ++j) u = fmaf(w1r[j], __shfl(f[j], k), u);
    float vv = (u - mu) * inv;
    float l = vv > 0.f ? vv : 0.2f * vv;
    float nsq = wave_sum(l * l);
    float nn = sqrtf(fmaxf(nsq, 1e-15f));
    float sn = 0.1f * nn;
    float sc = tanhf(sn) / sn;
    mx = fmaxf(mx, sc * l);
  }
  float msq = wave_sum(mx * mx);
  float mn = sqrtf(fmaxf(msq, 1e-15f));
  float sn = 0.1f * mn;
  float tt = fminf(sn, 1.f - 1e-7f);
  float val = atanhf(tt) / sn * mx;
  x1[(size_t)gw * 64 + lane] = val;
  float xs = wave_sum(val * val);
  if (lane == 0) xx[gw] = xs;
}

// ---- fp32 GEMM tile core: LDS transposed [k][row] stride 68, b128 reads ----
__device__ __forceinline__ void load_t68(float (&Lt)[64][68],
                                         const float* __restrict__ src,
                                         int ldr, int t) {
  int row = t >> 2, kq = (t & 3) * 16;
  const float* p = src + (size_t)row * ldr + kq;
  float4 v0 = *(const float4*)(p);
  float4 v1 = *(const float4*)(p + 4);
  float4 v2 = *(const float4*)(p + 8);
  float4 v3 = *(const float4*)(p + 12);
  Lt[kq + 0][row] = v0.x;  Lt[kq + 1][row] = v0.y;
  Lt[kq + 2][row] = v0.z;  Lt[kq + 3][row] = v0.w;
  Lt[kq + 4][row] = v1.x;  Lt[kq + 5][row] = v1.y;
  Lt[kq + 6][row] = v1.z;  Lt[kq + 7][row] = v1.w;
  Lt[kq + 8][row] = v2.x;  Lt[kq + 9][row] = v2.y;
  Lt[kq + 10][row] = v2.z; Lt[kq + 11][row] = v2.w;
  Lt[kq + 12][row] = v3.x; Lt[kq + 13][row] = v3.y;
  Lt[kq + 14][row] = v3.z; Lt[kq + 15][row] = v3.w;
}

// ---------------- pairwise pd = 2 x.y - |x|^2 - |y|^2 (fp32!) -------------
template <int CIN>
__global__ __launch_bounds__(256) void k_pd2(const float* __restrict__ xin,
                                             const float* __restrict__ xx,
                                             float* __restrict__ pd) {
  __shared__ float At[64][68], Bt[64][68];
  int b = blockIdx.z;
  int n0 = blockIdx.x * 64, m0 = blockIdx.y * 64;
  int t = threadIdx.x;
  int tr4 = (t >> 4) * 4, tc4 = (t & 15) * 4;
  float acc[4][4] = {};
  const float* xb = xin + (size_t)b * N_ * CIN;
  for (int c0 = 0; c0 < CIN; c0 += 64) {
    if (c0) __syncthreads();
    load_t68(At, xb + (size_t)n0 * CIN + c0, CIN, t);
    load_t68(Bt, xb + (size_t)m0 * CIN + c0, CIN, t);
    __syncthreads();
#pragma unroll 4
    for (int k = 0; k < 64; ++k) {
      float4 a = *(const float4*)&At[k][tr4];
      float4 bb = *(const float4*)&Bt[k][tc4];
      float av[4] = {a.x, a.y, a.z, a.w};
      float bv[4] = {bb.x, bb.y, bb.z, bb.w};
#pragma unroll
      for (int ii = 0; ii < 4; ++ii)
#pragma unroll
        for (int jj = 0; jj < 4; ++jj) acc[ii][jj] = fmaf(av[ii], bv[jj], acc[ii][jj]);
    }
  }
  const float* xxn = xx + b * N_;
#pragma unroll
  for (int ii = 0; ii < 4; ++ii) {
    int r = n0 + tr4 + ii;
#pragma unroll
    for (int jj = 0; jj < 4; ++jj) {
      int c = m0 + tc4 + jj;
      pd[((size_t)b * N_ + r) * N_ + c] = 2.f * acc[ii][jj] - xxn[r] - xxn[c];
    }
  }
}

// ---------------- per-point linear maps: Y = X wA^T, Z = X wB^T ----------
template <int CIN, int COUT>
__global__ __launch_bounds__(256) void k_xw2(const float* __restrict__ xin,
                                             const float* __restrict__ w,
                                             float* __restrict__ Y,
                                             float* __restrict__ Z) {
  __shared__ float At[64][68], Bt[64][68];
  int n0 = blockIdx.x * 64;
  int j0 = blockIdx.y * 64;
  float* outp; int obase, coff;
  if (j0 < COUT) { outp = Y; obase = j0; coff = 0; }
  else { outp = Z; obase = j0 - COUT; coff = CIN; }
  int t = threadIdx.x;
  int tr4 = (t >> 4) * 4, tc4 = (t & 15) * 4;
  float acc[4][4] = {};
  for (int c0 = 0; c0 < CIN; c0 += 64) {
    if (c0) __syncthreads();
    load_t68(At, xin + (size_t)n0 * CIN + c0, CIN, t);
    load_t68(Bt, w + (size_t)obase * (2 * CIN) + coff + c0, 2 * CIN, t);
    __syncthreads();
#pragma unroll 4
    for (int k = 0; k < 64; ++k) {
      float4 a = *(const float4*)&At[k][tr4];
      float4 bb = *(const float4*)&Bt[k][tc4];
      float av[4] = {a.x, a.y, a.z, a.w};
      float bv[4] = {bb.x, bb.y, bb.z, bb.w};
#pragma unroll
      for (int ii = 0; ii < 4; ++ii)
#pragma unroll
        for (int jj = 0; jj < 4; ++jj) acc[ii][jj] = fmaf(av[ii], bv[jj], acc[ii][jj]);
    }
  }
#pragma unroll
  for (int ii = 0; ii < 4; ++ii)
#pragma unroll
    for (int jj = 0; jj < 4; ++jj)
      outp[(size_t)(n0 + tr4 + ii) * COUT + obase + tc4 + jj] = acc[ii][jj];
}

// ---------------- gather + BN-stats (PASS0) / BN+leaky+max (PASS1) --------
// WXX: PASS1 also emits xx[bn] = |out row|^2 (rownorm fused)
template <int COUT, int PASS, bool WXX>
__global__ __launch_bounds__(256) void k_gather(
    const float* __restrict__ Y, const float* __restrict__ Z,
    const int* __restrict__ idx, float* gsum, float* gsq,
    const float* __restrict__ aArr, const float* __restrict__ cArr,
    float* __restrict__ xout, float* __restrict__ xx) {
  constexpr int J = COUT / 64;
  int t = threadIdx.x, lane = t & 63, w = t >> 6;
  int bn = blockIdx.x * 4 + w;
  int b = bn >> 10;
  int myidx = 0;
  if (lane < KNN) myidx = idx[(size_t)bn * KNN + lane];
  float base[J], acc[J], acc2[J], av[J], cv[J], mx[J];
#pragma unroll
  for (int j = 0; j < J; ++j) {
    int o = lane + 64 * j;
    base[j] = Z[(size_t)bn * COUT + o] - Y[(size_t)bn * COUT + o];
    acc[j] = 0.f; acc2[j] = 0.f; mx[j] = -INFINITY;
    if (PASS == 1) { av[j] = aArr[o]; cv[j] = cArr[o]; }
  }
  for (int k = 0; k < KNN; ++k) {
    int nbr = __shfl(myidx, k);
    const float* yr = Y + ((size_t)(b << 10) + nbr) * COUT;
#pragma unroll
    for (int j = 0; j < J; ++j) {
      float v = yr[lane + 64 * j] + base[j];
      if (PASS == 0) { acc[j] += v; acc2[j] += v * v; }
      else {
        float u = av[j] * v + cv[j];
        u = u > 0.f ? u : 0.2f * u;
        mx[j] = fmaxf(mx[j], u);
      }
    }
  }
  if (PASS == 0) {
    int bkt = bn & 31;
#pragma unroll
    for (int j = 0; j < J; ++j) {
      atomicAdd(&gsum[bkt * 1024 + lane + 64 * j], acc[j]);
      atomicAdd(&gsq[bkt * 1024 + lane + 64 * j], acc2[j]);
    }
  } else {
    float s = 0.f;
#pragma unroll
    for (int j = 0; j < J; ++j) {
      xout[(size_t)bn * COUT + lane + 64 * j] = mx[j];
      if (WXX) s = fmaf(mx[j], mx[j], s);
    }
    if (WXX) {
      s = wave_sum(s);
      if (lane == 0) xx[bn] = s;
    }
  }
}

// ---------------- bn finalize: scale/shift from bucketed sums -------------
__global__ void k_bnfin(const float* gsum, const float* gsq,
                        const float* __restrict__ g, const float* __restrict__ bb,
                        float* aArr, float* cArr, int COUT, float Minv) {
  int ch = blockIdx.x * 256 + threadIdx.x;
  if (ch >= COUT) return;
  float S = 0, S2 = 0;
  for (int k = 0; k < 32; ++k) { S += gsum[k * 1024 + ch]; S2 += gsq[k * 1024 + ch]; }
  float mu = S * Minv;
  float var = S2 * Minv - mu * mu;
  float a = g[ch] / sqrtf(var + 1e-5f);
  aArr[ch] = a;
  cArr[ch] = bb[ch] - mu * a;
}

// ---------------- pack feat (x1|x2|x3|x4) + w5 -> bf16 --------------------
__global__ void k_pack(const float* __restrict__ x1, const float* __restrict__ x2,
                       const float* __restrict__ x3, const float* __restrict__ x4,
                       const float* __restrict__ w5,
                       unsigned short* __restrict__ fb,
                       unsigned short* __restrict__ wb) {
  int q = blockIdx.x * 256 + threadIdx.x;
  if (q < 1048576) {
    int e = q * 4;
    int row = e >> 9, c = e & 511;
    const float* src; int off, ld;
    if (c < 64) { src = x1; off = 0; ld = 64; }
    else if (c < 128) { src = x2; off = 64; ld = 64; }
    else if (c < 256) { src = x3; off = 128; ld = 128; }
    else { src = x4; off = 256; ld = 256; }
    float4 v = *(const float4*)(src + (size_t)row * ld + (c - off));
    ushort4 o;
    o.x = rne_bf16(v.x); o.y = rne_bf16(v.y); o.z = rne_bf16(v.z); o.w = rne_bf16(v.w);
    *(ushort4*)(fb + (size_t)row * 512 + c) = o;
  } else {
    int e = (q - 1048576) * 4;
    float4 v = *(const float4*)(w5 + e);
    ushort4 o;
    o.x = rne_bf16(v.x); o.y = rne_bf16(v.y); o.z = rne_bf16(v.z); o.w = rne_bf16(v.w);
    *(ushort4*)(wb + e) = o;
  }
}

// ---------------- final GEMM via MFMA bf16, fused stats + per-block max ---
__global__ __launch_bounds__(256) void k_fgemm3(
    const unsigned short* __restrict__ fb, const unsigned short* __restrict__ wb,
    float* gsum, float* gsq, float* __restrict__ pmax) {
  int t = threadIdx.x, lane = t & 63, w = t >> 6;
  int m0 = blockIdx.x * 128;
  int j0 = blockIdx.y * 64;
  int r16 = lane & 15, kg = lane >> 4;
  f32x4 acc[2][4];
#pragma unroll
  for (int mi = 0; mi < 2; ++mi)
#pragma unroll
    for (int nj = 0; nj < 4; ++nj) acc[mi][nj] = {0.f, 0.f, 0.f, 0.f};
  const unsigned short* pa0 = fb + (size_t)(m0 + w * 32 + r16) * 512 + kg * 8;
  const unsigned short* pa1 = pa0 + 16 * 512;
  const unsigned short* pb0 = wb + (size_t)(j0 + r16) * 512 + kg * 8;
#pragma unroll 2
  for (int k0 = 0; k0 < 512; k0 += 32) {
    s8v a0 = *(const s8v*)(pa0 + k0);
    s8v a1 = *(const s8v*)(pa1 + k0);
    s8v b0 = *(const s8v*)(pb0 + k0);
    s8v b1 = *(const s8v*)(pb0 + 16 * 512 + k0);
    s8v b2 = *(const s8v*)(pb0 + 32 * 512 + k0);
    s8v b3 = *(const s8v*)(pb0 + 48 * 512 + k0);
    acc[0][0] = __builtin_amdgcn_mfma_f32_16x16x32_bf16(a0, b0, acc[0][0], 0, 0, 0);
    acc[0][1] = __builtin_amdgcn_mfma_f32_16x16x32_bf16(a0, b1, acc[0][1], 0, 0, 0);
    acc[0][2] = __builtin_amdgcn_mfma_f32_16x16x32_bf16(a0, b2, acc[0][2], 0, 0, 0);
    acc[0][3] = __builtin_amdgcn_mfma_f32_16x16x32_bf16(a0, b3, acc[0][3], 0, 0, 0);
    acc[1][0] = __builtin_amdgcn_mfma_f32_16x16x32_bf16(a1, b0, acc[1][0], 0, 0, 0);
    acc[1][1] = __builtin_amdgcn_mfma_f32_16x16x32_bf16(a1, b1, acc[1][1], 0, 0, 0);
    acc[1][2] = __builtin_amdgcn_mfma_f32_16x16x32_bf16(a1, b2, acc[1][2], 0, 0, 0);
    acc[1][3] = __builtin_amdgcn_mfma_f32_16x16x32_bf16(a1, b3, acc[1][3], 0, 0, 0);
  }
  float s[4], s2[4], mx[4];
#pragma unroll
  for (int nj = 0; nj < 4; ++nj) {
    s[nj] = 0.f; s2[nj] = 0.f; mx[nj] = -INFINITY;
#pragma unroll
    for (int mi = 0; mi < 2; ++mi)
#pragma unroll
      for (int r = 0; r < 4; ++r) {
        float v = acc[mi][nj][r];
        s[nj] += v; s2[nj] += v * v; mx[nj] = fmaxf(mx[nj], v);
      }
    s[nj] += __shfl_xor(s[nj], 16, 64);  s[nj] += __shfl_xor(s[nj], 32, 64);
    s2[nj] += __shfl_xor(s2[nj], 16, 64); s2[nj] += __shfl_xor(s2[nj], 32, 64);
    mx[nj] = fmaxf(mx[nj], __shfl_xor(mx[nj], 16, 64));
    mx[nj] = fmaxf(mx[nj], __shfl_xor(mx[nj], 32, 64));
  }
  __shared__ float wsum[4][64], wsq[4][64], wmax[4][64];
  if (lane < 16) {
#pragma unroll
    for (int nj = 0; nj < 4; ++nj) {
      wsum[w][nj * 16 + lane] = s[nj];
      wsq[w][nj * 16 + lane] = s2[nj];
      wmax[w][nj * 16 + lane] = mx[nj];
    }
  }
  __syncthreads();
  if (t < 64) {
    float S = 0.f, S2 = 0.f, MX = -INFINITY;
#pragma unroll
    for (int ww = 0; ww < 4; ++ww) {
      S += wsum[ww][t]; S2 += wsq[ww][t]; MX = fmaxf(MX, wmax[ww][t]);
    }
    int o = j0 + t;
    int bkt = blockIdx.x & 31;
    atomicAdd(&gsum[bkt * 1024 + o], S);
    atomicAdd(&gsq[bkt * 1024 + o], S2);
    pmax[(size_t)(blockIdx.x & 7) * 8192 + (blockIdx.x >> 3) * 1024 + o] = MX;
  }
}

// final: bn + leaky over per-chunk maxes (a>0 so affine+leaky commutes w/ max)
__global__ void k_fmax2(const float* __restrict__ pmax,
                        const float* __restrict__ aArr,
                        const float* __restrict__ cArr, float* __restrict__ out) {
  int j = blockIdx.x * 256 + threadIdx.x;  // 0..8191
  int o = j & 1023;
  float mx = -INFINITY;
#pragma unroll
  for (int c = 0; c < 8; ++c) mx = fmaxf(mx, pmax[c * 8192 + j]);
  float v = aArr[o] * mx + cArr[o];
  v = v > 0.f ? v : 0.2f * v;
  out[j] = v;
}

// ---------------- launch ----------------
extern "C" void kernel_launch(void* const* d_in, const int* in_sizes, int n_in,
                              void* d_out, int out_size, void* d_ws,
                              size_t ws_size, hipStream_t stream) {
  const float* x  = (const float*)d_in[0];
  const float* w1 = (const float*)d_in[1];
  const float* w2 = (const float*)d_in[2];
  const float* g2 = (const float*)d_in[3];
  const float* b2 = (const float*)d_in[4];
  const float* w3 = (const float*)d_in[5];
  const float* g3 = (const float*)d_in[6];
  const float* b3 = (const float*)d_in[7];
  const float* w4 = (const float*)d_in[8];
  const float* g4 = (const float*)d_in[9];
  const float* b4 = (const float*)d_in[10];
  const float* w5 = (const float*)d_in[11];
  const float* g5 = (const float*)d_in[12];
  const float* b5 = (const float*)d_in[13];

  float* W = (float*)d_ws;
  float* xt = W;                        // 24576
  float* xp = W + 24576;                // 24576
  float* xx = W + 49152;                // 8192
  float* stats = W + 57344;             // arena: 4 stages x (gsum|gsq) + tail
  // stage s: gsum = stats + s*65536, gsq = gsum + 32768
  float* aArr = stats + 262144;         // 1024
  float* cArr = stats + 263168;         // 1024
  float* mu64 = stats + 264192;         // 64
  float* invv = stats + 264256;         // 64 (1 used)
  float* mom  = stats + 264320;         // 27*16 = 432 (pad to 512)
  // arena ends at stats + 264832 = W + 322176
  float* x1 = W + 323584;               // 8192*64
  float* x2 = W + 847872;               // 8192*64
  float* x3 = W + 1372160;              // 8192*128 (reused as pmax)
  float* x4 = W + 2420736;              // 8192*256
  float* pd = W + 4517888;              // 8388608 (fgeo / Y|Z / featb+w5b alias)
  float* Y  = pd;
  float* Z  = pd + 2097152;
  float* fgeo = pd;                     // 6*163840 = 983040
  int* idx = (int*)(W + 12906496);      // 163840 ints
  unsigned short* featb = (unsigned short*)pd;              // 8192*512 bf16
  unsigned short* w5b   = (unsigned short*)(pd + 2097152);  // 1024*512 bf16
  float* pmax = x3;
  float* out = (float*)d_out;

  const float MinvE = 1.f / (float)(BN_ * KNN);
  float* gs0 = stats;           float* gq0 = stats + 32768;
  float* gs1 = stats + 65536;   float* gq1 = stats + 98304;
  float* gs2 = stats + 131072;  float* gq2 = stats + 163840;
  float* gs3 = stats + 196608;  float* gq3 = stats + 229376;

  // one arena clear for all stages + moments
  hipMemsetAsync(stats, 0, 264832 * sizeof(float), stream);

  // prep + hyper block
  k_prep<<<32, 256, 0, stream>>>(x, xt, xp);
  k_knn3w<<<2048, 256, 0, stream>>>(xt, idx);
  k_hgeom<<<640, 256, 0, stream>>>(xp, idx, fgeo, mom);
  k_hfin2<<<1, 64, 0, stream>>>(mom, w1, mu64, invv);
  k_hyper_x1<<<2048, 256, 0, stream>>>(fgeo, w1, mu64, invv, x1, xx);

  // edge block 2: x1(64) -> x2(64)
  k_pd2<64><<<dim3(16, 16, 8), 256, 0, stream>>>(x1, xx, pd);
  k_topkw<<<2048, 256, 0, stream>>>(pd, idx);
  k_xw2<64, 64><<<dim3(128, 2), 256, 0, stream>>>(x1, w2, Y, Z);
  k_gather<64, 0, false><<<2048, 256, 0, stream>>>(Y, Z, idx, gs0, gq0, aArr, cArr, x2, xx);
  k_bnfin<<<1, 256, 0, stream>>>(gs0, gq0, g2, b2, aArr, cArr, 64, MinvE);
  k_gather<64, 1, true><<<2048, 256, 0, stream>>>(Y, Z, idx, gs0, gq0, aArr, cArr, x2, xx);

  // edge block 3: x2(64) -> x3(128)
  k_pd2<64><<<dim3(16, 16, 8), 256, 0, stream>>>(x2, xx, pd);
  k_topkw<<<2048, 256, 0, stream>>>(pd, idx);
  k_xw2<64, 128><<<dim3(128, 4), 256, 0, stream>>>(x2, w3, Y, Z);
  k_gather<128, 0, false><<<2048, 256, 0, stream>>>(Y, Z, idx, gs1, gq1, aArr, cArr, x3, xx);
  k_bnfin<<<1, 256, 0, stream>>>(gs1, gq1, g3, b3, aArr, cArr, 128, MinvE);
  k_gather<128, 1, true><<<2048, 256, 0, stream>>>(Y, Z, idx, gs1, gq1, aArr, cArr, x3, xx);

  // edge block 4: x3(128) -> x4(256)
  k_pd2<128><<<dim3(16, 16, 8), 256, 0, stream>>>(x3, xx, pd);
  k_topkw<<<2048, 256, 0, stream>>>(pd, idx);
  k_xw2<128, 256><<<dim3(128, 8), 256, 0, stream>>>(x3, w4, Y, Z);
  k_gather<256, 0, false><<<2048, 256, 0, stream>>>(Y, Z, idx, gs2, gq2, aArr, cArr, x4, xx);
  k_bnfin<<<1, 256, 0, stream>>>(gs2, gq2, g4, b4, aArr, cArr, 256, MinvE);
  k_gather<256, 1, false><<<2048, 256, 0, stream>>>(Y, Z, idx, gs2, gq2, aArr, cArr, x4, xx);

  // pack bf16 operands (pd/Y/Z region is dead now)
  k_pack<<<4608, 256, 0, stream>>>(x1, x2, x3, x4, w5, featb, w5b);

  // final: MFMA GEMM w/ fused stats+max, then bn+leaky+reduce
  k_fgemm3<<<dim3(64, 16), 256, 0, stream>>>(featb, w5b, gs3, gq3, pmax);
  k_bnfin<<<4, 256, 0, stream>>>(gs3, gq3, g5, b5, aArr, cArr, 1024, 1.f / (float)BN_);
  k_fmax2<<<32, 256, 0, stream>>>(pmax, aArr, cArr, out);
}

// Round 7
// 540.306 us; speedup vs baseline: 14.0864x; 1.0081x over previous
//
#include <hip/hip_runtime.h>
#include <math.h>

#define KNN 20
constexpr int B_ = 8, N_ = 1024, BN_ = B_ * N_;
constexpr int NEDGE = BN_ * KNN;  // 163840

using f32x4 = __attribute__((ext_vector_type(4))) float;
using s8v = __attribute__((ext_vector_type(8))) short;

// ---------------- helpers ----------------
__device__ __forceinline__ float wave_sum(float v) {
#pragma unroll
  for (int off = 32; off >= 1; off >>= 1) v += __shfl_xor(v, off, 64);
  return v;
}

__device__ __forceinline__ unsigned sortable(float f) {
  unsigned u = __float_as_uint(f);
  return u ^ ((u & 0x80000000u) ? 0xFFFFFFFFu : 0x80000000u);
}

__device__ __forceinline__ unsigned short rne_bf16(float f) {
  unsigned u = __float_as_uint(f);
  unsigned r = (u + 0x7FFFu + ((u >> 16) & 1u)) >> 16;
  return (unsigned short)r;
}

// Wave-per-row top-K extraction (jax.lax.top_k tie rule: value desc, index asc).
__device__ __forceinline__ void topk_extract(unsigned (&key)[16], int lane,
                                             int* __restrict__ out) {
  for (int sel = 0; sel < KNN; ++sel) {
    unsigned bk = key[0]; int bs = 0;
#pragma unroll
    for (int s = 1; s < 16; ++s)
      if (key[s] > bk) { bk = key[s]; bs = s; }
    int bm = lane + (bs << 6);
#pragma unroll
    for (int off = 32; off >= 1; off >>= 1) {
      unsigned ok = __shfl_xor(bk, off, 64);
      int om = __shfl_xor(bm, off, 64);
      if (ok > bk || (ok == bk && om < bm)) { bk = ok; bm = om; }
    }
    if (lane == 0) out[sel] = bm;
    if ((bm & 63) == lane) {
      int ws_ = bm >> 6;
#pragma unroll
      for (int s = 0; s < 16; ++s)
        if (s == ws_) key[s] = 0u;
    }
  }
}

// ---------------- prep: transpose + expmap0 ----------------
__global__ void k_prep(const float* __restrict__ x, float* __restrict__ xt,
                       float* __restrict__ xp) {
  int i = blockIdx.x * 256 + threadIdx.x;  // 0..8191
  int b = i >> 10, n = i & 1023;
  float v0 = x[(b * 3 + 0) * N_ + n];
  float v1 = x[(b * 3 + 1) * N_ + n];
  float v2 = x[(b * 3 + 2) * N_ + n];
  xt[i * 3 + 0] = v0; xt[i * 3 + 1] = v1; xt[i * 3 + 2] = v2;
  float nsq = v0 * v0 + v1 * v1 + v2 * v2;
  float nn = sqrtf(fmaxf(nsq, 1e-15f));
  float s = tanhf(0.1f * nn) / (0.1f * nn);
  xp[i * 3 + 0] = s * v0; xp[i * 3 + 1] = s * v1; xp[i * 3 + 2] = s * v2;
}

// ---------------- knn in 3-d: wave per row, extraction top-k ---------------
__global__ __launch_bounds__(256) void k_knn3w(const float* __restrict__ xt,
                                               int* __restrict__ idx) {
  __shared__ float4 pts4[N_];
  int t = threadIdx.x;
  int row0 = blockIdx.x * 4;
  int b = row0 >> 10;
  const float* xb = xt + (size_t)b * 3 * N_;
  for (int i = t; i < N_; i += 256) {
    float px = xb[3 * i], py = xb[3 * i + 1], pz = xb[3 * i + 2];
    pts4[i] = make_float4(px, py, pz, px * px + py * py + pz * pz);
  }
  __syncthreads();
  int lane = t & 63, w = t >> 6;
  int row = row0 + w, rl = row & 1023;
  float4 c = pts4[rl];
  unsigned key[16];
#pragma unroll
  for (int s = 0; s < 16; ++s) {
    int m = lane + 64 * s;
    float4 q = pts4[m];
    float dot = c.x * q.x + c.y * q.y + c.z * q.z;
    float v = 2.f * dot - c.w - q.w;
    key[s] = sortable(v);
  }
  topk_extract(key, lane, idx + (size_t)row * KNN);
}

// ---------------- top-20 of a pd row: wave per row ----------------
__global__ __launch_bounds__(256) void k_topkw(const float* __restrict__ pd,
                                               int* __restrict__ idx) {
  int t = threadIdx.x, lane = t & 63, w = t >> 6;
  int row = blockIdx.x * 4 + w;
  const float* rp = pd + (size_t)row * N_;
  unsigned key[16];
#pragma unroll
  for (int s = 0; s < 16; ++s) key[s] = sortable(rp[lane + 64 * s]);
  topk_extract(key, lane, idx + (size_t)row * KNN);
}

// ---------------- hyper geometry per edge + moment accumulation -----------
__global__ __launch_bounds__(256) void k_hgeom(const float* __restrict__ xp,
                                               const int* __restrict__ idx,
                                               float* __restrict__ fgeo,
                                               float* __restrict__ mom) {
  int e = blockIdx.x * 256 + threadIdx.x;  // 0..163839
  int gw = e / KNN;
  int b = gw >> 10;
  int nbr = idx[e];
  const float* pc = xp + (size_t)gw * 3;
  float c0 = pc[0], c1 = pc[1], c2 = pc[2];
  const float* pn = xp + ((size_t)(b << 10) + nbr) * 3;
  float a0 = pn[0], a1 = pn[1], a2 = pn[2];
  float x2 = a0 * a0 + a1 * a1 + a2 * a2;
  float y2 = c0 * c0 + c1 * c1 + c2 * c2;
  float xy = -(a0 * c0 + a1 * c1 + a2 * c2);
  float f1 = 1.f + 0.02f * xy + 0.01f * y2;
  float f2 = 1.f - 0.01f * x2;
  float den = 1.f + 0.02f * xy + 0.0001f * x2 * y2;
  float rden = 1.f / fmaxf(den, 1e-15f);
  float m0 = (f1 * a0 - f2 * c0) * rden;
  float m1 = (f1 * a1 - f2 * c1) * rden;
  float m2 = (f1 * a2 - f2 * c2) * rden;
  float nsq = m0 * m0 + m1 * m1 + m2 * m2 + y2;
  float nn = sqrtf(fmaxf(nsq, 1e-15f));
  float sn = 0.1f * nn;
  float tt = fminf(sn, 1.f - 1e-7f);
  float s = atanhf(tt) / sn;
  float f[6] = {s * m0, s * m1, s * m2, s * c0, s * c1, s * c2};
#pragma unroll
  for (int j = 0; j < 6; ++j) fgeo[j * NEDGE + e] = f[j];
  float mm[27];
  {
    int q = 0;
#pragma unroll
    for (int i = 0; i < 6; ++i) mm[q++] = f[i];
#pragma unroll
    for (int i = 0; i < 6; ++i)
#pragma unroll
      for (int j = i; j < 6; ++j) mm[q++] = f[i] * f[j];
  }
#pragma unroll
  for (int m = 0; m < 27; ++m) mm[m] = wave_sum(mm[m]);
  __shared__ float part[4][27];
  int lane = threadIdx.x & 63, w = threadIdx.x >> 6;
  if (lane == 0) {
#pragma unroll
    for (int m = 0; m < 27; ++m) part[w][m] = mm[m];
  }
  __syncthreads();
  int t = threadIdx.x;
  if (t < 27) {
    float v = part[0][t] + part[1][t] + part[2][t] + part[3][t];
    atomicAdd(&mom[t * 16 + (blockIdx.x & 15)], v);
  }
}

// mu[ch] = w1[ch].fbar ; var = sum_ch (w1[ch]^T M w1[ch] - mu^2)
__global__ void k_hfin2(const float* __restrict__ mom,
                        const float* __restrict__ w1, float* mu64,
                        float* invv) {
  __shared__ float M[27];
  int t = threadIdx.x;  // 64
  if (t < 27) {
    float s = 0.f;
    for (int k = 0; k < 16; ++k) s += mom[t * 16 + k];
    M[t] = s * (1.f / (float)NEDGE);
  }
  __syncthreads();
  float w1r[6];
#pragma unroll
  for (int j = 0; j < 6; ++j) w1r[j] = w1[t * 6 + j];
  float mu = 0.f;
#pragma unroll
  for (int j = 0; j < 6; ++j) mu = fmaf(w1r[j], M[j], mu);
  float q = 0.f;
  {
    int off = 6;
#pragma unroll
    for (int i = 0; i < 6; ++i) {
      q = fmaf(w1r[i] * w1r[i], M[off], q); ++off;
#pragma unroll
      for (int j = i + 1; j < 6; ++j) {
        q = fmaf(2.f * w1r[i] * w1r[j], M[off], q); ++off;
      }
    }
  }
  float varc = q - mu * mu;
  float var = wave_sum(varc);
  mu64[t] = mu;
  if (t == 0) invv[0] = 1.f / sqrtf(var + 1e-5f);
}

// ---------------- hyper x1: matvec + BN + leaky + expmap/max/logmap -------
// emits x1 fp32, xx row-norms, and bf16 featb cols 0..63
__global__ __launch_bounds__(256) void k_hyper_x1(
    const float* __restrict__ fgeo, const float* __restrict__ w1,
    const float* __restrict__ mu64, const float* __restrict__ invv,
    float* __restrict__ x1, float* __restrict__ xx,
    unsigned short* __restrict__ fb) {
  int t = threadIdx.x, lane = t & 63, w = t >> 6;
  int gw = blockIdx.x * 4 + w;
  float w1r[6];
#pragma unroll
  for (int j = 0; j < 6; ++j) w1r[j] = w1[lane * 6 + j];
  float f[6] = {0.f, 0.f, 0.f, 0.f, 0.f, 0.f};
  if (lane < KNN) {
    int e = gw * KNN + lane;
#pragma unroll
    for (int j = 0; j < 6; ++j) f[j] = fgeo[j * NEDGE + e];
  }
  float mu = mu64[lane];
  float inv = invv[0];
  float mx = -INFINITY;
  for (int k = 0; k < KNN; ++k) {
    float u = 0.f;
#pragma unroll
    for (int j = 0; j < 6; ++j) u = fmaf(w1r[j], __shfl(f[j], k), u);
    float vv = (u - mu) * inv;
    float l = vv > 0.f ? vv : 0.2f * vv;
    float nsq = wave_sum(l * l);
    float nn = sqrtf(fmaxf(nsq, 1e-15f));
    float sn = 0.1f * nn;
    float sc = tanhf(sn) / sn;
    mx = fmaxf(mx, sc * l);
  }
  float msq = wave_sum(mx * mx);
  float mn = sqrtf(fmaxf(msq, 1e-15f));
  float sn = 0.1f * mn;
  float tt = fminf(sn, 1.f - 1e-7f);
  float val = atanhf(tt) / sn * mx;
  x1[(size_t)gw * 64 + lane] = val;
  fb[(size_t)gw * 512 + lane] = rne_bf16(val);
  float xs = wave_sum(val * val);
  if (lane == 0) xx[gw] = xs;
}

// ---- fp32 GEMM tile core: LDS transposed [k][row] stride 68, b128 reads ----
__device__ __forceinline__ void load_t68(float (&Lt)[64][68],
                                         const float* __restrict__ src,
                                         int ldr, int t) {
  int row = t >> 2, kq = (t & 3) * 16;
  const float* p = src + (size_t)row * ldr + kq;
  float4 v0 = *(const float4*)(p);
  float4 v1 = *(const float4*)(p + 4);
  float4 v2 = *(const float4*)(p + 8);
  float4 v3 = *(const float4*)(p + 12);
  Lt[kq + 0][row] = v0.x;  Lt[kq + 1][row] = v0.y;
  Lt[kq + 2][row] = v0.z;  Lt[kq + 3][row] = v0.w;
  Lt[kq + 4][row] = v1.x;  Lt[kq + 5][row] = v1.y;
  Lt[kq + 6][row] = v1.z;  Lt[kq + 7][row] = v1.w;
  Lt[kq + 8][row] = v2.x;  Lt[kq + 9][row] = v2.y;
  Lt[kq + 10][row] = v2.z; Lt[kq + 11][row] = v2.w;
  Lt[kq + 12][row] = v3.x; Lt[kq + 13][row] = v3.y;
  Lt[kq + 14][row] = v3.z; Lt[kq + 15][row] = v3.w;
}

// ---------------- pairwise pd = 2 x.y - |x|^2 - |y|^2 (fp32!) -------------
template <int CIN>
__global__ __launch_bounds__(256) void k_pd2(const float* __restrict__ xin,
                                             const float* __restrict__ xx,
                                             float* __restrict__ pd) {
  __shared__ float At[64][68], Bt[64][68];
  int b = blockIdx.z;
  int n0 = blockIdx.x * 64, m0 = blockIdx.y * 64;
  int t = threadIdx.x;
  int tr4 = (t >> 4) * 4, tc4 = (t & 15) * 4;
  float acc[4][4] = {};
  const float* xb = xin + (size_t)b * N_ * CIN;
  for (int c0 = 0; c0 < CIN; c0 += 64) {
    if (c0) __syncthreads();
    load_t68(At, xb + (size_t)n0 * CIN + c0, CIN, t);
    load_t68(Bt, xb + (size_t)m0 * CIN + c0, CIN, t);
    __syncthreads();
#pragma unroll 4
    for (int k = 0; k < 64; ++k) {
      float4 a = *(const float4*)&At[k][tr4];
      float4 bb = *(const float4*)&Bt[k][tc4];
      float av[4] = {a.x, a.y, a.z, a.w};
      float bv[4] = {bb.x, bb.y, bb.z, bb.w};
#pragma unroll
      for (int ii = 0; ii < 4; ++ii)
#pragma unroll
        for (int jj = 0; jj < 4; ++jj) acc[ii][jj] = fmaf(av[ii], bv[jj], acc[ii][jj]);
    }
  }
  const float* xxn = xx + b * N_;
#pragma unroll
  for (int ii = 0; ii < 4; ++ii) {
    int r = n0 + tr4 + ii;
#pragma unroll
    for (int jj = 0; jj < 4; ++jj) {
      int c = m0 + tc4 + jj;
      pd[((size_t)b * N_ + r) * N_ + c] = 2.f * acc[ii][jj] - xxn[r] - xxn[c];
    }
  }
}

// ---------------- per-point linear maps: Y = X wA^T, Z = X wB^T ----------
template <int CIN, int COUT>
__global__ __launch_bounds__(256) void k_xw2(const float* __restrict__ xin,
                                             const float* __restrict__ w,
                                             float* __restrict__ Y,
                                             float* __restrict__ Z) {
  __shared__ float At[64][68], Bt[64][68];
  int n0 = blockIdx.x * 64;
  int j0 = blockIdx.y * 64;
  float* outp; int obase, coff;
  if (j0 < COUT) { outp = Y; obase = j0; coff = 0; }
  else { outp = Z; obase = j0 - COUT; coff = CIN; }
  int t = threadIdx.x;
  int tr4 = (t >> 4) * 4, tc4 = (t & 15) * 4;
  float acc[4][4] = {};
  for (int c0 = 0; c0 < CIN; c0 += 64) {
    if (c0) __syncthreads();
    load_t68(At, xin + (size_t)n0 * CIN + c0, CIN, t);
    load_t68(Bt, w + (size_t)obase * (2 * CIN) + coff + c0, 2 * CIN, t);
    __syncthreads();
#pragma unroll 4
    for (int k = 0; k < 64; ++k) {
      float4 a = *(const float4*)&At[k][tr4];
      float4 bb = *(const float4*)&Bt[k][tc4];
      float av[4] = {a.x, a.y, a.z, a.w};
      float bv[4] = {bb.x, bb.y, bb.z, bb.w};
#pragma unroll
      for (int ii = 0; ii < 4; ++ii)
#pragma unroll
        for (int jj = 0; jj < 4; ++jj) acc[ii][jj] = fmaf(av[ii], bv[jj], acc[ii][jj]);
    }
  }
#pragma unroll
  for (int ii = 0; ii < 4; ++ii)
#pragma unroll
    for (int jj = 0; jj < 4; ++jj)
      outp[(size_t)(n0 + tr4 + ii) * COUT + obase + tc4 + jj] = acc[ii][jj];
}

// ---------------- single-pass gather: BN stats + raw per-point max --------
// v[bn,k,o] = Y[nbr,o] - Y[bn,o] + Z[bn,o]; stores max_k v (BN+leaky applied later:
// a>0 and leaky monotone => commute with max)
template <int COUT>
__global__ __launch_bounds__(256) void k_gather2(
    const float* __restrict__ Y, const float* __restrict__ Z,
    const int* __restrict__ idx, float* gsum, float* gsq,
    float* __restrict__ xout) {
  constexpr int J = COUT / 64;
  int t = threadIdx.x, lane = t & 63, w = t >> 6;
  int bn = blockIdx.x * 4 + w;
  int b = bn >> 10;
  int myidx = 0;
  if (lane < KNN) myidx = idx[(size_t)bn * KNN + lane];
  float base[J], acc[J], acc2[J], mx[J];
#pragma unroll
  for (int j = 0; j < J; ++j) {
    int o = lane + 64 * j;
    base[j] = Z[(size_t)bn * COUT + o] - Y[(size_t)bn * COUT + o];
    acc[j] = 0.f; acc2[j] = 0.f; mx[j] = -INFINITY;
  }
  for (int k = 0; k < KNN; ++k) {
    int nbr = __shfl(myidx, k);
    const float* yr = Y + ((size_t)(b << 10) + nbr) * COUT;
#pragma unroll
    for (int j = 0; j < J; ++j) {
      float v = yr[lane + 64 * j] + base[j];
      acc[j] += v; acc2[j] += v * v; mx[j] = fmaxf(mx[j], v);
    }
  }
  int bkt = bn & 31;
#pragma unroll
  for (int j = 0; j < J; ++j) {
    atomicAdd(&gsum[bkt * 1024 + lane + 64 * j], acc[j]);
    atomicAdd(&gsq[bkt * 1024 + lane + 64 * j], acc2[j]);
    xout[(size_t)bn * COUT + lane + 64 * j] = mx[j];
  }
}

// ---------------- elementwise BN+leaky apply + bf16 featb pack ------------
template <int COUT, bool WXX, bool WOUT>
__global__ void k_apply(float* __restrict__ xio,
                        const float* __restrict__ aArr,
                        const float* __restrict__ cArr,
                        unsigned short* __restrict__ fb, int coloff,
                        float* __restrict__ xx) {
  constexpr int J = COUT / 64;
  int t = threadIdx.x, lane = t & 63, w = t >> 6;
  int bn = blockIdx.x * 4 + w;
  float s = 0.f;
#pragma unroll
  for (int j = 0; j < J; ++j) {
    int o = lane + 64 * j;
    float v = xio[(size_t)bn * COUT + o];
    float u = aArr[o] * v + cArr[o];
    u = u > 0.f ? u : 0.2f * u;
    if (WOUT) xio[(size_t)bn * COUT + o] = u;
    fb[(size_t)bn * 512 + coloff + o] = rne_bf16(u);
    if (WXX) s = fmaf(u, u, s);
  }
  if (WXX) {
    s = wave_sum(s);
    if (lane == 0) xx[bn] = s;
  }
}

// ---------------- bn finalize: scale/shift from bucketed sums -------------
__global__ void k_bnfin(const float* gsum, const float* gsq,
                        const float* __restrict__ g, const float* __restrict__ bb,
                        float* aArr, float* cArr, int COUT, float Minv) {
  int ch = blockIdx.x * 256 + threadIdx.x;
  if (ch >= COUT) return;
  float S = 0, S2 = 0;
  for (int k = 0; k < 32; ++k) { S += gsum[k * 1024 + ch]; S2 += gsq[k * 1024 + ch]; }
  float mu = S * Minv;
  float var = S2 * Minv - mu * mu;
  float a = g[ch] / sqrtf(var + 1e-5f);
  aArr[ch] = a;
  cArr[ch] = bb[ch] - mu * a;
}

// ---------------- fp32 -> bf16 straight convert (w5) ----------------
__global__ void k_cvt(const float* __restrict__ src,
                      unsigned short* __restrict__ dst) {
  int e = (blockIdx.x * 256 + threadIdx.x) * 4;
  float4 v = *(const float4*)(src + e);
  ushort4 o;
  o.x = rne_bf16(v.x); o.y = rne_bf16(v.y); o.z = rne_bf16(v.z); o.w = rne_bf16(v.w);
  *(ushort4*)(dst + e) = o;
}

// ---------------- final GEMM via MFMA bf16: LDS-staged B, prefetched A ----
// C[8192][1024] = featb @ w5b^T; fused bucketed stats + per-block max; no C store.
__global__ __launch_bounds__(256) void k_fgemm3(
    const unsigned short* __restrict__ fb, const unsigned short* __restrict__ wb,
    float* gsum, float* gsq, float* __restrict__ pmax) {
  __shared__ unsigned short Bs[64][264];  // 64 cols x 256 k, +8 pad (2-way banks)
  int t = threadIdx.x, lane = t & 63, w = t >> 6;
  int m0 = blockIdx.x * 128;
  int j0 = blockIdx.y * 64;
  int r16 = lane & 15, kg = lane >> 4;
  f32x4 acc[2][4];
#pragma unroll
  for (int mi = 0; mi < 2; ++mi)
#pragma unroll
    for (int nj = 0; nj < 4; ++nj) acc[mi][nj] = {0.f, 0.f, 0.f, 0.f};
  const unsigned short* pa0 = fb + (size_t)(m0 + w * 32 + r16) * 512 + kg * 8;
  const unsigned short* pa1 = pa0 + 16 * 512;
  s8v a0 = *(const s8v*)pa0;
  s8v a1 = *(const s8v*)pa1;
  int kglob = 0;
  for (int kh = 0; kh < 2; ++kh) {
    if (kh) __syncthreads();
#pragma unroll
    for (int it = 0; it < 8; ++it) {
      int chunk = it * 256 + t;
      int row = chunk >> 5;            // 32 chunks (of 8 elems) per row
      int kc = (chunk & 31) * 8;
      *(s8v*)&Bs[row][kc] =
          *(const s8v*)(wb + (size_t)(j0 + row) * 512 + kh * 256 + kc);
    }
    __syncthreads();
#pragma unroll
    for (int ki = 0; ki < 8; ++ki) {
      s8v na0 = a0, na1 = a1;
      int knext = kglob + 32;
      if (knext < 512) {
        na0 = *(const s8v*)(pa0 + knext);
        na1 = *(const s8v*)(pa1 + knext);
      }
      int kl = ki * 32 + kg * 8;
      s8v b0 = *(const s8v*)&Bs[r16][kl];
      s8v b1 = *(const s8v*)&Bs[r16 + 16][kl];
      s8v b2 = *(const s8v*)&Bs[r16 + 32][kl];
      s8v b3 = *(const s8v*)&Bs[r16 + 48][kl];
      acc[0][0] = __builtin_amdgcn_mfma_f32_16x16x32_bf16(a0, b0, acc[0][0], 0, 0, 0);
      acc[0][1] = __builtin_amdgcn_mfma_f32_16x16x32_bf16(a0, b1, acc[0][1], 0, 0, 0);
      acc[0][2] = __builtin_amdgcn_mfma_f32_16x16x32_bf16(a0, b2, acc[0][2], 0, 0, 0);
      acc[0][3] = __builtin_amdgcn_mfma_f32_16x16x32_bf16(a0, b3, acc[0][3], 0, 0, 0);
      acc[1][0] = __builtin_amdgcn_mfma_f32_16x16x32_bf16(a1, b0, acc[1][0], 0, 0, 0);
      acc[1][1] = __builtin_amdgcn_mfma_f32_16x16x32_bf16(a1, b1, acc[1][1], 0, 0, 0);
      acc[1][2] = __builtin_amdgcn_mfma_f32_16x16x32_bf16(a1, b2, acc[1][2], 0, 0, 0);
      acc[1][3] = __builtin_amdgcn_mfma_f32_16x16x32_bf16(a1, b3, acc[1][3], 0, 0, 0);
      a0 = na0; a1 = na1; kglob = knext;
    }
  }
  float s[4], s2[4], mx[4];
#pragma unroll
  for (int nj = 0; nj < 4; ++nj) {
    s[nj] = 0.f; s2[nj] = 0.f; mx[nj] = -INFINITY;
#pragma unroll
    for (int mi = 0; mi < 2; ++mi)
#pragma unroll
      for (int r = 0; r < 4; ++r) {
        float v = acc[mi][nj][r];
        s[nj] += v; s2[nj] += v * v; mx[nj] = fmaxf(mx[nj], v);
      }
    s[nj] += __shfl_xor(s[nj], 16, 64);  s[nj] += __shfl_xor(s[nj], 32, 64);
    s2[nj] += __shfl_xor(s2[nj], 16, 64); s2[nj] += __shfl_xor(s2[nj], 32, 64);
    mx[nj] = fmaxf(mx[nj], __shfl_xor(mx[nj], 16, 64));
    mx[nj] = fmaxf(mx[nj], __shfl_xor(mx[nj], 32, 64));
  }
  __shared__ float wsum[4][64], wsq[4][64], wmax[4][64];
  if (lane < 16) {
#pragma unroll
    for (int nj = 0; nj < 4; ++nj) {
      wsum[w][nj * 16 + lane] = s[nj];
      wsq[w][nj * 16 + lane] = s2[nj];
      wmax[w][nj * 16 + lane] = mx[nj];
    }
  }
  __syncthreads();
  if (t < 64) {
    float S = 0.f, S2 = 0.f, MX = -INFINITY;
#pragma unroll
    for (int ww = 0; ww < 4; ++ww) {
      S += wsum[ww][t]; S2 += wsq[ww][t]; MX = fmaxf(MX, wmax[ww][t]);
    }
    int o = j0 + t;
    int bkt = blockIdx.x & 31;
    atomicAdd(&gsum[bkt * 1024 + o], S);
    atomicAdd(&gsq[bkt * 1024 + o], S2);
    pmax[(size_t)(blockIdx.x & 7) * 8192 + (blockIdx.x >> 3) * 1024 + o] = MX;
  }
}

// final: bn + leaky over per-chunk maxes (a>0 so affine+leaky commutes w/ max)
__global__ void k_fmax2(const float* __restrict__ pmax,
                        const float* __restrict__ aArr,
                        const float* __restrict__ cArr, float* __restrict__ out) {
  int j = blockIdx.x * 256 + threadIdx.x;  // 0..8191
  int o = j & 1023;
  float mx = -INFINITY;
#pragma unroll
  for (int c = 0; c < 8; ++c) mx = fmaxf(mx, pmax[c * 8192 + j]);
  float v = aArr[o] * mx + cArr[o];
  v = v > 0.f ? v : 0.2f * v;
  out[j] = v;
}

// ---------------- launch ----------------
extern "C" void kernel_launch(void* const* d_in, const int* in_sizes, int n_in,
                              void* d_out, int out_size, void* d_ws,
                              size_t ws_size, hipStream_t stream) {
  const float* x  = (const float*)d_in[0];
  const float* w1 = (const float*)d_in[1];
  const float* w2 = (const float*)d_in[2];
  const float* g2 = (const float*)d_in[3];
  const float* b2 = (const float*)d_in[4];
  const float* w3 = (const float*)d_in[5];
  const float* g3 = (const float*)d_in[6];
  const float* b3 = (const float*)d_in[7];
  const float* w4 = (const float*)d_in[8];
  const float* g4 = (const float*)d_in[9];
  const float* b4 = (const float*)d_in[10];
  const float* w5 = (const float*)d_in[11];
  const float* g5 = (const float*)d_in[12];
  const float* b5 = (const float*)d_in[13];

  float* W = (float*)d_ws;
  float* xt = W;                        // 24576
  float* xp = W + 24576;                // 24576
  float* xx = W + 49152;                // 8192
  float* stats = W + 57344;             // arena: 4 stages x (gsum|gsq) + tail
  float* aArr = stats + 262144;         // 1024
  float* cArr = stats + 263168;         // 1024
  float* mu64 = stats + 264192;         // 64
  float* invv = stats + 264256;         // 64 (1 used)
  float* mom  = stats + 264320;         // 27*16 (pad 512)
  // arena ends at stats + 264832 = W + 322176
  float* x1 = W + 323584;               // 8192*64
  float* x2 = W + 847872;               // 8192*64
  float* x3 = W + 1372160;              // 8192*128 (reused as pmax at the end)
  float* x4 = W + 2420736;              // 8192*256 (raw max only; no fp32 apply)
  float* pd = W + 4517888;              // 8388608 (fgeo / Y|Z alias)
  float* Y  = pd;
  float* Z  = pd + 2097152;
  float* fgeo = pd;                     // 6*163840
  int* idx = (int*)(W + 12906496);      // 163840 ints -> end 13070336
  unsigned short* featb = (unsigned short*)(W + 13070336);  // 8192*512 bf16 (8MB)
  unsigned short* w5b = (unsigned short*)(W + 13070336 + 2097152);  // 1MB
  float* pmax = x3;
  float* out = (float*)d_out;

  const float MinvE = 1.f / (float)(BN_ * KNN);
  float* gs0 = stats;           float* gq0 = stats + 32768;
  float* gs1 = stats + 65536;   float* gq1 = stats + 98304;
  float* gs2 = stats + 131072;  float* gq2 = stats + 163840;
  float* gs3 = stats + 196608;  float* gq3 = stats + 229376;

  // one arena clear for all stages + moments
  hipMemsetAsync(stats, 0, 264832 * sizeof(float), stream);

  // prep + hyper block
  k_prep<<<32, 256, 0, stream>>>(x, xt, xp);
  k_knn3w<<<2048, 256, 0, stream>>>(xt, idx);
  k_hgeom<<<640, 256, 0, stream>>>(xp, idx, fgeo, mom);
  k_hfin2<<<1, 64, 0, stream>>>(mom, w1, mu64, invv);
  k_hyper_x1<<<2048, 256, 0, stream>>>(fgeo, w1, mu64, invv, x1, xx, featb);

  // edge block 2: x1(64) -> x2(64), featb cols 64..127
  k_pd2<64><<<dim3(16, 16, 8), 256, 0, stream>>>(x1, xx, pd);
  k_topkw<<<2048, 256, 0, stream>>>(pd, idx);
  k_xw2<64, 64><<<dim3(128, 2), 256, 0, stream>>>(x1, w2, Y, Z);
  k_gather2<64><<<2048, 256, 0, stream>>>(Y, Z, idx, gs0, gq0, x2);
  k_bnfin<<<1, 256, 0, stream>>>(gs0, gq0, g2, b2, aArr, cArr, 64, MinvE);
  k_apply<64, true, true><<<2048, 256, 0, stream>>>(x2, aArr, cArr, featb, 64, xx);

  // edge block 3: x2(64) -> x3(128), featb cols 128..255
  k_pd2<64><<<dim3(16, 16, 8), 256, 0, stream>>>(x2, xx, pd);
  k_topkw<<<2048, 256, 0, stream>>>(pd, idx);
  k_xw2<64, 128><<<dim3(128, 4), 256, 0, stream>>>(x2, w3, Y, Z);
  k_gather2<128><<<2048, 256, 0, stream>>>(Y, Z, idx, gs1, gq1, x3);
  k_bnfin<<<1, 256, 0, stream>>>(gs1, gq1, g3, b3, aArr, cArr, 128, MinvE);
  k_apply<128, true, true><<<2048, 256, 0, stream>>>(x3, aArr, cArr, featb, 128, xx);

  // edge block 4: x3(128) -> x4(256), featb cols 256..511 (bf16 only)
  k_pd2<128><<<dim3(16, 16, 8), 256, 0, stream>>>(x3, xx, pd);
  k_topkw<<<2048, 256, 0, stream>>>(pd, idx);
  k_xw2<128, 256><<<dim3(128, 8), 256, 0, stream>>>(x3, w4, Y, Z);
  k_gather2<256><<<2048, 256, 0, stream>>>(Y, Z, idx, gs2, gq2, x4);
  k_bnfin<<<1, 256, 0, stream>>>(gs2, gq2, g4, b4, aArr, cArr, 256, MinvE);
  k_apply<256, false, false><<<2048, 256, 0, stream>>>(x4, aArr, cArr, featb, 256, xx);

  // w5 -> bf16
  k_cvt<<<512, 256, 0, stream>>>(w5, w5b);

  // final: MFMA GEMM w/ fused stats+max, then bn+leaky+reduce
  k_fgemm3<<<dim3(64, 16), 256, 0, stream>>>(featb, w5b, gs3, gq3, pmax);
  k_bnfin<<<4, 256, 0, stream>>>(gs3, gq3, g5, b5, aArr, cArr, 1024, 1.f / (float)BN_);
  k_fmax2<<<32, 256, 0, stream>>>(pmax, aArr, cArr, out);
}

// Round 9
// 442.100 us; speedup vs baseline: 17.2156x; 1.2221x over previous
//
#include <hip/hip_runtime.h>
#include <math.h>

#define KNN 20
constexpr int B_ = 8, N_ = 1024, BN_ = B_ * N_;
constexpr int NEDGE = BN_ * KNN;  // 163840

using f32x4 = __attribute__((ext_vector_type(4))) float;
using s8v = __attribute__((ext_vector_type(8))) short;
typedef unsigned long long u64;

// ---------------- helpers ----------------
__device__ __forceinline__ float wave_sum(float v) {
#pragma unroll
  for (int off = 32; off >= 1; off >>= 1) v += __shfl_xor(v, off, 64);
  return v;
}

__device__ __forceinline__ unsigned sortable(float f) {
  unsigned u = __float_as_uint(f);
  return u ^ ((u & 0x80000000u) ? 0xFFFFFFFFu : 0x80000000u);
}

__device__ __forceinline__ unsigned short rne_bf16(float f) {
  unsigned u = __float_as_uint(f);
  unsigned r = (u + 0x7FFFu + ((u >> 16) & 1u)) >> 16;
  return (unsigned short)r;
}

// pack candidate: (value desc, index asc) as one u64 max-order
__device__ __forceinline__ u64 packkey(float v, int m) {
  return ((u64)sortable(v) << 10) | (u64)(1023 - m);
}

// Batcher odd-even mergesort of 16 u64 in registers, DESCENDING.
__device__ __forceinline__ void sort16_desc(u64 (&v)[16]) {
#pragma unroll
  for (int p = 1; p < 16; p <<= 1)
#pragma unroll
    for (int k = p; k >= 1; k >>= 1)
#pragma unroll
      for (int j = k & (p - 1); j + k < 16; j += 2 * k)
#pragma unroll
        for (int i = 0; i < k && i + j + k < 16; ++i)
          if ((i + j) / (2 * p) == (i + j + k) / (2 * p)) {
            u64 a = v[i + j], b = v[i + j + k];
            bool sw = a < b;  // descending
            v[i + j] = sw ? b : a;
            v[i + j + k] = sw ? a : b;
          }
}

// bitonic sort across 64 lanes, DESCENDING (lane 0 = largest)
__device__ __forceinline__ u64 bitonic64_desc(u64 B, int lane) {
#pragma unroll
  for (int k = 2; k <= 64; k <<= 1)
#pragma unroll
    for (int j = k >> 1; j > 0; j >>= 1) {
      u64 o = __shfl_xor(B, j, 64);
      bool up = ((lane & k) != 0);
      bool lower = ((lane & j) == 0);
      bool keepMin = (up == lower);
      bool takeOther = keepMin ? (o < B) : (o > B);
      B = takeOther ? o : B;
    }
  return B;
}

// Wave-per-row top-20: per-lane sorted lists + distributed sorted head-buffer.
// Exact jax.lax.top_k semantics (value desc, index asc).
__device__ __forceinline__ void topk20_sorted(u64 (&v)[16], int lane,
                                              int* __restrict__ outp) {
  sort16_desc(v);
  u64 B = v[0];
#pragma unroll
  for (int s = 0; s < 15; ++s) v[s] = v[s + 1];
  v[15] = 0;
  B = bitonic64_desc(B, lane);
  for (int sel = 0; sel < KNN; ++sel) {
    u64 win = __shfl(B, 0, 64);
    int m = 1023 - (int)(win & 1023ull);
    if (lane == 0) outp[sel] = m;
    int origin = m & 63;
    u64 ins = __shfl(v[0], origin, 64);
    bool isorig = (lane == origin);
#pragma unroll
    for (int s = 0; s < 15; ++s) v[s] = isorig ? v[s + 1] : v[s];
    v[15] = isorig ? 0 : v[15];
    u64 Bs = __shfl_down(B, 1, 64);
    if (lane == 63) Bs = 0;
    unsigned long long ball = __ballot(Bs > ins);
    int pos = __popcll(ball);
    u64 Bup = __shfl_up(Bs, 1, 64);
    B = (lane < pos) ? Bs : (lane == pos ? ins : Bup);
  }
}

// ---------------- prep: expmap0 only ----------------
__global__ void k_prep(const float* __restrict__ x, float* __restrict__ xp) {
  int i = blockIdx.x * 256 + threadIdx.x;  // 0..8191
  int b = i >> 10, n = i & 1023;
  float v0 = x[(b * 3 + 0) * N_ + n];
  float v1 = x[(b * 3 + 1) * N_ + n];
  float v2 = x[(b * 3 + 2) * N_ + n];
  float nsq = v0 * v0 + v1 * v1 + v2 * v2;
  float nn = sqrtf(fmaxf(nsq, 1e-15f));
  float s = tanhf(0.1f * nn) / (0.1f * nn);
  xp[i * 3 + 0] = s * v0; xp[i * 3 + 1] = s * v1; xp[i * 3 + 2] = s * v2;
}

// ---------------- knn in 3-d: wave per row, sorted-merge top-k -------------
__global__ __launch_bounds__(256) void k_knn3s(const float* __restrict__ x,
                                               int* __restrict__ idx) {
  __shared__ float4 pts4[N_];
  int t = threadIdx.x;
  int row0 = blockIdx.x * 4;
  int b = row0 >> 10;
  const float* xb = x + (size_t)b * 3 * N_;
  for (int i = t; i < N_; i += 256) {
    float px = xb[i], py = xb[N_ + i], pz = xb[2 * N_ + i];
    pts4[i] = make_float4(px, py, pz, px * px + py * py + pz * pz);
  }
  __syncthreads();
  int lane = t & 63, w = t >> 6;
  int row = row0 + w, rl = row & 1023;
  float4 c = pts4[rl];
  u64 v[16];
#pragma unroll
  for (int s = 0; s < 16; ++s) {
    int m = lane + 64 * s;
    float4 q = pts4[m];
    float dot = c.x * q.x + c.y * q.y + c.z * q.z;
    float val = 2.f * dot - c.w - q.w;
    v[s] = packkey(val, m);
  }
  topk20_sorted(v, lane, idx + (size_t)row * KNN);
}

// ---------------- top-20 of a pd row: wave per row -------------------------
__global__ __launch_bounds__(256) void k_topks(const float* __restrict__ pd,
                                               int* __restrict__ idx) {
  int t = threadIdx.x, lane = t & 63, w = t >> 6;
  int row = blockIdx.x * 4 + w;
  const float* rp = pd + (size_t)row * N_;
  u64 v[16];
#pragma unroll
  for (int s = 0; s < 16; ++s) v[s] = packkey(rp[lane + 64 * s], lane + 64 * s);
  topk20_sorted(v, lane, idx + (size_t)row * KNN);
}

// ---------------- hyper geometry per edge + moment accumulation -----------
__global__ __launch_bounds__(256) void k_hgeom(const float* __restrict__ xp,
                                               const int* __restrict__ idx,
                                               float* __restrict__ fgeo,
                                               float* __restrict__ mom) {
  int e = blockIdx.x * 256 + threadIdx.x;  // 0..163839
  int gw = e / KNN;
  int b = gw >> 10;
  int nbr = idx[e];
  const float* pc = xp + (size_t)gw * 3;
  float c0 = pc[0], c1 = pc[1], c2 = pc[2];
  const float* pn = xp + ((size_t)(b << 10) + nbr) * 3;
  float a0 = pn[0], a1 = pn[1], a2 = pn[2];
  float x2 = a0 * a0 + a1 * a1 + a2 * a2;
  float y2 = c0 * c0 + c1 * c1 + c2 * c2;
  float xy = -(a0 * c0 + a1 * c1 + a2 * c2);
  float f1 = 1.f + 0.02f * xy + 0.01f * y2;
  float f2 = 1.f - 0.01f * x2;
  float den = 1.f + 0.02f * xy + 0.0001f * x2 * y2;
  float rden = 1.f / fmaxf(den, 1e-15f);
  float m0 = (f1 * a0 - f2 * c0) * rden;
  float m1 = (f1 * a1 - f2 * c1) * rden;
  float m2 = (f1 * a2 - f2 * c2) * rden;
  float nsq = m0 * m0 + m1 * m1 + m2 * m2 + y2;
  float nn = sqrtf(fmaxf(nsq, 1e-15f));
  float sn = 0.1f * nn;
  float tt = fminf(sn, 1.f - 1e-7f);
  float s = atanhf(tt) / sn;
  float f[6] = {s * m0, s * m1, s * m2, s * c0, s * c1, s * c2};
#pragma unroll
  for (int j = 0; j < 6; ++j) fgeo[j * NEDGE + e] = f[j];
  float mm[27];
  {
    int q = 0;
#pragma unroll
    for (int i = 0; i < 6; ++i) mm[q++] = f[i];
#pragma unroll
    for (int i = 0; i < 6; ++i)
#pragma unroll
      for (int j = i; j < 6; ++j) mm[q++] = f[i] * f[j];
  }
#pragma unroll
  for (int m = 0; m < 27; ++m) mm[m] = wave_sum(mm[m]);
  __shared__ float part[4][27];
  int lane = threadIdx.x & 63, w = threadIdx.x >> 6;
  if (lane == 0) {
#pragma unroll
    for (int m = 0; m < 27; ++m) part[w][m] = mm[m];
  }
  __syncthreads();
  int t = threadIdx.x;
  if (t < 27) {
    float v = part[0][t] + part[1][t] + part[2][t] + part[3][t];
    atomicAdd(&mom[t * 16 + (blockIdx.x & 15)], v);
  }
}

// mu[ch] = w1[ch].fbar ; var = sum_ch (w1[ch]^T M w1[ch] - mu^2)
__global__ void k_hfin2(const float* __restrict__ mom,
                        const float* __restrict__ w1, float* mu64,
                        float* invv) {
  __shared__ float M[27];
  int t = threadIdx.x;  // 64
  if (t < 27) {
    float s = 0.f;
    for (int k = 0; k < 16; ++k) s += mom[t * 16 + k];
    M[t] = s * (1.f / (float)NEDGE);
  }
  __syncthreads();
  float w1r[6];
#pragma unroll
  for (int j = 0; j < 6; ++j) w1r[j] = w1[t * 6 + j];
  float mu = 0.f;
#pragma unroll
  for (int j = 0; j < 6; ++j) mu = fmaf(w1r[j], M[j], mu);
  float q = 0.f;
  {
    int off = 6;
#pragma unroll
    for (int i = 0; i < 6; ++i) {
      q = fmaf(w1r[i] * w1r[i], M[off], q); ++off;
#pragma unroll
      for (int j = i + 1; j < 6; ++j) {
        q = fmaf(2.f * w1r[i] * w1r[j], M[off], q); ++off;
      }
    }
  }
  float varc = q - mu * mu;
  float var = wave_sum(varc);
  mu64[t] = mu;
  if (t == 0) invv[0] = 1.f / sqrtf(var + 1e-5f);
}

// ---------------- hyper x1: matvec + BN + leaky + expmap/max/logmap -------
__global__ __launch_bounds__(256) void k_hyper_x1(
    const float* __restrict__ fgeo, const float* __restrict__ w1,
    const float* __restrict__ mu64, const float* __restrict__ invv,
    float* __restrict__ x1, float* __restrict__ xx,
    unsigned short* __restrict__ fb) {
  int t = threadIdx.x, lane = t & 63, w = t >> 6;
  int gw = blockIdx.x * 4 + w;
  float w1r[6];
#pragma unroll
  for (int j = 0; j < 6; ++j) w1r[j] = w1[lane * 6 + j];
  float f[6] = {0.f, 0.f, 0.f, 0.f, 0.f, 0.f};
  if (lane < KNN) {
    int e = gw * KNN + lane;
#pragma unroll
    for (int j = 0; j < 6; ++j) f[j] = fgeo[j * NEDGE + e];
  }
  float mu = mu64[lane];
  float inv = invv[0];
  float mx = -INFINITY;
  for (int k = 0; k < KNN; ++k) {
    float u = 0.f;
#pragma unroll
    for (int j = 0; j < 6; ++j) u = fmaf(w1r[j], __shfl(f[j], k), u);
    float vv = (u - mu) * inv;
    float l = vv > 0.f ? vv : 0.2f * vv;
    float nsq = wave_sum(l * l);
    float nn = sqrtf(fmaxf(nsq, 1e-15f));
    float sn = 0.1f * nn;
    float sc = tanhf(sn) / sn;
    mx = fmaxf(mx, sc * l);
  }
  float msq = wave_sum(mx * mx);
  float mn = sqrtf(fmaxf(msq, 1e-15f));
  float sn = 0.1f * mn;
  float tt = fminf(sn, 1.f - 1e-7f);
  float val = atanhf(tt) / sn * mx;
  x1[(size_t)gw * 64 + lane] = val;
  fb[(size_t)gw * 512 + lane] = rne_bf16(val);
  float xs = wave_sum(val * val);
  if (lane == 0) xx[gw] = xs;
}

// ---- fp32 GEMM tile core: LDS transposed [k][row] stride 68, b128 reads ---
__device__ __forceinline__ void load_t68(float (&Lt)[64][68],
                                         const float* __restrict__ src,
                                         int ldr, int t) {
  int row = t >> 2, kq = (t & 3) * 16;
  const float* p = src + (size_t)row * ldr + kq;
  float4 v0 = *(const float4*)(p);
  float4 v1 = *(const float4*)(p + 4);
  float4 v2 = *(const float4*)(p + 8);
  float4 v3 = *(const float4*)(p + 12);
  Lt[kq + 0][row] = v0.x;  Lt[kq + 1][row] = v0.y;
  Lt[kq + 2][row] = v0.z;  Lt[kq + 3][row] = v0.w;
  Lt[kq + 4][row] = v1.x;  Lt[kq + 5][row] = v1.y;
  Lt[kq + 6][row] = v1.z;  Lt[kq + 7][row] = v1.w;
  Lt[kq + 8][row] = v2.x;  Lt[kq + 9][row] = v2.y;
  Lt[kq + 10][row] = v2.z; Lt[kq + 11][row] = v2.w;
  Lt[kq + 12][row] = v3.x; Lt[kq + 13][row] = v3.y;
  Lt[kq + 14][row] = v3.z; Lt[kq + 15][row] = v3.w;
}

// ---------------- pairwise pd = 2 x.y - |x|^2 - |y|^2 (fp32!) -------------
template <int CIN>
__global__ __launch_bounds__(256) void k_pd2(const float* __restrict__ xin,
                                             const float* __restrict__ xx,
                                             float* __restrict__ pd) {
  __shared__ float At[64][68], Bt[64][68];
  int b = blockIdx.z;
  int n0 = blockIdx.x * 64, m0 = blockIdx.y * 64;
  int t = threadIdx.x;
  int tr4 = (t >> 4) * 4, tc4 = (t & 15) * 4;
  float acc[4][4] = {};
  const float* xb = xin + (size_t)b * N_ * CIN;
  for (int c0 = 0; c0 < CIN; c0 += 64) {
    if (c0) __syncthreads();
    load_t68(At, xb + (size_t)n0 * CIN + c0, CIN, t);
    load_t68(Bt, xb + (size_t)m0 * CIN + c0, CIN, t);
    __syncthreads();
#pragma unroll 4
    for (int k = 0; k < 64; ++k) {
      float4 a = *(const float4*)&At[k][tr4];
      float4 bb = *(const float4*)&Bt[k][tc4];
      float av[4] = {a.x, a.y, a.z, a.w};
      float bv[4] = {bb.x, bb.y, bb.z, bb.w};
#pragma unroll
      for (int ii = 0; ii < 4; ++ii)
#pragma unroll
        for (int jj = 0; jj < 4; ++jj) acc[ii][jj] = fmaf(av[ii], bv[jj], acc[ii][jj]);
    }
  }
  const float* xxn = xx + b * N_;
#pragma unroll
  for (int ii = 0; ii < 4; ++ii) {
    int r = n0 + tr4 + ii;
#pragma unroll
    for (int jj = 0; jj < 4; ++jj) {
      int c = m0 + tc4 + jj;
      pd[((size_t)b * N_ + r) * N_ + c] = 2.f * acc[ii][jj] - xxn[r] - xxn[c];
    }
  }
}

// ---------------- per-point linear maps: Y = X wA^T, Z = X wB^T ----------
template <int CIN, int COUT>
__global__ __launch_bounds__(256) void k_xw2(const float* __restrict__ xin,
                                             const float* __restrict__ w,
                                             float* __restrict__ Y,
                                             float* __restrict__ Z) {
  __shared__ float At[64][68], Bt[64][68];
  int n0 = blockIdx.x * 64;
  int j0 = blockIdx.y * 64;
  float* outp; int obase, coff;
  if (j0 < COUT) { outp = Y; obase = j0; coff = 0; }
  else { outp = Z; obase = j0 - COUT; coff = CIN; }
  int t = threadIdx.x;
  int tr4 = (t >> 4) * 4, tc4 = (t & 15) * 4;
  float acc[4][4] = {};
  for (int c0 = 0; c0 < CIN; c0 += 64) {
    if (c0) __syncthreads();
    load_t68(At, xin + (size_t)n0 * CIN + c0, CIN, t);
    load_t68(Bt, w + (size_t)obase * (2 * CIN) + coff + c0, 2 * CIN, t);
    __syncthreads();
#pragma unroll 4
    for (int k = 0; k < 64; ++k) {
      float4 a = *(const float4*)&At[k][tr4];
      float4 bb = *(const float4*)&Bt[k][tc4];
      float av[4] = {a.x, a.y, a.z, a.w};
      float bv[4] = {bb.x, bb.y, bb.z, bb.w};
#pragma unroll
      for (int ii = 0; ii < 4; ++ii)
#pragma unroll
        for (int jj = 0; jj < 4; ++jj) acc[ii][jj] = fmaf(av[ii], bv[jj], acc[ii][jj]);
    }
  }
#pragma unroll
  for (int ii = 0; ii < 4; ++ii)
#pragma unroll
    for (int jj = 0; jj < 4; ++jj)
      outp[(size_t)(n0 + tr4 + ii) * COUT + obase + tc4 + jj] = acc[ii][jj];
}

// ---------------- single-pass gather: BN stats + raw per-point max --------
template <int COUT>
__global__ __launch_bounds__(256) void k_gather2(
    const float* __restrict__ Y, const float* __restrict__ Z,
    const int* __restrict__ idx, float* gsum, float* gsq,
    float* __restrict__ xout) {
  constexpr int J = COUT / 64;
  int t = threadIdx.x, lane = t & 63, w = t >> 6;
  int bn = blockIdx.x * 4 + w;
  int b = bn >> 10;
  int myidx = 0;
  if (lane < KNN) myidx = idx[(size_t)bn * KNN + lane];
  float base[J], acc[J], acc2[J], mx[J];
#pragma unroll
  for (int j = 0; j < J; ++j) {
    int o = lane + 64 * j;
    base[j] = Z[(size_t)bn * COUT + o] - Y[(size_t)bn * COUT + o];
    acc[j] = 0.f; acc2[j] = 0.f; mx[j] = -INFINITY;
  }
  for (int k = 0; k < KNN; ++k) {
    int nbr = __shfl(myidx, k);
    const float* yr = Y + ((size_t)(b << 10) + nbr) * COUT;
#pragma unroll
    for (int j = 0; j < J; ++j) {
      float v = yr[lane + 64 * j] + base[j];
      acc[j] += v; acc2[j] += v * v; mx[j] = fmaxf(mx[j], v);
    }
  }
  int bkt = bn & 31;
#pragma unroll
  for (int j = 0; j < J; ++j) {
    atomicAdd(&gsum[bkt * 1024 + lane + 64 * j], acc[j]);
    atomicAdd(&gsq[bkt * 1024 + lane + 64 * j], acc2[j]);
    xout[(size_t)bn * COUT + lane + 64 * j] = mx[j];
  }
}

// ---------------- elementwise BN+leaky apply + bf16 featb pack ------------
template <int COUT, bool WXX, bool WOUT>
__global__ void k_apply(float* __restrict__ xio,
                        const float* __restrict__ aArr,
                        const float* __restrict__ cArr,
                        unsigned short* __restrict__ fb, int coloff,
                        float* __restrict__ xx) {
  constexpr int J = COUT / 64;
  int t = threadIdx.x, lane = t & 63, w = t >> 6;
  int bn = blockIdx.x * 4 + w;
  float s = 0.f;
#pragma unroll
  for (int j = 0; j < J; ++j) {
    int o = lane + 64 * j;
    float v = xio[(size_t)bn * COUT + o];
    float u = aArr[o] * v + cArr[o];
    u = u > 0.f ? u : 0.2f * u;
    if (WOUT) xio[(size_t)bn * COUT + o] = u;
    fb[(size_t)bn * 512 + coloff + o] = rne_bf16(u);
    if (WXX) s = fmaf(u, u, s);
  }
  if (WXX) {
    s = wave_sum(s);
    if (lane == 0) xx[bn] = s;
  }
}

// ---------------- bn finalize: scale/shift from bucketed sums -------------
__global__ void k_bnfin(const float* gsum, const float* gsq,
                        const float* __restrict__ g, const float* __restrict__ bb,
                        float* aArr, float* cArr, int COUT, float Minv) {
  int ch = blockIdx.x * 256 + threadIdx.x;
  if (ch >= COUT) return;
  float S = 0, S2 = 0;
  for (int k = 0; k < 32; ++k) { S += gsum[k * 1024 + ch]; S2 += gsq[k * 1024 + ch]; }
  float mu = S * Minv;
  float var = S2 * Minv - mu * mu;
  float a = g[ch] / sqrtf(var + 1e-5f);
  aArr[ch] = a;
  cArr[ch] = bb[ch] - mu * a;
}

// ---------------- fp32 -> bf16 straight convert (w5) ----------------
__global__ void k_cvt(const float* __restrict__ src,
                      unsigned short* __restrict__ dst) {
  int e = (blockIdx.x * 256 + threadIdx.x) * 4;
  float4 v = *(const float4*)(src + e);
  ushort4 o;
  o.x = rne_bf16(v.x); o.y = rne_bf16(v.y); o.z = rne_bf16(v.z); o.w = rne_bf16(v.w);
  *(ushort4*)(dst + e) = o;
}

// ---------------- final GEMM via MFMA bf16: LDS-staged B, prefetched A ----
__global__ __launch_bounds__(256) void k_fgemm3(
    const unsigned short* __restrict__ fb, const unsigned short* __restrict__ wb,
    float* gsum, float* gsq, float* __restrict__ pmax) {
  __shared__ unsigned short Bs[64][264];
  int t = threadIdx.x, lane = t & 63, w = t >> 6;
  int m0 = blockIdx.x * 128;
  int j0 = blockIdx.y * 64;
  int r16 = lane & 15, kg = lane >> 4;
  f32x4 acc[2][4];
#pragma unroll
  for (int mi = 0; mi < 2; ++mi)
#pragma unroll
    for (int nj = 0; nj < 4; ++nj) acc[mi][nj] = {0.f, 0.f, 0.f, 0.f};
  const unsigned short* pa0 = fb + (size_t)(m0 + w * 32 + r16) * 512 + kg * 8;
  const unsigned short* pa1 = pa0 + 16 * 512;
  s8v a0 = *(const s8v*)pa0;
  s8v a1 = *(const s8v*)pa1;
  int kglob = 0;
  for (int kh = 0; kh < 2; ++kh) {
    if (kh) __syncthreads();
#pragma unroll
    for (int it = 0; it < 8; ++it) {
      int chunk = it * 256 + t;
      int row = chunk >> 5;
      int kc = (chunk & 31) * 8;
      *(s8v*)&Bs[row][kc] =
          *(const s8v*)(wb + (size_t)(j0 + row) * 512 + kh * 256 + kc);
    }
    __syncthreads();
#pragma unroll
    for (int ki = 0; ki < 8; ++ki) {
      s8v na0 = a0, na1 = a1;
      int knext = kglob + 32;
      if (knext < 512) {
        na0 = *(const s8v*)(pa0 + knext);
        na1 = *(const s8v*)(pa1 + knext);
      }
      int kl = ki * 32 + kg * 8;
      s8v b0 = *(const s8v*)&Bs[r16][kl];
      s8v b1 = *(const s8v*)&Bs[r16 + 16][kl];
      s8v b2 = *(const s8v*)&Bs[r16 + 32][kl];
      s8v b3 = *(const s8v*)&Bs[r16 + 48][kl];
      acc[0][0] = __builtin_amdgcn_mfma_f32_16x16x32_bf16(a0, b0, acc[0][0], 0, 0, 0);
      acc[0][1] = __builtin_amdgcn_mfma_f32_16x16x32_bf16(a0, b1, acc[0][1], 0, 0, 0);
      acc[0][2] = __builtin_amdgcn_mfma_f32_16x16x32_bf16(a0, b2, acc[0][2], 0, 0, 0);
      acc[0][3] = __builtin_amdgcn_mfma_f32_16x16x32_bf16(a0, b3, acc[0][3], 0, 0, 0);
      acc[1][0] = __builtin_amdgcn_mfma_f32_16x16x32_bf16(a1, b0, acc[1][0], 0, 0, 0);
      acc[1][1] = __builtin_amdgcn_mfma_f32_16x16x32_bf16(a1, b1, acc[1][1], 0, 0, 0);
      acc[1][2] = __builtin_amdgcn_mfma_f32_16x16x32_bf16(a1, b2, acc[1][2], 0, 0, 0);
      acc[1][3] = __builtin_amdgcn_mfma_f32_16x16x32_bf16(a1, b3, acc[1][3], 0, 0, 0);
      a0 = na0; a1 = na1; kglob = knext;
    }
  }
  float s[4], s2[4], mx[4];
#pragma unroll
  for (int nj = 0; nj < 4; ++nj) {
    s[nj] = 0.f; s2[nj] = 0.f; mx[nj] = -INFINITY;
#pragma unroll
    for (int mi = 0; mi < 2; ++mi)
#pragma unroll
      for (int r = 0; r < 4; ++r) {
        float v = acc[mi][nj][r];
        s[nj] += v; s2[nj] += v * v; mx[nj] = fmaxf(mx[nj], v);
      }
    s[nj] += __shfl_xor(s[nj], 16, 64);  s[nj] += __shfl_xor(s[nj], 32, 64);
    s2[nj] += __shfl_xor(s2[nj], 16, 64); s2[nj] += __shfl_xor(s2[nj], 32, 64);
    mx[nj] = fmaxf(mx[nj], __shfl_xor(mx[nj], 16, 64));
    mx[nj] = fmaxf(mx[nj], __shfl_xor(mx[nj], 32, 64));
  }
  __shared__ float wsum[4][64], wsq[4][64], wmax[4][64];
  if (lane < 16) {
#pragma unroll
    for (int nj = 0; nj < 4; ++nj) {
      wsum[w][nj * 16 + lane] = s[nj];
      wsq[w][nj * 16 + lane] = s2[nj];
      wmax[w][nj * 16 + lane] = mx[nj];
    }
  }
  __syncthreads();
  if (t < 64) {
    float S = 0.f, S2 = 0.f, MX = -INFINITY;
#pragma unroll
    for (int ww = 0; ww < 4; ++ww) {
      S += wsum[ww][t]; S2 += wsq[ww][t]; MX = fmaxf(MX, wmax[ww][t]);
    }
    int o = j0 + t;
    int bkt = blockIdx.x & 31;
    atomicAdd(&gsum[bkt * 1024 + o], S);
    atomicAdd(&gsq[bkt * 1024 + o], S2);
    pmax[(size_t)(blockIdx.x & 7) * 8192 + (blockIdx.x >> 3) * 1024 + o] = MX;
  }
}

// final: bn + leaky over per-chunk maxes (a>0 so affine+leaky commutes w/ max)
__global__ void k_fmax2(const float* __restrict__ pmax,
                        const float* __restrict__ aArr,
                        const float* __restrict__ cArr, float* __restrict__ out) {
  int j = blockIdx.x * 256 + threadIdx.x;  // 0..8191
  int o = j & 1023;
  float mx = -INFINITY;
#pragma unroll
  for (int c = 0; c < 8; ++c) mx = fmaxf(mx, pmax[c * 8192 + j]);
  float v = aArr[o] * mx + cArr[o];
  v = v > 0.f ? v : 0.2f * v;
  out[j] = v;
}

// ---------------- launch ----------------
extern "C" void kernel_launch(void* const* d_in, const int* in_sizes, int n_in,
                              void* d_out, int out_size, void* d_ws,
                              size_t ws_size, hipStream_t stream) {
  const float* x  = (const float*)d_in[0];
  const float* w1 = (const float*)d_in[1];
  const float* w2 = (const float*)d_in[2];
  const float* g2 = (const float*)d_in[3];
  const float* b2 = (const float*)d_in[4];
  const float* w3 = (const float*)d_in[5];
  const float* g3 = (const float*)d_in[6];
  const float* b3 = (const float*)d_in[7];
  const float* w4 = (const float*)d_in[8];
  const float* g4 = (const float*)d_in[9];
  const float* b4 = (const float*)d_in[10];
  const float* w5 = (const float*)d_in[11];
  const float* g5 = (const float*)d_in[12];
  const float* b5 = (const float*)d_in[13];

  float* W = (float*)d_ws;
  float* xp = W + 24576;                // 24576
  float* xx = W + 49152;                // 8192
  float* stats = W + 57344;             // arena: 4 stages x (gsum|gsq) + tail
  float* aArr = stats + 262144;
  float* cArr = stats + 263168;
  float* mu64 = stats + 264192;
  float* invv = stats + 264256;
  float* mom  = stats + 264320;
  float* x1 = W + 323584;               // 8192*64
  float* x2 = W + 847872;               // 8192*64
  float* x3 = W + 1372160;              // 8192*128 (reused as pmax)
  float* x4 = W + 2420736;              // 8192*256 (raw max only)
  float* pd = W + 4517888;              // 8388608 (fgeo / Y|Z alias — Y/Z
  float* Y  = pd;                       //   written only AFTER topk reads pd)
  float* Z  = pd + 2097152;
  float* fgeo = pd;
  int* idx = (int*)(W + 12906496);      // 163840 ints
  unsigned short* featb = (unsigned short*)(W + 13070336);  // 8192*512 bf16
  unsigned short* w5b = (unsigned short*)(W + 13070336 + 2097152);
  float* pmax = x3;
  float* out = (float*)d_out;

  const float MinvE = 1.f / (float)(BN_ * KNN);
  float* gs0 = stats;           float* gq0 = stats + 32768;
  float* gs1 = stats + 65536;   float* gq1 = stats + 98304;
  float* gs2 = stats + 131072;  float* gq2 = stats + 163840;
  float* gs3 = stats + 196608;  float* gq3 = stats + 229376;

  hipMemsetAsync(stats, 0, 264832 * sizeof(float), stream);

  // prep + hyper block
  k_prep<<<32, 256, 0, stream>>>(x, xp);
  k_knn3s<<<2048, 256, 0, stream>>>(x, idx);
  k_hgeom<<<640, 256, 0, stream>>>(xp, idx, fgeo, mom);
  k_hfin2<<<1, 64, 0, stream>>>(mom, w1, mu64, invv);
  k_hyper_x1<<<2048, 256, 0, stream>>>(fgeo, w1, mu64, invv, x1, xx, featb);

  // edge block 2: x1(64) -> x2(64), featb cols 64..127
  k_pd2<64><<<dim3(16, 16, 8), 256, 0, stream>>>(x1, xx, pd);
  k_topks<<<2048, 256, 0, stream>>>(pd, idx);
  k_xw2<64, 64><<<dim3(128, 2), 256, 0, stream>>>(x1, w2, Y, Z);
  k_gather2<64><<<2048, 256, 0, stream>>>(Y, Z, idx, gs0, gq0, x2);
  k_bnfin<<<1, 256, 0, stream>>>(gs0, gq0, g2, b2, aArr, cArr, 64, MinvE);
  k_apply<64, true, true><<<2048, 256, 0, stream>>>(x2, aArr, cArr, featb, 64, xx);

  // edge block 3: x2(64) -> x3(128), featb cols 128..255
  k_pd2<64><<<dim3(16, 16, 8), 256, 0, stream>>>(x2, xx, pd);
  k_topks<<<2048, 256, 0, stream>>>(pd, idx);
  k_xw2<64, 128><<<dim3(128, 4), 256, 0, stream>>>(x2, w3, Y, Z);
  k_gather2<128><<<2048, 256, 0, stream>>>(Y, Z, idx, gs1, gq1, x3);
  k_bnfin<<<1, 256, 0, stream>>>(gs1, gq1, g3, b3, aArr, cArr, 128, MinvE);
  k_apply<128, true, true><<<2048, 256, 0, stream>>>(x3, aArr, cArr, featb, 128, xx);

  // edge block 4: x3(128) -> x4(256), featb cols 256..511 (bf16 only)
  k_pd2<128><<<dim3(16, 16, 8), 256, 0, stream>>>(x3, xx, pd);
  k_topks<<<2048, 256, 0, stream>>>(pd, idx);
  k_xw2<128, 256><<<dim3(128, 8), 256, 0, stream>>>(x3, w4, Y, Z);
  k_gather2<256><<<2048, 256, 0, stream>>>(Y, Z, idx, gs2, gq2, x4);
  k_bnfin<<<1, 256, 0, stream>>>(gs2, gq2, g4, b4, aArr, cArr, 256, MinvE);
  k_apply<256, false, false><<<2048, 256, 0, stream>>>(x4, aArr, cArr, featb, 256, xx);

  // w5 -> bf16
  k_cvt<<<512, 256, 0, stream>>>(w5, w5b);

  // final: MFMA GEMM w/ fused stats+max, then bn+leaky+reduce
  k_fgemm3<<<dim3(64, 16), 256, 0, stream>>>(featb, w5b, gs3, gq3, pmax);
  k_bnfin<<<4, 256, 0, stream>>>(gs3, gq3, g5, b5, aArr, cArr, 1024, 1.f / (float)BN_);
  k_fmax2<<<32, 256, 0, stream>>>(pmax, aArr, cArr, out);
}

// Round 10
// 427.682 us; speedup vs baseline: 17.7959x; 1.0337x over previous
//
#include <hip/hip_runtime.h>
#include <math.h>

#define KNN 20
constexpr int B_ = 8, N_ = 1024, BN_ = B_ * N_;
constexpr int NEDGE = BN_ * KNN;  // 163840

using f32x4 = __attribute__((ext_vector_type(4))) float;
using s8v = __attribute__((ext_vector_type(8))) short;
typedef unsigned long long u64;

// ---------------- helpers ----------------
__device__ __forceinline__ float wave_sum(float v) {
#pragma unroll
  for (int off = 32; off >= 1; off >>= 1) v += __shfl_xor(v, off, 64);
  return v;
}

__device__ __forceinline__ unsigned sortable(float f) {
  unsigned u = __float_as_uint(f);
  return u ^ ((u & 0x80000000u) ? 0xFFFFFFFFu : 0x80000000u);
}

__device__ __forceinline__ unsigned short rne_bf16(float f) {
  unsigned u = __float_as_uint(f);
  unsigned r = (u + 0x7FFFu + ((u >> 16) & 1u)) >> 16;
  return (unsigned short)r;
}

// pack candidate: (value desc, index asc) as one u64 max-order
__device__ __forceinline__ u64 packkey(float v, int m) {
  return ((u64)sortable(v) << 10) | (u64)(1023 - m);
}

// Batcher odd-even mergesort of 16 u64 in registers, DESCENDING.
__device__ __forceinline__ void sort16_desc(u64 (&v)[16]) {
#pragma unroll
  for (int p = 1; p < 16; p <<= 1)
#pragma unroll
    for (int k = p; k >= 1; k >>= 1)
#pragma unroll
      for (int j = k & (p - 1); j + k < 16; j += 2 * k)
#pragma unroll
        for (int i = 0; i < k && i + j + k < 16; ++i)
          if ((i + j) / (2 * p) == (i + j + k) / (2 * p)) {
            u64 a = v[i + j], b = v[i + j + k];
            bool sw = a < b;  // descending
            v[i + j] = sw ? b : a;
            v[i + j + k] = sw ? a : b;
          }
}

// bitonic sort across 64 lanes, DESCENDING (lane 0 = largest)
__device__ __forceinline__ u64 bitonic64_desc(u64 B, int lane) {
#pragma unroll
  for (int k = 2; k <= 64; k <<= 1)
#pragma unroll
    for (int j = k >> 1; j > 0; j >>= 1) {
      u64 o = __shfl_xor(B, j, 64);
      bool up = ((lane & k) != 0);
      bool lower = ((lane & j) == 0);
      bool keepMin = (up == lower);
      bool takeOther = keepMin ? (o < B) : (o > B);
      B = takeOther ? o : B;
    }
  return B;
}

// Wave-per-row top-20: per-lane sorted lists + distributed sorted head-buffer.
// Exact jax.lax.top_k semantics (value desc, index asc).
__device__ __forceinline__ void topk20_sorted(u64 (&v)[16], int lane,
                                              int* __restrict__ outp) {
  sort16_desc(v);
  u64 B = v[0];
#pragma unroll
  for (int s = 0; s < 15; ++s) v[s] = v[s + 1];
  v[15] = 0;
  B = bitonic64_desc(B, lane);
  for (int sel = 0; sel < KNN; ++sel) {
    u64 win = __shfl(B, 0, 64);
    int m = 1023 - (int)(win & 1023ull);
    if (lane == 0) outp[sel] = m;
    int origin = m & 63;
    u64 ins = __shfl(v[0], origin, 64);
    bool isorig = (lane == origin);
#pragma unroll
    for (int s = 0; s < 15; ++s) v[s] = isorig ? v[s + 1] : v[s];
    v[15] = isorig ? 0 : v[15];
    u64 Bs = __shfl_down(B, 1, 64);
    if (lane == 63) Bs = 0;
    unsigned long long ball = __ballot(Bs > ins);
    int pos = __popcll(ball);
    u64 Bup = __shfl_up(Bs, 1, 64);
    B = (lane < pos) ? Bs : (lane == pos ? ins : Bup);
  }
}

// ---------------- prep: expmap0 + w5 bf16 convert (fused grids) -----------
__global__ void k_prep2(const float* __restrict__ x, float* __restrict__ xp,
                        const float* __restrict__ w5,
                        unsigned short* __restrict__ w5b) {
  int bid = blockIdx.x;
  if (bid < 32) {
    int i = bid * 256 + threadIdx.x;  // 0..8191
    int b = i >> 10, n = i & 1023;
    float v0 = x[(b * 3 + 0) * N_ + n];
    float v1 = x[(b * 3 + 1) * N_ + n];
    float v2 = x[(b * 3 + 2) * N_ + n];
    float nsq = v0 * v0 + v1 * v1 + v2 * v2;
    float nn = sqrtf(fmaxf(nsq, 1e-15f));
    float s = tanhf(0.1f * nn) / (0.1f * nn);
    xp[i * 3 + 0] = s * v0; xp[i * 3 + 1] = s * v1; xp[i * 3 + 2] = s * v2;
  } else {
    int e = ((bid - 32) * 256 + threadIdx.x) * 4;
    float4 v = *(const float4*)(w5 + e);
    ushort4 o;
    o.x = rne_bf16(v.x); o.y = rne_bf16(v.y); o.z = rne_bf16(v.z); o.w = rne_bf16(v.w);
    *(ushort4*)(w5b + e) = o;
  }
}

// ---------------- knn in 3-d: wave per row, sorted-merge top-k -------------
__global__ __launch_bounds__(256) void k_knn3s(const float* __restrict__ x,
                                               int* __restrict__ idx) {
  __shared__ float4 pts4[N_];
  int t = threadIdx.x;
  int row0 = blockIdx.x * 4;
  int b = row0 >> 10;
  const float* xb = x + (size_t)b * 3 * N_;
  for (int i = t; i < N_; i += 256) {
    float px = xb[i], py = xb[N_ + i], pz = xb[2 * N_ + i];
    pts4[i] = make_float4(px, py, pz, px * px + py * py + pz * pz);
  }
  __syncthreads();
  int lane = t & 63, w = t >> 6;
  int row = row0 + w, rl = row & 1023;
  float4 c = pts4[rl];
  u64 v[16];
#pragma unroll
  for (int s = 0; s < 16; ++s) {
    int m = lane + 64 * s;
    float4 q = pts4[m];
    float dot = c.x * q.x + c.y * q.y + c.z * q.z;
    float val = 2.f * dot - c.w - q.w;
    v[s] = packkey(val, m);
  }
  topk20_sorted(v, lane, idx + (size_t)row * KNN);
}

// ---------------- top-20 of a pd row: wave per row -------------------------
__global__ __launch_bounds__(256) void k_topks(const float* __restrict__ pd,
                                               int* __restrict__ idx) {
  int t = threadIdx.x, lane = t & 63, w = t >> 6;
  int row = blockIdx.x * 4 + w;
  const float* rp = pd + (size_t)row * N_;
  u64 v[16];
#pragma unroll
  for (int s = 0; s < 16; ++s) v[s] = packkey(rp[lane + 64 * s], lane + 64 * s);
  topk20_sorted(v, lane, idx + (size_t)row * KNN);
}

// ---------------- hyper geometry per edge + moment accumulation -----------
__global__ __launch_bounds__(256) void k_hgeom(const float* __restrict__ xp,
                                               const int* __restrict__ idx,
                                               float* __restrict__ fgeo,
                                               float* __restrict__ mom) {
  int e = blockIdx.x * 256 + threadIdx.x;  // 0..163839
  int gw = e / KNN;
  int b = gw >> 10;
  int nbr = idx[e];
  const float* pc = xp + (size_t)gw * 3;
  float c0 = pc[0], c1 = pc[1], c2 = pc[2];
  const float* pn = xp + ((size_t)(b << 10) + nbr) * 3;
  float a0 = pn[0], a1 = pn[1], a2 = pn[2];
  float x2 = a0 * a0 + a1 * a1 + a2 * a2;
  float y2 = c0 * c0 + c1 * c1 + c2 * c2;
  float xy = -(a0 * c0 + a1 * c1 + a2 * c2);
  float f1 = 1.f + 0.02f * xy + 0.01f * y2;
  float f2 = 1.f - 0.01f * x2;
  float den = 1.f + 0.02f * xy + 0.0001f * x2 * y2;
  float rden = 1.f / fmaxf(den, 1e-15f);
  float m0 = (f1 * a0 - f2 * c0) * rden;
  float m1 = (f1 * a1 - f2 * c1) * rden;
  float m2 = (f1 * a2 - f2 * c2) * rden;
  float nsq = m0 * m0 + m1 * m1 + m2 * m2 + y2;
  float nn = sqrtf(fmaxf(nsq, 1e-15f));
  float sn = 0.1f * nn;
  float tt = fminf(sn, 1.f - 1e-7f);
  float s = atanhf(tt) / sn;
  float f[6] = {s * m0, s * m1, s * m2, s * c0, s * c1, s * c2};
#pragma unroll
  for (int j = 0; j < 6; ++j) fgeo[j * NEDGE + e] = f[j];
  float mm[27];
  {
    int q = 0;
#pragma unroll
    for (int i = 0; i < 6; ++i) mm[q++] = f[i];
#pragma unroll
    for (int i = 0; i < 6; ++i)
#pragma unroll
      for (int j = i; j < 6; ++j) mm[q++] = f[i] * f[j];
  }
#pragma unroll
  for (int m = 0; m < 27; ++m) mm[m] = wave_sum(mm[m]);
  __shared__ float part[4][27];
  int lane = threadIdx.x & 63, w = threadIdx.x >> 6;
  if (lane == 0) {
#pragma unroll
    for (int m = 0; m < 27; ++m) part[w][m] = mm[m];
  }
  __syncthreads();
  int t = threadIdx.x;
  if (t < 27) {
    float v = part[0][t] + part[1][t] + part[2][t] + part[3][t];
    atomicAdd(&mom[t * 16 + (blockIdx.x & 15)], v);
  }
}

// mu[ch] = w1[ch].fbar ; var = sum_ch (w1[ch]^T M w1[ch] - mu^2)
__global__ void k_hfin2(const float* __restrict__ mom,
                        const float* __restrict__ w1, float* mu64,
                        float* invv) {
  __shared__ float M[27];
  int t = threadIdx.x;  // 64
  if (t < 27) {
    float s = 0.f;
    for (int k = 0; k < 16; ++k) s += mom[t * 16 + k];
    M[t] = s * (1.f / (float)NEDGE);
  }
  __syncthreads();
  float w1r[6];
#pragma unroll
  for (int j = 0; j < 6; ++j) w1r[j] = w1[t * 6 + j];
  float mu = 0.f;
#pragma unroll
  for (int j = 0; j < 6; ++j) mu = fmaf(w1r[j], M[j], mu);
  float q = 0.f;
  {
    int off = 6;
#pragma unroll
    for (int i = 0; i < 6; ++i) {
      q = fmaf(w1r[i] * w1r[i], M[off], q); ++off;
#pragma unroll
      for (int j = i + 1; j < 6; ++j) {
        q = fmaf(2.f * w1r[i] * w1r[j], M[off], q); ++off;
      }
    }
  }
  float varc = q - mu * mu;
  float var = wave_sum(varc);
  mu64[t] = mu;
  if (t == 0) invv[0] = 1.f / sqrtf(var + 1e-5f);
}

// ---------------- hyper x1: matvec + BN + leaky + expmap/max/logmap -------
__global__ __launch_bounds__(256) void k_hyper_x1(
    const float* __restrict__ fgeo, const float* __restrict__ w1,
    const float* __restrict__ mu64, const float* __restrict__ invv,
    float* __restrict__ x1, float* __restrict__ xx,
    unsigned short* __restrict__ fb) {
  int t = threadIdx.x, lane = t & 63, w = t >> 6;
  int gw = blockIdx.x * 4 + w;
  float w1r[6];
#pragma unroll
  for (int j = 0; j < 6; ++j) w1r[j] = w1[lane * 6 + j];
  float f[6] = {0.f, 0.f, 0.f, 0.f, 0.f, 0.f};
  if (lane < KNN) {
    int e = gw * KNN + lane;
#pragma unroll
    for (int j = 0; j < 6; ++j) f[j] = fgeo[j * NEDGE + e];
  }
  float mu = mu64[lane];
  float inv = invv[0];
  float mx = -INFINITY;
  for (int k = 0; k < KNN; ++k) {
    float u = 0.f;
#pragma unroll
    for (int j = 0; j < 6; ++j) u = fmaf(w1r[j], __shfl(f[j], k), u);
    float vv = (u - mu) * inv;
    float l = vv > 0.f ? vv : 0.2f * vv;
    float nsq = wave_sum(l * l);
    float nn = sqrtf(fmaxf(nsq, 1e-15f));
    float sn = 0.1f * nn;
    float sc = tanhf(sn) / sn;
    mx = fmaxf(mx, sc * l);
  }
  float msq = wave_sum(mx * mx);
  float mn = sqrtf(fmaxf(msq, 1e-15f));
  float sn = 0.1f * mn;
  float tt = fminf(sn, 1.f - 1e-7f);
  float val = atanhf(tt) / sn * mx;
  x1[(size_t)gw * 64 + lane] = val;
  fb[(size_t)gw * 512 + lane] = rne_bf16(val);
  float xs = wave_sum(val * val);
  if (lane == 0) xx[gw] = xs;
}

// ---- fp32 GEMM tile core: LDS transposed [k][row] stride 68, b128 reads ---
__device__ __forceinline__ void load_t68(float (&Lt)[64][68],
                                         const float* __restrict__ src,
                                         int ldr, int t) {
  int row = t >> 2, kq = (t & 3) * 16;
  const float* p = src + (size_t)row * ldr + kq;
  float4 v0 = *(const float4*)(p);
  float4 v1 = *(const float4*)(p + 4);
  float4 v2 = *(const float4*)(p + 8);
  float4 v3 = *(const float4*)(p + 12);
  Lt[kq + 0][row] = v0.x;  Lt[kq + 1][row] = v0.y;
  Lt[kq + 2][row] = v0.z;  Lt[kq + 3][row] = v0.w;
  Lt[kq + 4][row] = v1.x;  Lt[kq + 5][row] = v1.y;
  Lt[kq + 6][row] = v1.z;  Lt[kq + 7][row] = v1.w;
  Lt[kq + 8][row] = v2.x;  Lt[kq + 9][row] = v2.y;
  Lt[kq + 10][row] = v2.z; Lt[kq + 11][row] = v2.w;
  Lt[kq + 12][row] = v3.x; Lt[kq + 13][row] = v3.y;
  Lt[kq + 14][row] = v3.z; Lt[kq + 15][row] = v3.w;
}

// ------- symmetric pd: upper-triangular blocks only, mirrored writes ------
// pd[b][n][m] = 2 x_n.x_m - xx[n] - xx[m]  (exactly symmetric in our compute:
// same acc register feeds both writes, so bits match the full version)
template <int CIN>
__global__ __launch_bounds__(256) void k_pdsym(const float* __restrict__ xin,
                                               const float* __restrict__ xx,
                                               float* __restrict__ pd) {
  __shared__ float At[64][68], Bt[64][68];
  int b = blockIdx.z;
  int id = blockIdx.x;  // 0..135 upper-tri block pair
  int i = 0, rem = id;
  while (rem >= 16 - i) { rem -= 16 - i; ++i; }
  int j = i + rem;
  int n0 = i << 6, m0 = j << 6;
  int t = threadIdx.x;
  int tr4 = (t >> 4) * 4, tc4 = (t & 15) * 4;
  float acc[4][4] = {};
  const float* xb = xin + (size_t)b * N_ * CIN;
  for (int c0 = 0; c0 < CIN; c0 += 64) {
    if (c0) __syncthreads();
    load_t68(At, xb + (size_t)n0 * CIN + c0, CIN, t);
    load_t68(Bt, xb + (size_t)m0 * CIN + c0, CIN, t);
    __syncthreads();
#pragma unroll 4
    for (int k = 0; k < 64; ++k) {
      float4 a = *(const float4*)&At[k][tr4];
      float4 bb = *(const float4*)&Bt[k][tc4];
      float av[4] = {a.x, a.y, a.z, a.w};
      float bv[4] = {bb.x, bb.y, bb.z, bb.w};
#pragma unroll
      for (int ii = 0; ii < 4; ++ii)
#pragma unroll
        for (int jj = 0; jj < 4; ++jj) acc[ii][jj] = fmaf(av[ii], bv[jj], acc[ii][jj]);
    }
  }
  const float* xxn = xx + b * N_;
  float v[4][4];
#pragma unroll
  for (int ii = 0; ii < 4; ++ii) {
    int r = n0 + tr4 + ii;
#pragma unroll
    for (int jj = 0; jj < 4; ++jj) {
      int c = m0 + tc4 + jj;
      v[ii][jj] = 2.f * acc[ii][jj] - xxn[r] - xxn[c];
      pd[((size_t)b * N_ + r) * N_ + c] = v[ii][jj];
    }
  }
  if (i != j) {
    // stage transposed tile in LDS (reuse At), then coalesced mirror write
    __syncthreads();
#pragma unroll
    for (int ii = 0; ii < 4; ++ii)
#pragma unroll
      for (int jj = 0; jj < 4; ++jj) At[tc4 + jj][tr4 + ii] = v[ii][jj];
    __syncthreads();
#pragma unroll
    for (int ii = 0; ii < 4; ++ii) {
      float4 rv = *(const float4*)&At[tr4 + ii][tc4];
      *(float4*)&pd[((size_t)b * N_ + m0 + tr4 + ii) * N_ + n0 + tc4] = rv;
    }
  }
}

// ---------------- per-point linear maps: Y = X wA^T, Z = X wB^T ----------
template <int CIN, int COUT>
__global__ __launch_bounds__(256) void k_xw2(const float* __restrict__ xin,
                                             const float* __restrict__ w,
                                             float* __restrict__ Y,
                                             float* __restrict__ Z) {
  __shared__ float At[64][68], Bt[64][68];
  int n0 = blockIdx.x * 64;
  int j0 = blockIdx.y * 64;
  float* outp; int obase, coff;
  if (j0 < COUT) { outp = Y; obase = j0; coff = 0; }
  else { outp = Z; obase = j0 - COUT; coff = CIN; }
  int t = threadIdx.x;
  int tr4 = (t >> 4) * 4, tc4 = (t & 15) * 4;
  float acc[4][4] = {};
  for (int c0 = 0; c0 < CIN; c0 += 64) {
    if (c0) __syncthreads();
    load_t68(At, xin + (size_t)n0 * CIN + c0, CIN, t);
    load_t68(Bt, w + (size_t)obase * (2 * CIN) + coff + c0, 2 * CIN, t);
    __syncthreads();
#pragma unroll 4
    for (int k = 0; k < 64; ++k) {
      float4 a = *(const float4*)&At[k][tr4];
      float4 bb = *(const float4*)&Bt[k][tc4];
      float av[4] = {a.x, a.y, a.z, a.w};
      float bv[4] = {bb.x, bb.y, bb.z, bb.w};
#pragma unroll
      for (int ii = 0; ii < 4; ++ii)
#pragma unroll
        for (int jj = 0; jj < 4; ++jj) acc[ii][jj] = fmaf(av[ii], bv[jj], acc[ii][jj]);
    }
  }
#pragma unroll
  for (int ii = 0; ii < 4; ++ii)
#pragma unroll
    for (int jj = 0; jj < 4; ++jj)
      outp[(size_t)(n0 + tr4 + ii) * COUT + obase + tc4 + jj] = acc[ii][jj];
}

// ---------------- single-pass gather: BN stats + raw per-point max --------
template <int COUT>
__global__ __launch_bounds__(256) void k_gather2(
    const float* __restrict__ Y, const float* __restrict__ Z,
    const int* __restrict__ idx, float* gsum, float* gsq,
    float* __restrict__ xout) {
  constexpr int J = COUT / 64;
  int t = threadIdx.x, lane = t & 63, w = t >> 6;
  int bn = blockIdx.x * 4 + w;
  int b = bn >> 10;
  int myidx = 0;
  if (lane < KNN) myidx = idx[(size_t)bn * KNN + lane];
  float base[J], acc[J], acc2[J], mx[J];
#pragma unroll
  for (int j = 0; j < J; ++j) {
    int o = lane + 64 * j;
    base[j] = Z[(size_t)bn * COUT + o] - Y[(size_t)bn * COUT + o];
    acc[j] = 0.f; acc2[j] = 0.f; mx[j] = -INFINITY;
  }
  for (int k = 0; k < KNN; ++k) {
    int nbr = __shfl(myidx, k);
    const float* yr = Y + ((size_t)(b << 10) + nbr) * COUT;
#pragma unroll
    for (int j = 0; j < J; ++j) {
      float v = yr[lane + 64 * j] + base[j];
      acc[j] += v; acc2[j] += v * v; mx[j] = fmaxf(mx[j], v);
    }
  }
  int bkt = bn & 31;
#pragma unroll
  for (int j = 0; j < J; ++j) {
    atomicAdd(&gsum[bkt * 1024 + lane + 64 * j], acc[j]);
    atomicAdd(&gsq[bkt * 1024 + lane + 64 * j], acc2[j]);
    xout[(size_t)bn * COUT + lane + 64 * j] = mx[j];
  }
}

// ---------------- elementwise BN+leaky apply + bf16 featb pack ------------
template <int COUT, bool WXX, bool WOUT>
__global__ void k_apply(float* __restrict__ xio,
                        const float* __restrict__ aArr,
                        const float* __restrict__ cArr,
                        unsigned short* __restrict__ fb, int coloff,
                        float* __restrict__ xx) {
  constexpr int J = COUT / 64;
  int t = threadIdx.x, lane = t & 63, w = t >> 6;
  int bn = blockIdx.x * 4 + w;
  float s = 0.f;
#pragma unroll
  for (int j = 0; j < J; ++j) {
    int o = lane + 64 * j;
    float v = xio[(size_t)bn * COUT + o];
    float u = aArr[o] * v + cArr[o];
    u = u > 0.f ? u : 0.2f * u;
    if (WOUT) xio[(size_t)bn * COUT + o] = u;
    fb[(size_t)bn * 512 + coloff + o] = rne_bf16(u);
    if (WXX) s = fmaf(u, u, s);
  }
  if (WXX) {
    s = wave_sum(s);
    if (lane == 0) xx[bn] = s;
  }
}

// ---------------- bn finalize: scale/shift from bucketed sums -------------
__global__ void k_bnfin(const float* gsum, const float* gsq,
                        const float* __restrict__ g, const float* __restrict__ bb,
                        float* aArr, float* cArr, int COUT, float Minv) {
  int ch = blockIdx.x * 256 + threadIdx.x;
  if (ch >= COUT) return;
  float S = 0, S2 = 0;
  for (int k = 0; k < 32; ++k) { S += gsum[k * 1024 + ch]; S2 += gsq[k * 1024 + ch]; }
  float mu = S * Minv;
  float var = S2 * Minv - mu * mu;
  float a = g[ch] / sqrtf(var + 1e-5f);
  aArr[ch] = a;
  cArr[ch] = bb[ch] - mu * a;
}

// ---------------- final GEMM via MFMA bf16: LDS-staged B, prefetched A ----
__global__ __launch_bounds__(256) void k_fgemm3(
    const unsigned short* __restrict__ fb, const unsigned short* __restrict__ wb,
    float* gsum, float* gsq, float* __restrict__ pmax) {
  __shared__ unsigned short Bs[64][264];
  int t = threadIdx.x, lane = t & 63, w = t >> 6;
  int m0 = blockIdx.x * 128;
  int j0 = blockIdx.y * 64;
  int r16 = lane & 15, kg = lane >> 4;
  f32x4 acc[2][4];
#pragma unroll
  for (int mi = 0; mi < 2; ++mi)
#pragma unroll
    for (int nj = 0; nj < 4; ++nj) acc[mi][nj] = {0.f, 0.f, 0.f, 0.f};
  const unsigned short* pa0 = fb + (size_t)(m0 + w * 32 + r16) * 512 + kg * 8;
  const unsigned short* pa1 = pa0 + 16 * 512;
  s8v a0 = *(const s8v*)pa0;
  s8v a1 = *(const s8v*)pa1;
  int kglob = 0;
  for (int kh = 0; kh < 2; ++kh) {
    if (kh) __syncthreads();
#pragma unroll
    for (int it = 0; it < 8; ++it) {
      int chunk = it * 256 + t;
      int row = chunk >> 5;
      int kc = (chunk & 31) * 8;
      *(s8v*)&Bs[row][kc] =
          *(const s8v*)(wb + (size_t)(j0 + row) * 512 + kh * 256 + kc);
    }
    __syncthreads();
#pragma unroll
    for (int ki = 0; ki < 8; ++ki) {
      s8v na0 = a0, na1 = a1;
      int knext = kglob + 32;
      if (knext < 512) {
        na0 = *(const s8v*)(pa0 + knext);
        na1 = *(const s8v*)(pa1 + knext);
      }
      int kl = ki * 32 + kg * 8;
      s8v b0 = *(const s8v*)&Bs[r16][kl];
      s8v b1 = *(const s8v*)&Bs[r16 + 16][kl];
      s8v b2 = *(const s8v*)&Bs[r16 + 32][kl];
      s8v b3 = *(const s8v*)&Bs[r16 + 48][kl];
      acc[0][0] = __builtin_amdgcn_mfma_f32_16x16x32_bf16(a0, b0, acc[0][0], 0, 0, 0);
      acc[0][1] = __builtin_amdgcn_mfma_f32_16x16x32_bf16(a0, b1, acc[0][1], 0, 0, 0);
      acc[0][2] = __builtin_amdgcn_mfma_f32_16x16x32_bf16(a0, b2, acc[0][2], 0, 0, 0);
      acc[0][3] = __builtin_amdgcn_mfma_f32_16x16x32_bf16(a0, b3, acc[0][3], 0, 0, 0);
      acc[1][0] = __builtin_amdgcn_mfma_f32_16x16x32_bf16(a1, b0, acc[1][0], 0, 0, 0);
      acc[1][1] = __builtin_amdgcn_mfma_f32_16x16x32_bf16(a1, b1, acc[1][1], 0, 0, 0);
      acc[1][2] = __builtin_amdgcn_mfma_f32_16x16x32_bf16(a1, b2, acc[1][2], 0, 0, 0);
      acc[1][3] = __builtin_amdgcn_mfma_f32_16x16x32_bf16(a1, b3, acc[1][3], 0, 0, 0);
      a0 = na0; a1 = na1; kglob = knext;
    }
  }
  float s[4], s2[4], mx[4];
#pragma unroll
  for (int nj = 0; nj < 4; ++nj) {
    s[nj] = 0.f; s2[nj] = 0.f; mx[nj] = -INFINITY;
#pragma unroll
    for (int mi = 0; mi < 2; ++mi)
#pragma unroll
      for (int r = 0; r < 4; ++r) {
        float v = acc[mi][nj][r];
        s[nj] += v; s2[nj] += v * v; mx[nj] = fmaxf(mx[nj], v);
      }
    s[nj] += __shfl_xor(s[nj], 16, 64);  s[nj] += __shfl_xor(s[nj], 32, 64);
    s2[nj] += __shfl_xor(s2[nj], 16, 64); s2[nj] += __shfl_xor(s2[nj], 32, 64);
    mx[nj] = fmaxf(mx[nj], __shfl_xor(mx[nj], 16, 64));
    mx[nj] = fmaxf(mx[nj], __shfl_xor(mx[nj], 32, 64));
  }
  __shared__ float wsum[4][64], wsq[4][64], wmax[4][64];
  if (lane < 16) {
#pragma unroll
    for (int nj = 0; nj < 4; ++nj) {
      wsum[w][nj * 16 + lane] = s[nj];
      wsq[w][nj * 16 + lane] = s2[nj];
      wmax[w][nj * 16 + lane] = mx[nj];
    }
  }
  __syncthreads();
  if (t < 64) {
    float S = 0.f, S2 = 0.f, MX = -INFINITY;
#pragma unroll
    for (int ww = 0; ww < 4; ++ww) {
      S += wsum[ww][t]; S2 += wsq[ww][t]; MX = fmaxf(MX, wmax[ww][t]);
    }
    int o = j0 + t;
    int bkt = blockIdx.x & 31;
    atomicAdd(&gsum[bkt * 1024 + o], S);
    atomicAdd(&gsq[bkt * 1024 + o], S2);
    pmax[(size_t)(blockIdx.x & 7) * 8192 + (blockIdx.x >> 3) * 1024 + o] = MX;
  }
}

// final: bn + leaky over per-chunk maxes (a>0 so affine+leaky commutes w/ max)
__global__ void k_fmax2(const float* __restrict__ pmax,
                        const float* __restrict__ aArr,
                        const float* __restrict__ cArr, float* __restrict__ out) {
  int j = blockIdx.x * 256 + threadIdx.x;  // 0..8191
  int o = j & 1023;
  float mx = -INFINITY;
#pragma unroll
  for (int c = 0; c < 8; ++c) mx = fmaxf(mx, pmax[c * 8192 + j]);
  float v = aArr[o] * mx + cArr[o];
  v = v > 0.f ? v : 0.2f * v;
  out[j] = v;
}

// ---------------- launch ----------------
extern "C" void kernel_launch(void* const* d_in, const int* in_sizes, int n_in,
                              void* d_out, int out_size, void* d_ws,
                              size_t ws_size, hipStream_t stream) {
  const float* x  = (const float*)d_in[0];
  const float* w1 = (const float*)d_in[1];
  const float* w2 = (const float*)d_in[2];
  const float* g2 = (const float*)d_in[3];
  const float* b2 = (const float*)d_in[4];
  const float* w3 = (const float*)d_in[5];
  const float* g3 = (const float*)d_in[6];
  const float* b3 = (const float*)d_in[7];
  const float* w4 = (const float*)d_in[8];
  const float* g4 = (const float*)d_in[9];
  const float* b4 = (const float*)d_in[10];
  const float* w5 = (const float*)d_in[11];
  const float* g5 = (const float*)d_in[12];
  const float* b5 = (const float*)d_in[13];

  float* W = (float*)d_ws;
  float* xp = W + 24576;                // 24576
  float* xx = W + 49152;                // 8192
  float* stats = W + 57344;             // arena: 4 stages x (gsum|gsq) + tail
  float* aArr = stats + 262144;
  float* cArr = stats + 263168;
  float* mu64 = stats + 264192;
  float* invv = stats + 264256;
  float* mom  = stats + 264320;
  float* x1 = W + 323584;               // 8192*64
  float* x2 = W + 847872;               // 8192*64
  float* x3 = W + 1372160;              // 8192*128 (reused as pmax)
  float* x4 = W + 2420736;              // 8192*256 (raw max only)
  float* pd = W + 4517888;              // 8388608 (fgeo / Y|Z alias — Y/Z
  float* Y  = pd;                       //   written only AFTER topk reads pd)
  float* Z  = pd + 2097152;
  float* fgeo = pd;
  int* idx = (int*)(W + 12906496);      // 163840 ints
  unsigned short* featb = (unsigned short*)(W + 13070336);  // 8192*512 bf16
  unsigned short* w5b = (unsigned short*)(W + 13070336 + 2097152);
  float* pmax = x3;
  float* out = (float*)d_out;

  const float MinvE = 1.f / (float)(BN_ * KNN);
  float* gs0 = stats;           float* gq0 = stats + 32768;
  float* gs1 = stats + 65536;   float* gq1 = stats + 98304;
  float* gs2 = stats + 131072;  float* gq2 = stats + 163840;
  float* gs3 = stats + 196608;  float* gq3 = stats + 229376;

  hipMemsetAsync(stats, 0, 264832 * sizeof(float), stream);

  // prep (+ w5 cvt) + hyper block
  k_prep2<<<32 + 512, 256, 0, stream>>>(x, xp, w5, w5b);
  k_knn3s<<<2048, 256, 0, stream>>>(x, idx);
  k_hgeom<<<640, 256, 0, stream>>>(xp, idx, fgeo, mom);
  k_hfin2<<<1, 64, 0, stream>>>(mom, w1, mu64, invv);
  k_hyper_x1<<<2048, 256, 0, stream>>>(fgeo, w1, mu64, invv, x1, xx, featb);

  // edge block 2: x1(64) -> x2(64), featb cols 64..127
  k_pdsym<64><<<dim3(136, 1, 8), 256, 0, stream>>>(x1, xx, pd);
  k_topks<<<2048, 256, 0, stream>>>(pd, idx);
  k_xw2<64, 64><<<dim3(128, 2), 256, 0, stream>>>(x1, w2, Y, Z);
  k_gather2<64><<<2048, 256, 0, stream>>>(Y, Z, idx, gs0, gq0, x2);
  k_bnfin<<<1, 256, 0, stream>>>(gs0, gq0, g2, b2, aArr, cArr, 64, MinvE);
  k_apply<64, true, true><<<2048, 256, 0, stream>>>(x2, aArr, cArr, featb, 64, xx);

  // edge block 3: x2(64) -> x3(128), featb cols 128..255
  k_pdsym<64><<<dim3(136, 1, 8), 256, 0, stream>>>(x2, xx, pd);
  k_topks<<<2048, 256, 0, stream>>>(pd, idx);
  k_xw2<64, 128><<<dim3(128, 4), 256, 0, stream>>>(x2, w3, Y, Z);
  k_gather2<128><<<2048, 256, 0, stream>>>(Y, Z, idx, gs1, gq1, x3);
  k_bnfin<<<1, 256, 0, stream>>>(gs1, gq1, g3, b3, aArr, cArr, 128, MinvE);
  k_apply<128, true, true><<<2048, 256, 0, stream>>>(x3, aArr, cArr, featb, 128, xx);

  // edge block 4: x3(128) -> x4(256), featb cols 256..511 (bf16 only)
  k_pdsym<128><<<dim3(136, 1, 8), 256, 0, stream>>>(x3, xx, pd);
  k_topks<<<2048, 256, 0, stream>>>(pd, idx);
  k_xw2<128, 256><<<dim3(128, 8), 256, 0, stream>>>(x3, w4, Y, Z);
  k_gather2<256><<<2048, 256, 0, stream>>>(Y, Z, idx, gs2, gq2, x4);
  k_bnfin<<<1, 256, 0, stream>>>(gs2, gq2, g4, b4, aArr, cArr, 256, MinvE);
  k_apply<256, false, false><<<2048, 256, 0, stream>>>(x4, aArr, cArr, featb, 256, xx);

  // final: MFMA GEMM w/ fused stats+max, then bn+leaky+reduce
  k_fgemm3<<<dim3(64, 16), 256, 0, stream>>>(featb, w5b, gs3, gq3, pmax);
  k_bnfin<<<4, 256, 0, stream>>>(gs3, gq3, g5, b5, aArr, cArr, 1024, 1.f / (float)BN_);
  k_fmax2<<<32, 256, 0, stream>>>(pmax, aArr, cArr, out);
}

// Round 13
// 413.503 us; speedup vs baseline: 18.4061x; 1.0343x over previous
//
#include <hip/hip_runtime.h>
#include <math.h>

#define KNN 20
constexpr int B_ = 8, N_ = 1024, BN_ = B_ * N_;
constexpr int NEDGE = BN_ * KNN;  // 163840

using f32x4 = __attribute__((ext_vector_type(4))) float;
using s8v = __attribute__((ext_vector_type(8))) short;
typedef unsigned long long u64;

// ---------------- helpers ----------------
__device__ __forceinline__ float wave_sum(float v) {
#pragma unroll
  for (int off = 32; off >= 1; off >>= 1) v += __shfl_xor(v, off, 64);
  return v;
}

__device__ __forceinline__ unsigned sortable(float f) {
  unsigned u = __float_as_uint(f);
  return u ^ ((u & 0x80000000u) ? 0xFFFFFFFFu : 0x80000000u);
}

__device__ __forceinline__ unsigned short rne_bf16(float f) {
  unsigned u = __float_as_uint(f);
  unsigned r = (u + 0x7FFFu + ((u >> 16) & 1u)) >> 16;
  return (unsigned short)r;
}

__device__ __forceinline__ u64 packkey(float v, int m) {
  return ((u64)sortable(v) << 10) | (u64)(1023 - m);
}

// Batcher odd-even mergesort of 16 u64 in registers, DESCENDING.
__device__ __forceinline__ void sort16_desc(u64 (&v)[16]) {
#pragma unroll
  for (int p = 1; p < 16; p <<= 1)
#pragma unroll
    for (int k = p; k >= 1; k >>= 1)
#pragma unroll
      for (int j = k & (p - 1); j + k < 16; j += 2 * k)
#pragma unroll
        for (int i = 0; i < k && i + j + k < 16; ++i)
          if ((i + j) / (2 * p) == (i + j + k) / (2 * p)) {
            u64 a = v[i + j], b = v[i + j + k];
            bool sw = a < b;
            v[i + j] = sw ? b : a;
            v[i + j + k] = sw ? a : b;
          }
}

// bitonic sort across 64 lanes, DESCENDING (lane 0 = largest)
__device__ __forceinline__ u64 bitonic64_desc(u64 B, int lane) {
#pragma unroll
  for (int k = 2; k <= 64; k <<= 1)
#pragma unroll
    for (int j = k >> 1; j > 0; j >>= 1) {
      u64 o = __shfl_xor(B, j, 64);
      bool up = ((lane & k) != 0);
      bool lower = ((lane & j) == 0);
      bool keepMin = (up == lower);
      bool takeOther = keepMin ? (o < B) : (o > B);
      B = takeOther ? o : B;
    }
  return B;
}

// Wave-per-row top-20 (exact jax.lax.top_k tie semantics).
__device__ __forceinline__ void topk20_sorted(u64 (&v)[16], int lane,
                                              int* __restrict__ outp) {
  sort16_desc(v);
  u64 B = v[0];
#pragma unroll
  for (int s = 0; s < 15; ++s) v[s] = v[s + 1];
  v[15] = 0;
  B = bitonic64_desc(B, lane);
  for (int sel = 0; sel < KNN; ++sel) {
    u64 win = __shfl(B, 0, 64);
    int m = 1023 - (int)(win & 1023ull);
    if (lane == 0) outp[sel] = m;
    int origin = m & 63;
    u64 ins = __shfl(v[0], origin, 64);
    bool isorig = (lane == origin);
#pragma unroll
    for (int s = 0; s < 15; ++s) v[s] = isorig ? v[s + 1] : v[s];
    v[15] = isorig ? 0 : v[15];
    u64 Bs = __shfl_down(B, 1, 64);
    if (lane == 63) Bs = 0;
    unsigned long long ball = __ballot(Bs > ins);
    int pos = __popcll(ball);
    u64 Bup = __shfl_up(Bs, 1, 64);
    B = (lane < pos) ? Bs : (lane == pos ? ins : Bup);
  }
}

// ------ fused: knn (2048 blocks) | expmap0 (32) | w5->bf16 (512) ----------
__global__ __launch_bounds__(256) void k_prep3(const float* __restrict__ x,
                                               float* __restrict__ xp,
                                               const float* __restrict__ w5,
                                               unsigned short* __restrict__ w5b,
                                               int* __restrict__ idx) {
  int bid = blockIdx.x;
  int t = threadIdx.x;
  if (bid < 2048) {
    __shared__ float4 pts4[N_];
    int row0 = bid * 4;
    int b = row0 >> 10;
    const float* xb = x + (size_t)b * 3 * N_;
    for (int i = t; i < N_; i += 256) {
      float px = xb[i], py = xb[N_ + i], pz = xb[2 * N_ + i];
      pts4[i] = make_float4(px, py, pz, px * px + py * py + pz * pz);
    }
    __syncthreads();
    int lane = t & 63, w = t >> 6;
    int row = row0 + w, rl = row & 1023;
    float4 c = pts4[rl];
    u64 v[16];
#pragma unroll
    for (int s = 0; s < 16; ++s) {
      int m = lane + 64 * s;
      float4 q = pts4[m];
      float dot = c.x * q.x + c.y * q.y + c.z * q.z;
      float val = 2.f * dot - c.w - q.w;
      v[s] = packkey(val, m);
    }
    topk20_sorted(v, lane, idx + (size_t)row * KNN);
  } else if (bid < 2080) {
    int i = (bid - 2048) * 256 + t;  // 0..8191
    int b = i >> 10, n = i & 1023;
    float v0 = x[(b * 3 + 0) * N_ + n];
    float v1 = x[(b * 3 + 1) * N_ + n];
    float v2 = x[(b * 3 + 2) * N_ + n];
    float nsq = v0 * v0 + v1 * v1 + v2 * v2;
    float nn = sqrtf(fmaxf(nsq, 1e-15f));
    float s = tanhf(0.1f * nn) / (0.1f * nn);
    xp[i * 3 + 0] = s * v0; xp[i * 3 + 1] = s * v1; xp[i * 3 + 2] = s * v2;
  } else {
    int e = ((bid - 2080) * 256 + t) * 4;
    float4 v = *(const float4*)(w5 + e);
    ushort4 o;
    o.x = rne_bf16(v.x); o.y = rne_bf16(v.y); o.z = rne_bf16(v.z); o.w = rne_bf16(v.w);
    *(ushort4*)(w5b + e) = o;
  }
}

// ---------------- top-20 of a pd row: wave per row -------------------------
__global__ __launch_bounds__(256) void k_topks(const float* __restrict__ pd,
                                               int* __restrict__ idx) {
  int t = threadIdx.x, lane = t & 63, w = t >> 6;
  int row = blockIdx.x * 4 + w;
  const float* rp = pd + (size_t)row * N_;
  u64 v[16];
#pragma unroll
  for (int s = 0; s < 16; ++s) v[s] = packkey(rp[lane + 64 * s], lane + 64 * s);
  topk20_sorted(v, lane, idx + (size_t)row * KNN);
}

// ---------------- hyper geometry per edge + moment accumulation -----------
__global__ __launch_bounds__(256) void k_hgeom(const float* __restrict__ xp,
                                               const int* __restrict__ idx,
                                               float* __restrict__ fgeo,
                                               float* __restrict__ mom) {
  int e = blockIdx.x * 256 + threadIdx.x;  // 0..163839
  int gw = e / KNN;
  int b = gw >> 10;
  int nbr = idx[e];
  const float* pc = xp + (size_t)gw * 3;
  float c0 = pc[0], c1 = pc[1], c2 = pc[2];
  const float* pn = xp + ((size_t)(b << 10) + nbr) * 3;
  float a0 = pn[0], a1 = pn[1], a2 = pn[2];
  float x2 = a0 * a0 + a1 * a1 + a2 * a2;
  float y2 = c0 * c0 + c1 * c1 + c2 * c2;
  float xy = -(a0 * c0 + a1 * c1 + a2 * c2);
  float f1 = 1.f + 0.02f * xy + 0.01f * y2;
  float f2 = 1.f - 0.01f * x2;
  float den = 1.f + 0.02f * xy + 0.0001f * x2 * y2;
  float rden = 1.f / fmaxf(den, 1e-15f);
  float m0 = (f1 * a0 - f2 * c0) * rden;
  float m1 = (f1 * a1 - f2 * c1) * rden;
  float m2 = (f1 * a2 - f2 * c2) * rden;
  float nsq = m0 * m0 + m1 * m1 + m2 * m2 + y2;
  float nn = sqrtf(fmaxf(nsq, 1e-15f));
  float sn = 0.1f * nn;
  float tt = fminf(sn, 1.f - 1e-7f);
  float s = atanhf(tt) / sn;
  float f[6] = {s * m0, s * m1, s * m2, s * c0, s * c1, s * c2};
#pragma unroll
  for (int j = 0; j < 6; ++j) fgeo[j * NEDGE + e] = f[j];
  float mm[27];
  {
    int q = 0;
#pragma unroll
    for (int i = 0; i < 6; ++i) mm[q++] = f[i];
#pragma unroll
    for (int i = 0; i < 6; ++i)
#pragma unroll
      for (int j = i; j < 6; ++j) mm[q++] = f[i] * f[j];
  }
#pragma unroll
  for (int m = 0; m < 27; ++m) mm[m] = wave_sum(mm[m]);
  __shared__ float part[4][27];
  int lane = threadIdx.x & 63, w = threadIdx.x >> 6;
  if (lane == 0) {
#pragma unroll
    for (int m = 0; m < 27; ++m) part[w][m] = mm[m];
  }
  __syncthreads();
  int t = threadIdx.x;
  if (t < 27) {
    float v = part[0][t] + part[1][t] + part[2][t] + part[3][t];
    atomicAdd(&mom[t * 16 + (blockIdx.x & 15)], v);
  }
}

// ---------------- hyper x1 (with inlined hfin2 stats finalize) -------------
__global__ __launch_bounds__(256) void k_hyper_x1(
    const float* __restrict__ fgeo, const float* __restrict__ w1,
    const float* __restrict__ mom, float* __restrict__ x1,
    float* __restrict__ xx, unsigned short* __restrict__ fb) {
  __shared__ float Msh[27], muS[64], invS;
  int t = threadIdx.x, lane = t & 63, w = t >> 6;
  if (t < 27) {
    float s = 0.f;
    for (int k = 0; k < 16; ++k) s += mom[t * 16 + k];
    Msh[t] = s * (1.f / (float)NEDGE);
  }
  __syncthreads();
  if (t < 64) {
    float w1r[6];
#pragma unroll
    for (int j = 0; j < 6; ++j) w1r[j] = w1[t * 6 + j];
    float mu = 0.f;
#pragma unroll
    for (int j = 0; j < 6; ++j) mu = fmaf(w1r[j], Msh[j], mu);
    float q = 0.f;
    int off = 6;
#pragma unroll
    for (int i = 0; i < 6; ++i) {
      q = fmaf(w1r[i] * w1r[i], Msh[off], q); ++off;
#pragma unroll
      for (int j = i + 1; j < 6; ++j) {
        q = fmaf(2.f * w1r[i] * w1r[j], Msh[off], q); ++off;
      }
    }
    float varc = q - mu * mu;
    float var = wave_sum(varc);
    muS[t] = mu;
    if (t == 0) invS = 1.f / sqrtf(var + 1e-5f);
  }
  __syncthreads();
  int gw = blockIdx.x * 4 + w;
  float w1r[6];
#pragma unroll
  for (int j = 0; j < 6; ++j) w1r[j] = w1[lane * 6 + j];
  float f[6] = {0.f, 0.f, 0.f, 0.f, 0.f, 0.f};
  if (lane < KNN) {
    int e = gw * KNN + lane;
#pragma unroll
    for (int j = 0; j < 6; ++j) f[j] = fgeo[j * NEDGE + e];
  }
  float mu = muS[lane];
  float inv = invS;
  float mx = -INFINITY;
  for (int k = 0; k < KNN; ++k) {
    float u = 0.f;
#pragma unroll
    for (int j = 0; j < 6; ++j) u = fmaf(w1r[j], __shfl(f[j], k), u);
    float vv = (u - mu) * inv;
    float l = vv > 0.f ? vv : 0.2f * vv;
    float nsq = wave_sum(l * l);
    float nn = sqrtf(fmaxf(nsq, 1e-15f));
    float sn = 0.1f * nn;
    float sc = tanhf(sn) / sn;
    mx = fmaxf(mx, sc * l);
  }
  float msq = wave_sum(mx * mx);
  float mn = sqrtf(fmaxf(msq, 1e-15f));
  float sn = 0.1f * mn;
  float tt = fminf(sn, 1.f - 1e-7f);
  float val = atanhf(tt) / sn * mx;
  x1[(size_t)gw * 64 + lane] = val;
  fb[(size_t)gw * 512 + lane] = rne_bf16(val);
  float xs = wave_sum(val * val);
  if (lane == 0) xx[gw] = xs;
}

// ---- fp32 GEMM tile core: LDS transposed [k][row] stride 68, b128 reads ---
__device__ __forceinline__ void load_t68(float (&Lt)[64][68],
                                         const float* __restrict__ src,
                                         int ldr, int t) {
  int row = t >> 2, kq = (t & 3) * 16;
  const float* p = src + (size_t)row * ldr + kq;
  float4 v0 = *(const float4*)(p);
  float4 v1 = *(const float4*)(p + 4);
  float4 v2 = *(const float4*)(p + 8);
  float4 v3 = *(const float4*)(p + 12);
  Lt[kq + 0][row] = v0.x;  Lt[kq + 1][row] = v0.y;
  Lt[kq + 2][row] = v0.z;  Lt[kq + 3][row] = v0.w;
  Lt[kq + 4][row] = v1.x;  Lt[kq + 5][row] = v1.y;
  Lt[kq + 6][row] = v1.z;  Lt[kq + 7][row] = v1.w;
  Lt[kq + 8][row] = v2.x;  Lt[kq + 9][row] = v2.y;
  Lt[kq + 10][row] = v2.z; Lt[kq + 11][row] = v2.w;
  Lt[kq + 12][row] = v3.x; Lt[kq + 13][row] = v3.y;
  Lt[kq + 14][row] = v3.z; Lt[kq + 15][row] = v3.w;
}

// --- pd 64x64 tile body (upper-tri + mirror) -------------------------------
template <int CIN>
__device__ __forceinline__ void pd_body(const float* __restrict__ xin,
                                        const float* __restrict__ xx,
                                        float* __restrict__ pd, int b, int tri,
                                        int t, float (&At)[64][68],
                                        float (&Bt)[64][68]) {
  int i = 0, rem = tri;
  while (rem >= 16 - i) { rem -= 16 - i; ++i; }
  int j = i + rem;
  int n0 = i << 6, m0 = j << 6;
  int tr4 = (t >> 4) * 4, tc4 = (t & 15) * 4;
  float acc[4][4] = {};
  const float* xb = xin + (size_t)b * N_ * CIN;
  for (int c0 = 0; c0 < CIN; c0 += 64) {
    if (c0) __syncthreads();
    load_t68(At, xb + (size_t)n0 * CIN + c0, CIN, t);
    load_t68(Bt, xb + (size_t)m0 * CIN + c0, CIN, t);
    __syncthreads();
#pragma unroll 4
    for (int k = 0; k < 64; ++k) {
      float4 a = *(const float4*)&At[k][tr4];
      float4 bb = *(const float4*)&Bt[k][tc4];
      float av[4] = {a.x, a.y, a.z, a.w};
      float bv[4] = {bb.x, bb.y, bb.z, bb.w};
#pragma unroll
      for (int ii = 0; ii < 4; ++ii)
#pragma unroll
        for (int jj = 0; jj < 4; ++jj) acc[ii][jj] = fmaf(av[ii], bv[jj], acc[ii][jj]);
    }
  }
  const float* xxn = xx + b * N_;
  float v[4][4];
#pragma unroll
  for (int ii = 0; ii < 4; ++ii) {
    int r = n0 + tr4 + ii;
#pragma unroll
    for (int jj = 0; jj < 4; ++jj) {
      int c = m0 + tc4 + jj;
      v[ii][jj] = 2.f * acc[ii][jj] - xxn[r] - xxn[c];
      pd[((size_t)b * N_ + r) * N_ + c] = v[ii][jj];
    }
  }
  if (i != j) {
    __syncthreads();
#pragma unroll
    for (int ii = 0; ii < 4; ++ii)
#pragma unroll
      for (int jj = 0; jj < 4; ++jj) At[tc4 + jj][tr4 + ii] = v[ii][jj];
    __syncthreads();
#pragma unroll
    for (int ii = 0; ii < 4; ++ii) {
      float4 rv = *(const float4*)&At[tr4 + ii][tc4];
      *(float4*)&pd[((size_t)b * N_ + m0 + tr4 + ii) * N_ + n0 + tc4] = rv;
    }
  }
}

// --- xw 64x64 tile body ----------------------------------------------------
template <int CIN, int COUT>
__device__ __forceinline__ void xw_body(const float* __restrict__ xin,
                                        const float* __restrict__ w,
                                        float* __restrict__ Y,
                                        float* __restrict__ Z, int bid, int t,
                                        float (&At)[64][68],
                                        float (&Bt)[64][68]) {
  int n0 = (bid & 127) * 64;
  int j0 = (bid >> 7) * 64;
  float* outp; int obase, coff;
  if (j0 < COUT) { outp = Y; obase = j0; coff = 0; }
  else { outp = Z; obase = j0 - COUT; coff = CIN; }
  int tr4 = (t >> 4) * 4, tc4 = (t & 15) * 4;
  float acc[4][4] = {};
  for (int c0 = 0; c0 < CIN; c0 += 64) {
    if (c0) __syncthreads();
    load_t68(At, xin + (size_t)n0 * CIN + c0, CIN, t);
    load_t68(Bt, w + (size_t)obase * (2 * CIN) + coff + c0, 2 * CIN, t);
    __syncthreads();
#pragma unroll 4
    for (int k = 0; k < 64; ++k) {
      float4 a = *(const float4*)&At[k][tr4];
      float4 bb = *(const float4*)&Bt[k][tc4];
      float av[4] = {a.x, a.y, a.z, a.w};
      float bv[4] = {bb.x, bb.y, bb.z, bb.w};
#pragma unroll
      for (int ii = 0; ii < 4; ++ii)
#pragma unroll
        for (int jj = 0; jj < 4; ++jj) acc[ii][jj] = fmaf(av[ii], bv[jj], acc[ii][jj]);
    }
  }
#pragma unroll
  for (int ii = 0; ii < 4; ++ii)
#pragma unroll
    for (int jj = 0; jj < 4; ++jj)
      outp[(size_t)(n0 + tr4 + ii) * COUT + obase + tc4 + jj] = acc[ii][jj];
}

// ------- fused pd+xw (Y/Z DISJOINT from pd — stages 2,3 only) --------------
template <int CIN, int COUT>
__global__ __launch_bounds__(256) void k_pdxw(const float* __restrict__ xin,
                                              const float* __restrict__ xx,
                                              float* __restrict__ pd,
                                              const float* __restrict__ w,
                                              float* __restrict__ Y,
                                              float* __restrict__ Z) {
  __shared__ float At[64][68], Bt[64][68];
  int id = blockIdx.x;
  int t = threadIdx.x;
  if (id < 1088) {
    int b = id / 136, tri = id - b * 136;
    pd_body<CIN>(xin, xx, pd, b, tri, t, At, Bt);
  } else {
    xw_body<CIN, COUT>(xin, w, Y, Z, id - 1088, t, At, Bt);
  }
}

// ------- standalone pdsym / xw2 (stage 4: Y/Z alias pd, must stay split) ---
template <int CIN>
__global__ __launch_bounds__(256) void k_pdsym(const float* __restrict__ xin,
                                               const float* __restrict__ xx,
                                               float* __restrict__ pd) {
  __shared__ float At[64][68], Bt[64][68];
  pd_body<CIN>(xin, xx, pd, blockIdx.z, blockIdx.x, threadIdx.x, At, Bt);
}

template <int CIN, int COUT>
__global__ __launch_bounds__(256) void k_xw2(const float* __restrict__ xin,
                                             const float* __restrict__ w,
                                             float* __restrict__ Y,
                                             float* __restrict__ Z) {
  __shared__ float At[64][68], Bt[64][68];
  int bid = blockIdx.x + blockIdx.y * 128;
  xw_body<CIN, COUT>(xin, w, Y, Z, bid, threadIdx.x, At, Bt);
}

// ---------------- single-pass gather: BN stats + raw per-point max --------
template <int COUT>
__global__ __launch_bounds__(256) void k_gather2(
    const float* __restrict__ Y, const float* __restrict__ Z,
    const int* __restrict__ idx, float* gsum, float* gsq,
    float* __restrict__ xout) {
  constexpr int J = COUT / 64;
  int t = threadIdx.x, lane = t & 63, w = t >> 6;
  int bn = blockIdx.x * 4 + w;
  int b = bn >> 10;
  int myidx = 0;
  if (lane < KNN) myidx = idx[(size_t)bn * KNN + lane];
  float base[J], acc[J], acc2[J], mx[J];
#pragma unroll
  for (int j = 0; j < J; ++j) {
    int o = lane + 64 * j;
    base[j] = Z[(size_t)bn * COUT + o] - Y[(size_t)bn * COUT + o];
    acc[j] = 0.f; acc2[j] = 0.f; mx[j] = -INFINITY;
  }
  for (int k = 0; k < KNN; ++k) {
    int nbr = __shfl(myidx, k);
    const float* yr = Y + ((size_t)(b << 10) + nbr) * COUT;
#pragma unroll
    for (int j = 0; j < J; ++j) {
      float v = yr[lane + 64 * j] + base[j];
      acc[j] += v; acc2[j] += v * v; mx[j] = fmaxf(mx[j], v);
    }
  }
  int bkt = bn & 31;
#pragma unroll
  for (int j = 0; j < J; ++j) {
    atomicAdd(&gsum[bkt * 1024 + lane + 64 * j], acc[j]);
    atomicAdd(&gsq[bkt * 1024 + lane + 64 * j], acc2[j]);
    xout[(size_t)bn * COUT + lane + 64 * j] = mx[j];
  }
}

// ---------------- elementwise BN+leaky apply + bf16 featb pack ------------
template <int COUT, bool WXX, bool WOUT>
__global__ void k_apply(float* __restrict__ xio,
                        const float* __restrict__ aArr,
                        const float* __restrict__ cArr,
                        unsigned short* __restrict__ fb, int coloff,
                        float* __restrict__ xx) {
  constexpr int J = COUT / 64;
  int t = threadIdx.x, lane = t & 63, w = t >> 6;
  int bn = blockIdx.x * 4 + w;
  float s = 0.f;
#pragma unroll
  for (int j = 0; j < J; ++j) {
    int o = lane + 64 * j;
    float v = xio[(size_t)bn * COUT + o];
    float u = aArr[o] * v + cArr[o];
    u = u > 0.f ? u : 0.2f * u;
    if (WOUT) xio[(size_t)bn * COUT + o] = u;
    fb[(size_t)bn * 512 + coloff + o] = rne_bf16(u);
    if (WXX) s = fmaf(u, u, s);
  }
  if (WXX) {
    s = wave_sum(s);
    if (lane == 0) xx[bn] = s;
  }
}

// ---------------- bn finalize: scale/shift from bucketed sums -------------
__global__ void k_bnfin(const float* gsum, const float* gsq,
                        const float* __restrict__ g, const float* __restrict__ bb,
                        float* aArr, float* cArr, int COUT, float Minv) {
  int ch = blockIdx.x * 256 + threadIdx.x;
  if (ch >= COUT) return;
  float S = 0, S2 = 0;
  for (int k = 0; k < 32; ++k) { S += gsum[k * 1024 + ch]; S2 += gsq[k * 1024 + ch]; }
  float mu = S * Minv;
  float var = S2 * Minv - mu * mu;
  float a = g[ch] / sqrtf(var + 1e-5f);
  aArr[ch] = a;
  cArr[ch] = bb[ch] - mu * a;
}

// ---------------- final GEMM via MFMA bf16: LDS B, 2-deep A prefetch ------
__global__ __launch_bounds__(256) void k_fgemm3(
    const unsigned short* __restrict__ fb, const unsigned short* __restrict__ wb,
    float* gsum, float* gsq, float* __restrict__ pmax) {
  __shared__ unsigned short Bs[64][264];
  int t = threadIdx.x, lane = t & 63, w = t >> 6;
  int m0 = blockIdx.x * 128;
  int j0 = blockIdx.y * 64;
  int r16 = lane & 15, kg = lane >> 4;
  f32x4 acc[2][4];
#pragma unroll
  for (int mi = 0; mi < 2; ++mi)
#pragma unroll
    for (int nj = 0; nj < 4; ++nj) acc[mi][nj] = {0.f, 0.f, 0.f, 0.f};
  const unsigned short* pa0 = fb + (size_t)(m0 + w * 32 + r16) * 512 + kg * 8;
  const unsigned short* pa1 = pa0 + 16 * 512;
  s8v aC0 = *(const s8v*)pa0,        aC1 = *(const s8v*)pa1;
  s8v aN0 = *(const s8v*)(pa0 + 32), aN1 = *(const s8v*)(pa1 + 32);
  int kglob = 0;
  for (int kh = 0; kh < 2; ++kh) {
    if (kh) __syncthreads();
#pragma unroll
    for (int it = 0; it < 8; ++it) {
      int chunk = it * 256 + t;
      int row = chunk >> 5;
      int kc = (chunk & 31) * 8;
      *(s8v*)&Bs[row][kc] =
          *(const s8v*)(wb + (size_t)(j0 + row) * 512 + kh * 256 + kc);
    }
    __syncthreads();
#pragma unroll
    for (int ki = 0; ki < 8; ++ki) {
      s8v aF0 = aN0, aF1 = aN1;
      int kf = kglob + 64;
      if (kf < 512) {
        aF0 = *(const s8v*)(pa0 + kf);
        aF1 = *(const s8v*)(pa1 + kf);
      }
      int kl = ki * 32 + kg * 8;
      s8v b0 = *(const s8v*)&Bs[r16][kl];
      s8v b1 = *(const s8v*)&Bs[r16 + 16][kl];
      s8v b2 = *(const s8v*)&Bs[r16 + 32][kl];
      s8v b3 = *(const s8v*)&Bs[r16 + 48][kl];
      acc[0][0] = __builtin_amdgcn_mfma_f32_16x16x32_bf16(aC0, b0, acc[0][0], 0, 0, 0);
      acc[0][1] = __builtin_amdgcn_mfma_f32_16x16x32_bf16(aC0, b1, acc[0][1], 0, 0, 0);
      acc[0][2] = __builtin_amdgcn_mfma_f32_16x16x32_bf16(aC0, b2, acc[0][2], 0, 0, 0);
      acc[0][3] = __builtin_amdgcn_mfma_f32_16x16x32_bf16(aC0, b3, acc[0][3], 0, 0, 0);
      acc[1][0] = __builtin_amdgcn_mfma_f32_16x16x32_bf16(aC1, b0, acc[1][0], 0, 0, 0);
      acc[1][1] = __builtin_amdgcn_mfma_f32_16x16x32_bf16(aC1, b1, acc[1][1], 0, 0, 0);
      acc[1][2] = __builtin_amdgcn_mfma_f32_16x16x32_bf16(aC1, b2, acc[1][2], 0, 0, 0);
      acc[1][3] = __builtin_amdgcn_mfma_f32_16x16x32_bf16(aC1, b3, acc[1][3], 0, 0, 0);
      aC0 = aN0; aC1 = aN1; aN0 = aF0; aN1 = aF1; kglob += 32;
    }
  }
  float s[4], s2[4], mx[4];
#pragma unroll
  for (int nj = 0; nj < 4; ++nj) {
    s[nj] = 0.f; s2[nj] = 0.f; mx[nj] = -INFINITY;
#pragma unroll
    for (int mi = 0; mi < 2; ++mi)
#pragma unroll
      for (int r = 0; r < 4; ++r) {
        float v = acc[mi][nj][r];
        s[nj] += v; s2[nj] += v * v; mx[nj] = fmaxf(mx[nj], v);
      }
    s[nj] += __shfl_xor(s[nj], 16, 64);  s[nj] += __shfl_xor(s[nj], 32, 64);
    s2[nj] += __shfl_xor(s2[nj], 16, 64); s2[nj] += __shfl_xor(s2[nj], 32, 64);
    mx[nj] = fmaxf(mx[nj], __shfl_xor(mx[nj], 16, 64));
    mx[nj] = fmaxf(mx[nj], __shfl_xor(mx[nj], 32, 64));
  }
  __shared__ float wsum[4][64], wsq[4][64], wmax[4][64];
  if (lane < 16) {
#pragma unroll
    for (int nj = 0; nj < 4; ++nj) {
      wsum[w][nj * 16 + lane] = s[nj];
      wsq[w][nj * 16 + lane] = s2[nj];
      wmax[w][nj * 16 + lane] = mx[nj];
    }
  }
  __syncthreads();
  if (t < 64) {
    float S = 0.f, S2 = 0.f, MX = -INFINITY;
#pragma unroll
    for (int ww = 0; ww < 4; ++ww) {
      S += wsum[ww][t]; S2 += wsq[ww][t]; MX = fmaxf(MX, wmax[ww][t]);
    }
    int o = j0 + t;
    int bkt = blockIdx.x & 31;
    atomicAdd(&gsum[bkt * 1024 + o], S);
    atomicAdd(&gsq[bkt * 1024 + o], S2);
    pmax[(size_t)(blockIdx.x & 7) * 8192 + (blockIdx.x >> 3) * 1024 + o] = MX;
  }
}

// final: per-channel bnfin (folded) + bn + leaky over per-chunk maxes
__global__ void k_fmax3(const float* __restrict__ pmax, const float* gsum,
                        const float* gsq, const float* __restrict__ g,
                        const float* __restrict__ bb, float* __restrict__ out) {
  int j = blockIdx.x * 256 + threadIdx.x;  // 0..8191
  int o = j & 1023;
  float S = 0.f, S2 = 0.f;
#pragma unroll 8
  for (int k = 0; k < 32; ++k) { S += gsum[k * 1024 + o]; S2 += gsq[k * 1024 + o]; }
  const float Minv = 1.f / (float)BN_;
  float mu = S * Minv;
  float var = S2 * Minv - mu * mu;
  float a = g[o] / sqrtf(var + 1e-5f);
  float c = bb[o] - mu * a;
  float mx = -INFINITY;
#pragma unroll
  for (int ch = 0; ch < 8; ++ch) mx = fmaxf(mx, pmax[ch * 8192 + j]);
  float v = a * mx + c;
  v = v > 0.f ? v : 0.2f * v;
  out[j] = v;
}

// ---------------- launch ----------------
extern "C" void kernel_launch(void* const* d_in, const int* in_sizes, int n_in,
                              void* d_out, int out_size, void* d_ws,
                              size_t ws_size, hipStream_t stream) {
  const float* x  = (const float*)d_in[0];
  const float* w1 = (const float*)d_in[1];
  const float* w2 = (const float*)d_in[2];
  const float* g2 = (const float*)d_in[3];
  const float* b2 = (const float*)d_in[4];
  const float* w3 = (const float*)d_in[5];
  const float* g3 = (const float*)d_in[6];
  const float* b3 = (const float*)d_in[7];
  const float* w4 = (const float*)d_in[8];
  const float* g4 = (const float*)d_in[9];
  const float* b4 = (const float*)d_in[10];
  const float* w5 = (const float*)d_in[11];
  const float* g5 = (const float*)d_in[12];
  const float* b5 = (const float*)d_in[13];

  float* W = (float*)d_ws;
  float* xp = W + 24576;
  float* xx = W + 49152;
  float* stats = W + 57344;             // arena: 4 stages x (gsum|gsq) + tail
  float* aArr = stats + 262144;
  float* cArr = stats + 263168;
  float* mom  = stats + 264320;
  float* x1 = W + 323584;               // 8192*64
  float* x2 = W + 847872;               // 8192*64
  float* x3 = W + 1372160;              // 8192*128 (reused as pmax)
  float* x4 = W + 2420736;              // 8192*256 (stage-2/3 Y|Z; stage-4 raw max)
  float* pd = W + 4517888;              // 8388608 (fgeo alias; stage-4 Y|Z alias)
  float* Y4 = pd;                       //   written only AFTER topks reads pd
  float* Z4 = pd + 2097152;
  float* fgeo = pd;
  int* idx = (int*)(W + 12906496);      // 163840 ints
  unsigned short* featb = (unsigned short*)(W + 13070336);  // 8192*512 bf16
  unsigned short* w5b = (unsigned short*)(W + 13070336 + 2097152);
  float* pmax = x3;
  float* out = (float*)d_out;

  // stage-2/3 Y/Z live in the x4 region (disjoint from pd)
  float* Y2 = x4;             float* Z2 = x4 + 524288;   // 8192*64 each
  float* Y3 = x4;             float* Z3 = x4 + 1048576;  // 8192*128 each

  const float MinvE = 1.f / (float)(BN_ * KNN);
  float* gs0 = stats;           float* gq0 = stats + 32768;
  float* gs1 = stats + 65536;   float* gq1 = stats + 98304;
  float* gs2 = stats + 131072;  float* gq2 = stats + 163840;
  float* gs3 = stats + 196608;  float* gq3 = stats + 229376;

  hipMemsetAsync(stats, 0, 264832 * sizeof(float), stream);

  // fused prep: knn + expmap0 + w5 cvt; then hyper block
  k_prep3<<<2592, 256, 0, stream>>>(x, xp, w5, w5b, idx);
  k_hgeom<<<640, 256, 0, stream>>>(xp, idx, fgeo, mom);
  k_hyper_x1<<<2048, 256, 0, stream>>>(fgeo, w1, mom, x1, xx, featb);

  // edge block 2: x1(64) -> x2(64), featb cols 64..127
  k_pdxw<64, 64><<<1088 + 256, 256, 0, stream>>>(x1, xx, pd, w2, Y2, Z2);
  k_topks<<<2048, 256, 0, stream>>>(pd, idx);
  k_gather2<64><<<2048, 256, 0, stream>>>(Y2, Z2, idx, gs0, gq0, x2);
  k_bnfin<<<1, 256, 0, stream>>>(gs0, gq0, g2, b2, aArr, cArr, 64, MinvE);
  k_apply<64, true, true><<<2048, 256, 0, stream>>>(x2, aArr, cArr, featb, 64, xx);

  // edge block 3: x2(64) -> x3(128), featb cols 128..255
  k_pdxw<64, 128><<<1088 + 512, 256, 0, stream>>>(x2, xx, pd, w3, Y3, Z3);
  k_topks<<<2048, 256, 0, stream>>>(pd, idx);
  k_gather2<128><<<2048, 256, 0, stream>>>(Y3, Z3, idx, gs1, gq1, x3);
  k_bnfin<<<1, 256, 0, stream>>>(gs1, gq1, g3, b3, aArr, cArr, 128, MinvE);
  k_apply<128, true, true><<<2048, 256, 0, stream>>>(x3, aArr, cArr, featb, 128, xx);

  // edge block 4: x3(128) -> x4(256), featb cols 256..511 (bf16 only)
  k_pdsym<128><<<dim3(136, 1, 8), 256, 0, stream>>>(x3, xx, pd);
  k_topks<<<2048, 256, 0, stream>>>(pd, idx);
  k_xw2<128, 256><<<dim3(128, 8), 256, 0, stream>>>(x3, w4, Y4, Z4);
  k_gather2<256><<<2048, 256, 0, stream>>>(Y4, Z4, idx, gs2, gq2, x4);
  k_bnfin<<<1, 256, 0, stream>>>(gs2, gq2, g4, b4, aArr, cArr, 256, MinvE);
  k_apply<256, false, false><<<2048, 256, 0, stream>>>(x4, aArr, cArr, featb, 256, xx);

  // final: MFMA GEMM w/ fused stats+max, then folded bnfin+bn+leaky+reduce
  k_fgemm3<<<dim3(64, 16), 256, 0, stream>>>(featb, w5b, gs3, gq3, pmax);
  k_fmax3<<<32, 256, 0, stream>>>(pmax, gs3, gq3, g5, b5, out);
}